// Round 6
// baseline (966.860 us; speedup 1.0000x reference)
//
#include <hip/hip_runtime.h>
#include <hip/hip_bf16.h>

#define D 64
#define NB 8      // nodes per wave-block
#define WPAD 68   // padded weight stride (floats), 16B-aligned, bank-spread

__device__ __forceinline__ float selu_f(float x) {
    const float SC = 1.0507009873554805f;
    const float AL = 1.6732632423543772f;
    return x > 0.f ? SC * x : SC * AL * (expf(x) - 1.f);
}
__device__ __forceinline__ float sigmoid_f(float x) { return 1.f / (1.f + expf(-x)); }
__device__ __forceinline__ float dot4(float4 a, float4 b, float acc) {
    acc = fmaf(a.x, b.x, acc);
    acc = fmaf(a.y, b.y, acc);
    acc = fmaf(a.z, b.z, acc);
    return fmaf(a.w, b.w, acc);
}

// ---- A: y = x@Wy^T, z = x@Wz^T (Wy = Wmsg[:,:64], Wz = Wmsg[:,64:]) ----
__global__ void __launch_bounds__(1024) yz_kernel(const float* __restrict__ x,
                                                  const float* __restrict__ Wmsg,
                                                  float* __restrict__ y,
                                                  float* __restrict__ z, int N) {
    __shared__ __align__(16) float wbuf[2 * 64 * WPAD];  // 34 KB
    __shared__ __align__(16) float xs[16 * NB * 64];     // 32 KB
    for (int idx = threadIdx.x; idx < 2 * 64 * 64; idx += 1024) {
        int g = idx >> 12, rem = idx & 4095;
        int d = rem >> 6, j = rem & 63;
        wbuf[g * 64 * WPAD + d * WPAD + j] = Wmsg[d * 128 + g * 64 + j];
    }
    __syncthreads();
    int lane = threadIdx.x & 63;
    int w = threadIdx.x >> 6;
    float* xw = &xs[w * (NB * 64)];
    const float* wy = wbuf;
    const float* wz = wbuf + 64 * WPAD;
    int nbTot = (N + NB - 1) / NB;
    for (int nb = blockIdx.x * 16 + w; nb < nbTot; nb += gridDim.x * 16) {
        int n0 = nb * NB;
#pragma unroll
        for (int n = 0; n < NB; ++n) {
            int i = n0 + n;
            xw[n * 64 + lane] = (i < N) ? x[(size_t)i * 64 + lane] : 0.f;
        }
        float accy[NB], accz[NB];
#pragma unroll
        for (int n = 0; n < NB; ++n) { accy[n] = 0.f; accz[n] = 0.f; }
#pragma unroll 1
        for (int jg = 0; jg < 16; ++jg) {
            float4 wyv = *(const float4*)&wy[lane * WPAD + jg * 4];
            float4 wzv = *(const float4*)&wz[lane * WPAD + jg * 4];
#pragma unroll
            for (int n = 0; n < NB; ++n) {
                float4 xv = *(const float4*)&xw[n * 64 + jg * 4];  // uniform: broadcast
                accy[n] = dot4(wyv, xv, accy[n]);
                accz[n] = dot4(wzv, xv, accz[n]);
            }
        }
#pragma unroll
        for (int n = 0; n < NB; ++n) {
            int i = n0 + n;
            if (i < N) {
                y[(size_t)i * 64 + lane] = accy[n];
                z[(size_t)i * 64 + lane] = accz[n];
            }
        }
    }
}

// ---- CSR build ----
__global__ void __launch_bounds__(256) count_kernel(const int* __restrict__ idn,
                                                    int* __restrict__ cnt, int E) {
    int i = blockIdx.x * blockDim.x + threadIdx.x;
    if (i < E) atomicAdd(&cnt[idn[i]], 1);
}

__global__ void __launch_bounds__(1024) scan_kernel(const int* __restrict__ cnt,
                                                    int* __restrict__ row_start, int N) {
    __shared__ int part[1024];
    int t = threadIdx.x;
    int chunk = (N + 1023) / 1024;
    int lo = t * chunk;
    int hi = lo + chunk < N ? lo + chunk : N;
    int s = 0;
    for (int i = lo; i < hi; ++i) s += cnt[i];
    part[t] = s;
    __syncthreads();
    for (int off = 1; off < 1024; off <<= 1) {
        int v = part[t];
        int u = (t >= off) ? part[t - off] : 0;
        __syncthreads();
        part[t] = v + u;
        __syncthreads();
    }
    int excl = (t == 0) ? 0 : part[t - 1];
    for (int i = lo; i < hi; ++i) {
        row_start[i] = excl;
        excl += cnt[i];
    }
    if (t == 1023) row_start[N] = part[1023];
}

__global__ void __launch_bounds__(256) fill_kernel(const int* __restrict__ idm,
                                                   const int* __restrict__ idn,
                                                   const int* __restrict__ row_start,
                                                   int* __restrict__ cursor,
                                                   int* __restrict__ csr_src, int E) {
    int i = blockIdx.x * blockDim.x + threadIdx.x;
    if (i < E) {
        int n = idn[i];
        int p = atomicAdd(&cursor[n], 1);
        csr_src[row_start[n] + p] = idm[i];
    }
}

// ---- B: gather+selu -> M ; gi = M@Wih^T ; gh = h@Whh^T ; GRU combine ----
__global__ void __launch_bounds__(512) void_step_guard();  // (unused decl guard)
__global__ void __launch_bounds__(512) step_kernel(
    const float* __restrict__ y, const float* __restrict__ z,
    float* __restrict__ cur, const float* __restrict__ bmsg,
    const int* __restrict__ row_start, const int* __restrict__ csr_src,
    const float* __restrict__ Wih, const float* __restrict__ Whh,
    const float* __restrict__ bih, const float* __restrict__ bhh, int N) {
    __shared__ __align__(16) float wbuf[6 * 64 * WPAD];  // 104.4 KB
    __shared__ __align__(16) float xsM[8 * NB * 64];     // 16 KB
    __shared__ __align__(16) float xsH[8 * NB * 64];     // 16 KB
    for (int idx = threadIdx.x; idx < 6 * 64 * 64; idx += 512) {
        int g = idx >> 12, rem = idx & 4095;
        int d = rem >> 6, j = rem & 63;
        const float* src = (g < 3) ? Wih : Whh;
        int gg = (g < 3) ? g : g - 3;
        wbuf[g * 64 * WPAD + d * WPAD + j] = src[(gg * 64 + d) * 64 + j];
    }
    __syncthreads();
    int lane = threadIdx.x & 63;
    int w = threadIdx.x >> 6;
    float* xm = &xsM[w * (NB * 64)];
    float* xh = &xsH[w * (NB * 64)];
    const float* wir = wbuf + 0 * 64 * WPAD;
    const float* wiz = wbuf + 1 * 64 * WPAD;
    const float* win = wbuf + 2 * 64 * WPAD;
    const float* whr = wbuf + 3 * 64 * WPAD;
    const float* whz = wbuf + 4 * 64 * WPAD;
    const float* whn = wbuf + 5 * 64 * WPAD;
    float b = bmsg[lane];
    float bir = bih[lane], biz = bih[64 + lane], bin_ = bih[128 + lane];
    float bhr = bhh[lane], bhz = bhh[64 + lane], bhn = bhh[128 + lane];
    int nbTot = (N + NB - 1) / NB;
    for (int nb = blockIdx.x * 8 + w; nb < nbTot; nb += gridDim.x * 8) {
        int n0 = nb * NB;
        float hv[NB];
#pragma unroll
        for (int n = 0; n < NB; ++n) {
            int i = n0 + n;
            hv[n] = (i < N) ? cur[(size_t)i * 64 + lane] : 0.f;
            xh[n * 64 + lane] = hv[n];
        }
#pragma unroll
        for (int n = 0; n < NB; ++n) {
            int i = n0 + n;
            float macc = 0.f;
            if (i < N) {
                float zb = z[(size_t)i * 64 + lane] + b;
                int s0 = row_start[i], s1 = row_start[i + 1];
                int s = s0;
                for (; s + 4 <= s1; s += 4) {
                    int e0 = csr_src[s], e1 = csr_src[s + 1];
                    int e2 = csr_src[s + 2], e3 = csr_src[s + 3];
                    float v0 = y[(size_t)e0 * 64 + lane];
                    float v1 = y[(size_t)e1 * 64 + lane];
                    float v2 = y[(size_t)e2 * 64 + lane];
                    float v3 = y[(size_t)e3 * 64 + lane];
                    macc += selu_f(v0 + zb);
                    macc += selu_f(v1 + zb);
                    macc += selu_f(v2 + zb);
                    macc += selu_f(v3 + zb);
                }
                for (; s < s1; ++s) macc += selu_f(y[(size_t)csr_src[s] * 64 + lane] + zb);
            }
            xm[n * 64 + lane] = macc;
        }
        float air[NB], aiz[NB], ain[NB], ahr[NB], ahz[NB], ahn[NB];
#pragma unroll
        for (int n = 0; n < NB; ++n) {
            air[n] = 0.f; aiz[n] = 0.f; ain[n] = 0.f;
            ahr[n] = 0.f; ahz[n] = 0.f; ahn[n] = 0.f;
        }
#pragma unroll 1
        for (int jg = 0; jg < 16; ++jg) {
            float4 wirv = *(const float4*)&wir[lane * WPAD + jg * 4];
            float4 wizv = *(const float4*)&wiz[lane * WPAD + jg * 4];
            float4 winv = *(const float4*)&win[lane * WPAD + jg * 4];
            float4 whrv = *(const float4*)&whr[lane * WPAD + jg * 4];
            float4 whzv = *(const float4*)&whz[lane * WPAD + jg * 4];
            float4 whnv = *(const float4*)&whn[lane * WPAD + jg * 4];
#pragma unroll
            for (int n = 0; n < NB; ++n) {
                float4 m4 = *(const float4*)&xm[n * 64 + jg * 4];  // uniform broadcast
                float4 h4 = *(const float4*)&xh[n * 64 + jg * 4];
                air[n] = dot4(wirv, m4, air[n]);
                aiz[n] = dot4(wizv, m4, aiz[n]);
                ain[n] = dot4(winv, m4, ain[n]);
                ahr[n] = dot4(whrv, h4, ahr[n]);
                ahz[n] = dot4(whzv, h4, ahz[n]);
                ahn[n] = dot4(whnv, h4, ahn[n]);
            }
        }
#pragma unroll
        for (int n = 0; n < NB; ++n) {
            int i = n0 + n;
            if (i < N) {
                float r = sigmoid_f(air[n] + bir + ahr[n] + bhr);
                float zg = sigmoid_f(aiz[n] + biz + ahz[n] + bhz);
                float nn = tanhf(ain[n] + bin_ + r * (ahn[n] + bhn));
                cur[(size_t)i * 64 + lane] = (1.f - zg) * nn + zg * hv[n];
            }
        }
    }
}

__global__ void __launch_bounds__(256) pathsum_kernel(const float* __restrict__ h,
                                                      float* __restrict__ kp, int N, int K) {
    int per = N / K;
    int blocksPerPath = gridDim.x / K;
    int p = blockIdx.x / blocksPerPath;
    int c = blockIdx.x % blocksPerPath;
    int d = threadIdx.x & 63;
    int row0 = c * (blockDim.x >> 6) + (threadIdx.x >> 6);
    int stride = blocksPerPath * (blockDim.x >> 6);
    float acc = 0.f;
    for (int r = row0; r < per; r += stride) acc += h[((size_t)p * per + r) * 64 + d];
    __shared__ float red[256];
    red[threadIdx.x] = acc;
    __syncthreads();
    if (threadIdx.x < 64) {
        float s = red[threadIdx.x] + red[64 + threadIdx.x] + red[128 + threadIdx.x] +
                  red[192 + threadIdx.x];
        atomicAdd(&kp[p * 64 + threadIdx.x], s);
    }
}

// 8 blocks, one per path: h1 = selu(kp@Wr1^T+br1); h2 = selu(h1@Wr2^T+br2)
__global__ void __launch_bounds__(256) readout1_kernel(const float* __restrict__ kp,
                                                       const float* __restrict__ Wr1,
                                                       const float* __restrict__ br1,
                                                       const float* __restrict__ Wr2,
                                                       const float* __restrict__ br2,
                                                       float* __restrict__ h2) {
    int p = blockIdx.x;
    int t = threadIdx.x;
    __shared__ __align__(16) float kps[64];
    __shared__ __align__(16) float h1[256];
    if (t < 64) kps[t] = kp[p * 64 + t];
    __syncthreads();
    float acc = br1[t];
#pragma unroll
    for (int d4 = 0; d4 < 16; ++d4) {
        float4 wv = *(const float4*)&Wr1[t * 64 + d4 * 4];
        float4 kv = *(const float4*)&kps[d4 * 4];
        acc = dot4(wv, kv, acc);
    }
    h1[t] = selu_f(acc);
    __syncthreads();
    float acc2 = br2[t];
#pragma unroll 8
    for (int j4 = 0; j4 < 64; ++j4) {
        float4 wv = *(const float4*)&Wr2[t * 256 + j4 * 4];
        float4 hv = *(const float4*)&h1[j4 * 4];
        acc2 = dot4(wv, hv, acc2);
    }
    h2[p * 256 + t] = selu_f(acc2);
}

__global__ void __launch_bounds__(256) readout2_kernel(const float* __restrict__ h2,
                                                       const float* __restrict__ Wr3,
                                                       const float* __restrict__ br3,
                                                       float* __restrict__ out) {
    __shared__ float red[256];
    __shared__ float lg[8];
    int t = threadIdx.x;
    float w3 = Wr3[t];
    for (int p = 0; p < 8; ++p) {
        red[t] = w3 * h2[p * 256 + t];
        __syncthreads();
        for (int off = 128; off > 0; off >>= 1) {
            if (t < off) red[t] += red[t + off];
            __syncthreads();
        }
        if (t == 0) lg[p] = red[0] + br3[0];
        __syncthreads();
    }
    if (t == 0) {
        float mx = lg[0];
        for (int p = 1; p < 8; ++p) mx = fmaxf(mx, lg[p]);
        float s = 0.f, e[8];
        for (int p = 0; p < 8; ++p) {
            e[p] = expf(lg[p] - mx);
            s += e[p];
        }
        for (int p = 0; p < 8; ++p) out[p] = e[p] / s;
    }
}

extern "C" void kernel_launch(void* const* d_in, const int* in_sizes, int n_in,
                              void* d_out, int out_size, void* d_ws, size_t ws_size,
                              hipStream_t stream) {
    const float* links_state = (const float*)d_in[0];
    const int* idm = (const int*)d_in[1];
    const int* idn = (const int*)d_in[2];
    const float* Wmsg = (const float*)d_in[3];
    const float* bmsg = (const float*)d_in[4];
    const float* Wih = (const float*)d_in[5];
    const float* Whh = (const float*)d_in[6];
    const float* bih = (const float*)d_in[7];
    const float* bhh = (const float*)d_in[8];
    const float* Wr1 = (const float*)d_in[9];
    const float* br1 = (const float*)d_in[10];
    const float* Wr2 = (const float*)d_in[11];
    const float* br2 = (const float*)d_in[12];
    const float* Wr3 = (const float*)d_in[13];
    const float* br3 = (const float*)d_in[14];

    const int N = in_sizes[0] / D;  // 50000
    const int E = in_sizes[1];      // 800000
    const int K = 8, T = 3;

    float* ws = (float*)d_ws;
    size_t nd = (size_t)N * D;
    float* cur = ws;
    float* y = ws + nd;
    float* z = ws + 2 * nd;
    float* kp = ws + 3 * nd;       // 512
    float* h2 = kp + 512;          // 2048
    int* ibase = (int*)(h2 + 2048);
    int* cnt = ibase;                  // N
    int* row_start = ibase + N;        // N+1
    int* cursor = ibase + 2 * N + 1;   // N
    int* csr_src = ibase + 3 * N + 1;  // E

    // CSR build (once per launch)
    hipMemsetAsync(cnt, 0, (size_t)N * sizeof(int), stream);
    hipMemsetAsync(cursor, 0, (size_t)N * sizeof(int), stream);
    count_kernel<<<dim3((E + 255) / 256), dim3(256), 0, stream>>>(idn, cnt, E);
    scan_kernel<<<dim3(1), dim3(1024), 0, stream>>>(cnt, row_start, N);
    fill_kernel<<<dim3((E + 255) / 256), dim3(256), 0, stream>>>(idm, idn, row_start, cursor,
                                                                 csr_src, E);

    hipMemcpyAsync(cur, links_state, nd * sizeof(float), hipMemcpyDeviceToDevice, stream);

    int nbTot = (N + NB - 1) / NB;         // 6250
    int gridA = (nbTot + 15) / 16;         // 391
    int gridB = (nbTot + 7) / 8;           // 782
    for (int t = 0; t < T; ++t) {
        yz_kernel<<<dim3(gridA), dim3(1024), 0, stream>>>(cur, Wmsg, y, z, N);
        step_kernel<<<dim3(gridB), dim3(512), 0, stream>>>(y, z, cur, bmsg, row_start,
                                                           csr_src, Wih, Whh, bih, bhh, N);
    }

    hipMemsetAsync(kp, 0, (size_t)K * 64 * sizeof(float), stream);
    pathsum_kernel<<<dim3(256), dim3(256), 0, stream>>>(cur, kp, N, K);
    readout1_kernel<<<dim3(8), dim3(256), 0, stream>>>(kp, Wr1, br1, Wr2, br2, h2);
    readout2_kernel<<<dim3(1), dim3(256), 0, stream>>>(h2, Wr3, br3, (float*)d_out);
}

// Round 7
// 966.572 us; speedup vs baseline: 1.0003x; 1.0003x over previous
//
#include <hip/hip_runtime.h>
#include <hip/hip_bf16.h>

#define D 64
#define NB 8      // nodes per wave-block
#define WPAD 68   // padded weight stride (floats), 16B-aligned, bank-spread

__device__ __forceinline__ float selu_f(float x) {
    const float SC = 1.0507009873554805f;
    const float AL = 1.6732632423543772f;
    return x > 0.f ? SC * x : SC * AL * (expf(x) - 1.f);
}
__device__ __forceinline__ float sigmoid_f(float x) { return 1.f / (1.f + expf(-x)); }
__device__ __forceinline__ float dot4(float4 a, float4 b, float acc) {
    acc = fmaf(a.x, b.x, acc);
    acc = fmaf(a.y, b.y, acc);
    acc = fmaf(a.z, b.z, acc);
    return fmaf(a.w, b.w, acc);
}

// ---- A: y = x@Wy^T, z = x@Wz^T (Wy = Wmsg[:,:64], Wz = Wmsg[:,64:]) ----
__global__ void __launch_bounds__(1024) yz_kernel(const float* __restrict__ x,
                                                  const float* __restrict__ Wmsg,
                                                  float* __restrict__ y,
                                                  float* __restrict__ z, int N) {
    __shared__ __align__(16) float wbuf[2 * 64 * WPAD];  // 34 KB
    __shared__ __align__(16) float xs[16 * NB * 64];     // 32 KB
    for (int idx = threadIdx.x; idx < 2 * 64 * 64; idx += 1024) {
        int g = idx >> 12, rem = idx & 4095;
        int d = rem >> 6, j = rem & 63;
        wbuf[g * 64 * WPAD + d * WPAD + j] = Wmsg[d * 128 + g * 64 + j];
    }
    __syncthreads();
    int lane = threadIdx.x & 63;
    int w = threadIdx.x >> 6;
    float* xw = &xs[w * (NB * 64)];
    const float* wy = wbuf;
    const float* wz = wbuf + 64 * WPAD;
    int nbTot = (N + NB - 1) / NB;
    for (int nb = blockIdx.x * 16 + w; nb < nbTot; nb += gridDim.x * 16) {
        int n0 = nb * NB;
#pragma unroll
        for (int n = 0; n < NB; ++n) {
            int i = n0 + n;
            xw[n * 64 + lane] = (i < N) ? x[(size_t)i * 64 + lane] : 0.f;
        }
        float accy[NB], accz[NB];
#pragma unroll
        for (int n = 0; n < NB; ++n) { accy[n] = 0.f; accz[n] = 0.f; }
#pragma unroll 1
        for (int jg = 0; jg < 16; ++jg) {
            float4 wyv = *(const float4*)&wy[lane * WPAD + jg * 4];
            float4 wzv = *(const float4*)&wz[lane * WPAD + jg * 4];
#pragma unroll
            for (int n = 0; n < NB; ++n) {
                float4 xv = *(const float4*)&xw[n * 64 + jg * 4];  // uniform: broadcast
                accy[n] = dot4(wyv, xv, accy[n]);
                accz[n] = dot4(wzv, xv, accz[n]);
            }
        }
#pragma unroll
        for (int n = 0; n < NB; ++n) {
            int i = n0 + n;
            if (i < N) {
                y[(size_t)i * 64 + lane] = accy[n];
                z[(size_t)i * 64 + lane] = accz[n];
            }
        }
    }
}

// ---- CSR build ----
__global__ void __launch_bounds__(256) count_kernel(const int* __restrict__ idn,
                                                    int* __restrict__ cnt, int E) {
    int i = blockIdx.x * blockDim.x + threadIdx.x;
    if (i < E) atomicAdd(&cnt[idn[i]], 1);
}

__global__ void __launch_bounds__(1024) scan_kernel(const int* __restrict__ cnt,
                                                    int* __restrict__ row_start, int N) {
    __shared__ int part[1024];
    int t = threadIdx.x;
    int chunk = (N + 1023) / 1024;
    int lo = t * chunk;
    int hi = lo + chunk < N ? lo + chunk : N;
    int s = 0;
    for (int i = lo; i < hi; ++i) s += cnt[i];
    part[t] = s;
    __syncthreads();
    for (int off = 1; off < 1024; off <<= 1) {
        int v = part[t];
        int u = (t >= off) ? part[t - off] : 0;
        __syncthreads();
        part[t] = v + u;
        __syncthreads();
    }
    int excl = (t == 0) ? 0 : part[t - 1];
    for (int i = lo; i < hi; ++i) {
        row_start[i] = excl;
        excl += cnt[i];
    }
    if (t == 1023) row_start[N] = part[1023];
}

__global__ void __launch_bounds__(256) fill_kernel(const int* __restrict__ idm,
                                                   const int* __restrict__ idn,
                                                   const int* __restrict__ row_start,
                                                   int* __restrict__ cursor,
                                                   int* __restrict__ csr_src, int E) {
    int i = blockIdx.x * blockDim.x + threadIdx.x;
    if (i < E) {
        int n = idn[i];
        int p = atomicAdd(&cursor[n], 1);
        csr_src[row_start[n] + p] = idm[i];
    }
}

// ---- B: gather+selu -> M ; gi = M@Wih^T ; gh = h@Whh^T ; GRU combine ----
__global__ void __launch_bounds__(512) void_step_guard();  // (unused decl guard)
__global__ void __launch_bounds__(512) step_kernel(
    const float* __restrict__ y, const float* __restrict__ z,
    float* __restrict__ cur, const float* __restrict__ bmsg,
    const int* __restrict__ row_start, const int* __restrict__ csr_src,
    const float* __restrict__ Wih, const float* __restrict__ Whh,
    const float* __restrict__ bih, const float* __restrict__ bhh, int N) {
    __shared__ __align__(16) float wbuf[6 * 64 * WPAD];  // 104.4 KB
    __shared__ __align__(16) float xsM[8 * NB * 64];     // 16 KB
    __shared__ __align__(16) float xsH[8 * NB * 64];     // 16 KB
    for (int idx = threadIdx.x; idx < 6 * 64 * 64; idx += 512) {
        int g = idx >> 12, rem = idx & 4095;
        int d = rem >> 6, j = rem & 63;
        const float* src = (g < 3) ? Wih : Whh;
        int gg = (g < 3) ? g : g - 3;
        wbuf[g * 64 * WPAD + d * WPAD + j] = src[(gg * 64 + d) * 64 + j];
    }
    __syncthreads();
    int lane = threadIdx.x & 63;
    int w = threadIdx.x >> 6;
    float* xm = &xsM[w * (NB * 64)];
    float* xh = &xsH[w * (NB * 64)];
    const float* wir = wbuf + 0 * 64 * WPAD;
    const float* wiz = wbuf + 1 * 64 * WPAD;
    const float* win = wbuf + 2 * 64 * WPAD;
    const float* whr = wbuf + 3 * 64 * WPAD;
    const float* whz = wbuf + 4 * 64 * WPAD;
    const float* whn = wbuf + 5 * 64 * WPAD;
    float b = bmsg[lane];
    float bir = bih[lane], biz = bih[64 + lane], bin_ = bih[128 + lane];
    float bhr = bhh[lane], bhz = bhh[64 + lane], bhn = bhh[128 + lane];
    int nbTot = (N + NB - 1) / NB;
    for (int nb = blockIdx.x * 8 + w; nb < nbTot; nb += gridDim.x * 8) {
        int n0 = nb * NB;
        float hv[NB];
#pragma unroll
        for (int n = 0; n < NB; ++n) {
            int i = n0 + n;
            hv[n] = (i < N) ? cur[(size_t)i * 64 + lane] : 0.f;
            xh[n * 64 + lane] = hv[n];
        }
#pragma unroll
        for (int n = 0; n < NB; ++n) {
            int i = n0 + n;
            float macc = 0.f;
            if (i < N) {
                float zb = z[(size_t)i * 64 + lane] + b;
                int s0 = row_start[i], s1 = row_start[i + 1];
                int s = s0;
                for (; s + 4 <= s1; s += 4) {
                    int e0 = csr_src[s], e1 = csr_src[s + 1];
                    int e2 = csr_src[s + 2], e3 = csr_src[s + 3];
                    float v0 = y[(size_t)e0 * 64 + lane];
                    float v1 = y[(size_t)e1 * 64 + lane];
                    float v2 = y[(size_t)e2 * 64 + lane];
                    float v3 = y[(size_t)e3 * 64 + lane];
                    macc += selu_f(v0 + zb);
                    macc += selu_f(v1 + zb);
                    macc += selu_f(v2 + zb);
                    macc += selu_f(v3 + zb);
                }
                for (; s < s1; ++s) macc += selu_f(y[(size_t)csr_src[s] * 64 + lane] + zb);
            }
            xm[n * 64 + lane] = macc;
        }
        float air[NB], aiz[NB], ain[NB], ahr[NB], ahz[NB], ahn[NB];
#pragma unroll
        for (int n = 0; n < NB; ++n) {
            air[n] = 0.f; aiz[n] = 0.f; ain[n] = 0.f;
            ahr[n] = 0.f; ahz[n] = 0.f; ahn[n] = 0.f;
        }
#pragma unroll 1
        for (int jg = 0; jg < 16; ++jg) {
            float4 wirv = *(const float4*)&wir[lane * WPAD + jg * 4];
            float4 wizv = *(const float4*)&wiz[lane * WPAD + jg * 4];
            float4 winv = *(const float4*)&win[lane * WPAD + jg * 4];
            float4 whrv = *(const float4*)&whr[lane * WPAD + jg * 4];
            float4 whzv = *(const float4*)&whz[lane * WPAD + jg * 4];
            float4 whnv = *(const float4*)&whn[lane * WPAD + jg * 4];
#pragma unroll
            for (int n = 0; n < NB; ++n) {
                float4 m4 = *(const float4*)&xm[n * 64 + jg * 4];  // uniform broadcast
                float4 h4 = *(const float4*)&xh[n * 64 + jg * 4];
                air[n] = dot4(wirv, m4, air[n]);
                aiz[n] = dot4(wizv, m4, aiz[n]);
                ain[n] = dot4(winv, m4, ain[n]);
                ahr[n] = dot4(whrv, h4, ahr[n]);
                ahz[n] = dot4(whzv, h4, ahz[n]);
                ahn[n] = dot4(whnv, h4, ahn[n]);
            }
        }
#pragma unroll
        for (int n = 0; n < NB; ++n) {
            int i = n0 + n;
            if (i < N) {
                float r = sigmoid_f(air[n] + bir + ahr[n] + bhr);
                float zg = sigmoid_f(aiz[n] + biz + ahz[n] + bhz);
                float nn = tanhf(ain[n] + bin_ + r * (ahn[n] + bhn));
                cur[(size_t)i * 64 + lane] = (1.f - zg) * nn + zg * hv[n];
            }
        }
    }
}

__global__ void __launch_bounds__(256) pathsum_kernel(const float* __restrict__ h,
                                                      float* __restrict__ kp, int N, int K) {
    int per = N / K;
    int blocksPerPath = gridDim.x / K;
    int p = blockIdx.x / blocksPerPath;
    int c = blockIdx.x % blocksPerPath;
    int d = threadIdx.x & 63;
    int row0 = c * (blockDim.x >> 6) + (threadIdx.x >> 6);
    int stride = blocksPerPath * (blockDim.x >> 6);
    float acc = 0.f;
    for (int r = row0; r < per; r += stride) acc += h[((size_t)p * per + r) * 64 + d];
    __shared__ float red[256];
    red[threadIdx.x] = acc;
    __syncthreads();
    if (threadIdx.x < 64) {
        float s = red[threadIdx.x] + red[64 + threadIdx.x] + red[128 + threadIdx.x] +
                  red[192 + threadIdx.x];
        atomicAdd(&kp[p * 64 + threadIdx.x], s);
    }
}

// 8 blocks, one per path: h1 = selu(kp@Wr1^T+br1); h2 = selu(h1@Wr2^T+br2)
__global__ void __launch_bounds__(256) readout1_kernel(const float* __restrict__ kp,
                                                       const float* __restrict__ Wr1,
                                                       const float* __restrict__ br1,
                                                       const float* __restrict__ Wr2,
                                                       const float* __restrict__ br2,
                                                       float* __restrict__ h2) {
    int p = blockIdx.x;
    int t = threadIdx.x;
    __shared__ __align__(16) float kps[64];
    __shared__ __align__(16) float h1[256];
    if (t < 64) kps[t] = kp[p * 64 + t];
    __syncthreads();
    float acc = br1[t];
#pragma unroll
    for (int d4 = 0; d4 < 16; ++d4) {
        float4 wv = *(const float4*)&Wr1[t * 64 + d4 * 4];
        float4 kv = *(const float4*)&kps[d4 * 4];
        acc = dot4(wv, kv, acc);
    }
    h1[t] = selu_f(acc);
    __syncthreads();
    float acc2 = br2[t];
#pragma unroll 8
    for (int j4 = 0; j4 < 64; ++j4) {
        float4 wv = *(const float4*)&Wr2[t * 256 + j4 * 4];
        float4 hv = *(const float4*)&h1[j4 * 4];
        acc2 = dot4(wv, hv, acc2);
    }
    h2[p * 256 + t] = selu_f(acc2);
}

__global__ void __launch_bounds__(256) readout2_kernel(const float* __restrict__ h2,
                                                       const float* __restrict__ Wr3,
                                                       const float* __restrict__ br3,
                                                       float* __restrict__ out) {
    __shared__ float red[256];
    __shared__ float lg[8];
    int t = threadIdx.x;
    float w3 = Wr3[t];
    for (int p = 0; p < 8; ++p) {
        red[t] = w3 * h2[p * 256 + t];
        __syncthreads();
        for (int off = 128; off > 0; off >>= 1) {
            if (t < off) red[t] += red[t + off];
            __syncthreads();
        }
        if (t == 0) lg[p] = red[0] + br3[0];
        __syncthreads();
    }
    if (t == 0) {
        float mx = lg[0];
        for (int p = 1; p < 8; ++p) mx = fmaxf(mx, lg[p]);
        float s = 0.f, e[8];
        for (int p = 0; p < 8; ++p) {
            e[p] = expf(lg[p] - mx);
            s += e[p];
        }
        for (int p = 0; p < 8; ++p) out[p] = e[p] / s;
    }
}

extern "C" void kernel_launch(void* const* d_in, const int* in_sizes, int n_in,
                              void* d_out, int out_size, void* d_ws, size_t ws_size,
                              hipStream_t stream) {
    const float* links_state = (const float*)d_in[0];
    const int* idm = (const int*)d_in[1];
    const int* idn = (const int*)d_in[2];
    const float* Wmsg = (const float*)d_in[3];
    const float* bmsg = (const float*)d_in[4];
    const float* Wih = (const float*)d_in[5];
    const float* Whh = (const float*)d_in[6];
    const float* bih = (const float*)d_in[7];
    const float* bhh = (const float*)d_in[8];
    const float* Wr1 = (const float*)d_in[9];
    const float* br1 = (const float*)d_in[10];
    const float* Wr2 = (const float*)d_in[11];
    const float* br2 = (const float*)d_in[12];
    const float* Wr3 = (const float*)d_in[13];
    const float* br3 = (const float*)d_in[14];

    const int N = in_sizes[0] / D;  // 50000
    const int E = in_sizes[1];      // 800000
    const int K = 8, T = 3;

    float* ws = (float*)d_ws;
    size_t nd = (size_t)N * D;
    float* cur = ws;
    float* y = ws + nd;
    float* z = ws + 2 * nd;
    float* kp = ws + 3 * nd;       // 512
    float* h2 = kp + 512;          // 2048
    int* ibase = (int*)(h2 + 2048);
    int* cnt = ibase;                  // N
    int* row_start = ibase + N;        // N+1
    int* cursor = ibase + 2 * N + 1;   // N
    int* csr_src = ibase + 3 * N + 1;  // E

    // CSR build (once per launch)
    hipMemsetAsync(cnt, 0, (size_t)N * sizeof(int), stream);
    hipMemsetAsync(cursor, 0, (size_t)N * sizeof(int), stream);
    count_kernel<<<dim3((E + 255) / 256), dim3(256), 0, stream>>>(idn, cnt, E);
    scan_kernel<<<dim3(1), dim3(1024), 0, stream>>>(cnt, row_start, N);
    fill_kernel<<<dim3((E + 255) / 256), dim3(256), 0, stream>>>(idm, idn, row_start, cursor,
                                                                 csr_src, E);

    hipMemcpyAsync(cur, links_state, nd * sizeof(float), hipMemcpyDeviceToDevice, stream);

    int nbTot = (N + NB - 1) / NB;         // 6250
    int gridA = (nbTot + 15) / 16;         // 391
    int gridB = (nbTot + 7) / 8;           // 782
    for (int t = 0; t < T; ++t) {
        yz_kernel<<<dim3(gridA), dim3(1024), 0, stream>>>(cur, Wmsg, y, z, N);
        step_kernel<<<dim3(gridB), dim3(512), 0, stream>>>(y, z, cur, bmsg, row_start,
                                                           csr_src, Wih, Whh, bih, bhh, N);
    }

    hipMemsetAsync(kp, 0, (size_t)K * 64 * sizeof(float), stream);
    pathsum_kernel<<<dim3(256), dim3(256), 0, stream>>>(cur, kp, N, K);
    readout1_kernel<<<dim3(8), dim3(256), 0, stream>>>(kp, Wr1, br1, Wr2, br2, h2);
    readout2_kernel<<<dim3(1), dim3(256), 0, stream>>>(h2, Wr3, br3, (float*)d_out);
}

// Round 8
// 966.127 us; speedup vs baseline: 1.0008x; 1.0005x over previous
//
#include <hip/hip_runtime.h>
#include <hip/hip_bf16.h>

#define D 64
#define NB 8      // nodes per wave-block
#define WPAD 68   // padded weight stride (floats), 16B-aligned, bank-spread

__device__ __forceinline__ float selu_f(float x) {
    const float SC = 1.0507009873554805f;
    const float AL = 1.6732632423543772f;
    return x > 0.f ? SC * x : SC * AL * (expf(x) - 1.f);
}
__device__ __forceinline__ float sigmoid_f(float x) { return 1.f / (1.f + expf(-x)); }
__device__ __forceinline__ float dot4(float4 a, float4 b, float acc) {
    acc = fmaf(a.x, b.x, acc);
    acc = fmaf(a.y, b.y, acc);
    acc = fmaf(a.z, b.z, acc);
    return fmaf(a.w, b.w, acc);
}

// ---- A: y = x@Wy^T, z = x@Wz^T (Wy = Wmsg[:,:64], Wz = Wmsg[:,64:]) ----
__global__ void __launch_bounds__(1024) yz_kernel(const float* __restrict__ x,
                                                  const float* __restrict__ Wmsg,
                                                  float* __restrict__ y,
                                                  float* __restrict__ z, int N) {
    __shared__ __align__(16) float wbuf[2 * 64 * WPAD];  // 34 KB
    __shared__ __align__(16) float xs[16 * NB * 64];     // 32 KB
    for (int idx = threadIdx.x; idx < 2 * 64 * 64; idx += 1024) {
        int g = idx >> 12, rem = idx & 4095;
        int d = rem >> 6, j = rem & 63;
        wbuf[g * 64 * WPAD + d * WPAD + j] = Wmsg[d * 128 + g * 64 + j];
    }
    __syncthreads();
    int lane = threadIdx.x & 63;
    int w = threadIdx.x >> 6;
    float* xw = &xs[w * (NB * 64)];
    const float* wy = wbuf;
    const float* wz = wbuf + 64 * WPAD;
    int nbTot = (N + NB - 1) / NB;
    for (int nb = blockIdx.x * 16 + w; nb < nbTot; nb += gridDim.x * 16) {
        int n0 = nb * NB;
#pragma unroll
        for (int n = 0; n < NB; ++n) {
            int i = n0 + n;
            xw[n * 64 + lane] = (i < N) ? x[(size_t)i * 64 + lane] : 0.f;
        }
        float accy[NB], accz[NB];
#pragma unroll
        for (int n = 0; n < NB; ++n) { accy[n] = 0.f; accz[n] = 0.f; }
#pragma unroll 1
        for (int jg = 0; jg < 16; ++jg) {
            float4 wyv = *(const float4*)&wy[lane * WPAD + jg * 4];
            float4 wzv = *(const float4*)&wz[lane * WPAD + jg * 4];
#pragma unroll
            for (int n = 0; n < NB; ++n) {
                float4 xv = *(const float4*)&xw[n * 64 + jg * 4];  // uniform: broadcast
                accy[n] = dot4(wyv, xv, accy[n]);
                accz[n] = dot4(wzv, xv, accz[n]);
            }
        }
#pragma unroll
        for (int n = 0; n < NB; ++n) {
            int i = n0 + n;
            if (i < N) {
                y[(size_t)i * 64 + lane] = accy[n];
                z[(size_t)i * 64 + lane] = accz[n];
            }
        }
    }
}

// ---- CSR build ----
__global__ void __launch_bounds__(256) count_kernel(const int* __restrict__ idn,
                                                    int* __restrict__ cnt, int E) {
    int i = blockIdx.x * blockDim.x + threadIdx.x;
    if (i < E) atomicAdd(&cnt[idn[i]], 1);
}

__global__ void __launch_bounds__(1024) scan_kernel(const int* __restrict__ cnt,
                                                    int* __restrict__ row_start, int N) {
    __shared__ int part[1024];
    int t = threadIdx.x;
    int chunk = (N + 1023) / 1024;
    int lo = t * chunk;
    int hi = lo + chunk < N ? lo + chunk : N;
    int s = 0;
    for (int i = lo; i < hi; ++i) s += cnt[i];
    part[t] = s;
    __syncthreads();
    for (int off = 1; off < 1024; off <<= 1) {
        int v = part[t];
        int u = (t >= off) ? part[t - off] : 0;
        __syncthreads();
        part[t] = v + u;
        __syncthreads();
    }
    int excl = (t == 0) ? 0 : part[t - 1];
    for (int i = lo; i < hi; ++i) {
        row_start[i] = excl;
        excl += cnt[i];
    }
    if (t == 1023) row_start[N] = part[1023];
}

__global__ void __launch_bounds__(256) fill_kernel(const int* __restrict__ idm,
                                                   const int* __restrict__ idn,
                                                   const int* __restrict__ row_start,
                                                   int* __restrict__ cursor,
                                                   int* __restrict__ csr_src, int E) {
    int i = blockIdx.x * blockDim.x + threadIdx.x;
    if (i < E) {
        int n = idn[i];
        int p = atomicAdd(&cursor[n], 1);
        csr_src[row_start[n] + p] = idm[i];
    }
}

// ---- B: gather+selu -> M ; gi = M@Wih^T ; gh = h@Whh^T ; GRU combine ----
__global__ void __launch_bounds__(512) void_step_guard();  // (unused decl guard)
__global__ void __launch_bounds__(512) step_kernel(
    const float* __restrict__ y, const float* __restrict__ z,
    float* __restrict__ cur, const float* __restrict__ bmsg,
    const int* __restrict__ row_start, const int* __restrict__ csr_src,
    const float* __restrict__ Wih, const float* __restrict__ Whh,
    const float* __restrict__ bih, const float* __restrict__ bhh, int N) {
    __shared__ __align__(16) float wbuf[6 * 64 * WPAD];  // 104.4 KB
    __shared__ __align__(16) float xsM[8 * NB * 64];     // 16 KB
    __shared__ __align__(16) float xsH[8 * NB * 64];     // 16 KB
    for (int idx = threadIdx.x; idx < 6 * 64 * 64; idx += 512) {
        int g = idx >> 12, rem = idx & 4095;
        int d = rem >> 6, j = rem & 63;
        const float* src = (g < 3) ? Wih : Whh;
        int gg = (g < 3) ? g : g - 3;
        wbuf[g * 64 * WPAD + d * WPAD + j] = src[(gg * 64 + d) * 64 + j];
    }
    __syncthreads();
    int lane = threadIdx.x & 63;
    int w = threadIdx.x >> 6;
    float* xm = &xsM[w * (NB * 64)];
    float* xh = &xsH[w * (NB * 64)];
    const float* wir = wbuf + 0 * 64 * WPAD;
    const float* wiz = wbuf + 1 * 64 * WPAD;
    const float* win = wbuf + 2 * 64 * WPAD;
    const float* whr = wbuf + 3 * 64 * WPAD;
    const float* whz = wbuf + 4 * 64 * WPAD;
    const float* whn = wbuf + 5 * 64 * WPAD;
    float b = bmsg[lane];
    float bir = bih[lane], biz = bih[64 + lane], bin_ = bih[128 + lane];
    float bhr = bhh[lane], bhz = bhh[64 + lane], bhn = bhh[128 + lane];
    int nbTot = (N + NB - 1) / NB;
    for (int nb = blockIdx.x * 8 + w; nb < nbTot; nb += gridDim.x * 8) {
        int n0 = nb * NB;
        float hv[NB];
#pragma unroll
        for (int n = 0; n < NB; ++n) {
            int i = n0 + n;
            hv[n] = (i < N) ? cur[(size_t)i * 64 + lane] : 0.f;
            xh[n * 64 + lane] = hv[n];
        }
#pragma unroll
        for (int n = 0; n < NB; ++n) {
            int i = n0 + n;
            float macc = 0.f;
            if (i < N) {
                float zb = z[(size_t)i * 64 + lane] + b;
                int s0 = row_start[i], s1 = row_start[i + 1];
                int s = s0;
                for (; s + 4 <= s1; s += 4) {
                    int e0 = csr_src[s], e1 = csr_src[s + 1];
                    int e2 = csr_src[s + 2], e3 = csr_src[s + 3];
                    float v0 = y[(size_t)e0 * 64 + lane];
                    float v1 = y[(size_t)e1 * 64 + lane];
                    float v2 = y[(size_t)e2 * 64 + lane];
                    float v3 = y[(size_t)e3 * 64 + lane];
                    macc += selu_f(v0 + zb);
                    macc += selu_f(v1 + zb);
                    macc += selu_f(v2 + zb);
                    macc += selu_f(v3 + zb);
                }
                for (; s < s1; ++s) macc += selu_f(y[(size_t)csr_src[s] * 64 + lane] + zb);
            }
            xm[n * 64 + lane] = macc;
        }
        float air[NB], aiz[NB], ain[NB], ahr[NB], ahz[NB], ahn[NB];
#pragma unroll
        for (int n = 0; n < NB; ++n) {
            air[n] = 0.f; aiz[n] = 0.f; ain[n] = 0.f;
            ahr[n] = 0.f; ahz[n] = 0.f; ahn[n] = 0.f;
        }
#pragma unroll 1
        for (int jg = 0; jg < 16; ++jg) {
            float4 wirv = *(const float4*)&wir[lane * WPAD + jg * 4];
            float4 wizv = *(const float4*)&wiz[lane * WPAD + jg * 4];
            float4 winv = *(const float4*)&win[lane * WPAD + jg * 4];
            float4 whrv = *(const float4*)&whr[lane * WPAD + jg * 4];
            float4 whzv = *(const float4*)&whz[lane * WPAD + jg * 4];
            float4 whnv = *(const float4*)&whn[lane * WPAD + jg * 4];
#pragma unroll
            for (int n = 0; n < NB; ++n) {
                float4 m4 = *(const float4*)&xm[n * 64 + jg * 4];  // uniform broadcast
                float4 h4 = *(const float4*)&xh[n * 64 + jg * 4];
                air[n] = dot4(wirv, m4, air[n]);
                aiz[n] = dot4(wizv, m4, aiz[n]);
                ain[n] = dot4(winv, m4, ain[n]);
                ahr[n] = dot4(whrv, h4, ahr[n]);
                ahz[n] = dot4(whzv, h4, ahz[n]);
                ahn[n] = dot4(whnv, h4, ahn[n]);
            }
        }
#pragma unroll
        for (int n = 0; n < NB; ++n) {
            int i = n0 + n;
            if (i < N) {
                float r = sigmoid_f(air[n] + bir + ahr[n] + bhr);
                float zg = sigmoid_f(aiz[n] + biz + ahz[n] + bhz);
                float nn = tanhf(ain[n] + bin_ + r * (ahn[n] + bhn));
                cur[(size_t)i * 64 + lane] = (1.f - zg) * nn + zg * hv[n];
            }
        }
    }
}

__global__ void __launch_bounds__(256) pathsum_kernel(const float* __restrict__ h,
                                                      float* __restrict__ kp, int N, int K) {
    int per = N / K;
    int blocksPerPath = gridDim.x / K;
    int p = blockIdx.x / blocksPerPath;
    int c = blockIdx.x % blocksPerPath;
    int d = threadIdx.x & 63;
    int row0 = c * (blockDim.x >> 6) + (threadIdx.x >> 6);
    int stride = blocksPerPath * (blockDim.x >> 6);
    float acc = 0.f;
    for (int r = row0; r < per; r += stride) acc += h[((size_t)p * per + r) * 64 + d];
    __shared__ float red[256];
    red[threadIdx.x] = acc;
    __syncthreads();
    if (threadIdx.x < 64) {
        float s = red[threadIdx.x] + red[64 + threadIdx.x] + red[128 + threadIdx.x] +
                  red[192 + threadIdx.x];
        atomicAdd(&kp[p * 64 + threadIdx.x], s);
    }
}

// 8 blocks, one per path: h1 = selu(kp@Wr1^T+br1); h2 = selu(h1@Wr2^T+br2)
__global__ void __launch_bounds__(256) readout1_kernel(const float* __restrict__ kp,
                                                       const float* __restrict__ Wr1,
                                                       const float* __restrict__ br1,
                                                       const float* __restrict__ Wr2,
                                                       const float* __restrict__ br2,
                                                       float* __restrict__ h2) {
    int p = blockIdx.x;
    int t = threadIdx.x;
    __shared__ __align__(16) float kps[64];
    __shared__ __align__(16) float h1[256];
    if (t < 64) kps[t] = kp[p * 64 + t];
    __syncthreads();
    float acc = br1[t];
#pragma unroll
    for (int d4 = 0; d4 < 16; ++d4) {
        float4 wv = *(const float4*)&Wr1[t * 64 + d4 * 4];
        float4 kv = *(const float4*)&kps[d4 * 4];
        acc = dot4(wv, kv, acc);
    }
    h1[t] = selu_f(acc);
    __syncthreads();
    float acc2 = br2[t];
#pragma unroll 8
    for (int j4 = 0; j4 < 64; ++j4) {
        float4 wv = *(const float4*)&Wr2[t * 256 + j4 * 4];
        float4 hv = *(const float4*)&h1[j4 * 4];
        acc2 = dot4(wv, hv, acc2);
    }
    h2[p * 256 + t] = selu_f(acc2);
}

__global__ void __launch_bounds__(256) readout2_kernel(const float* __restrict__ h2,
                                                       const float* __restrict__ Wr3,
                                                       const float* __restrict__ br3,
                                                       float* __restrict__ out) {
    __shared__ float red[256];
    __shared__ float lg[8];
    int t = threadIdx.x;
    float w3 = Wr3[t];
    for (int p = 0; p < 8; ++p) {
        red[t] = w3 * h2[p * 256 + t];
        __syncthreads();
        for (int off = 128; off > 0; off >>= 1) {
            if (t < off) red[t] += red[t + off];
            __syncthreads();
        }
        if (t == 0) lg[p] = red[0] + br3[0];
        __syncthreads();
    }
    if (t == 0) {
        float mx = lg[0];
        for (int p = 1; p < 8; ++p) mx = fmaxf(mx, lg[p]);
        float s = 0.f, e[8];
        for (int p = 0; p < 8; ++p) {
            e[p] = expf(lg[p] - mx);
            s += e[p];
        }
        for (int p = 0; p < 8; ++p) out[p] = e[p] / s;
    }
}

extern "C" void kernel_launch(void* const* d_in, const int* in_sizes, int n_in,
                              void* d_out, int out_size, void* d_ws, size_t ws_size,
                              hipStream_t stream) {
    const float* links_state = (const float*)d_in[0];
    const int* idm = (const int*)d_in[1];
    const int* idn = (const int*)d_in[2];
    const float* Wmsg = (const float*)d_in[3];
    const float* bmsg = (const float*)d_in[4];
    const float* Wih = (const float*)d_in[5];
    const float* Whh = (const float*)d_in[6];
    const float* bih = (const float*)d_in[7];
    const float* bhh = (const float*)d_in[8];
    const float* Wr1 = (const float*)d_in[9];
    const float* br1 = (const float*)d_in[10];
    const float* Wr2 = (const float*)d_in[11];
    const float* br2 = (const float*)d_in[12];
    const float* Wr3 = (const float*)d_in[13];
    const float* br3 = (const float*)d_in[14];

    const int N = in_sizes[0] / D;  // 50000
    const int E = in_sizes[1];      // 800000
    const int K = 8, T = 3;

    float* ws = (float*)d_ws;
    size_t nd = (size_t)N * D;
    float* cur = ws;
    float* y = ws + nd;
    float* z = ws + 2 * nd;
    float* kp = ws + 3 * nd;       // 512
    float* h2 = kp + 512;          // 2048
    int* ibase = (int*)(h2 + 2048);
    int* cnt = ibase;                  // N
    int* row_start = ibase + N;        // N+1
    int* cursor = ibase + 2 * N + 1;   // N
    int* csr_src = ibase + 3 * N + 1;  // E

    // CSR build (once per launch)
    hipMemsetAsync(cnt, 0, (size_t)N * sizeof(int), stream);
    hipMemsetAsync(cursor, 0, (size_t)N * sizeof(int), stream);
    count_kernel<<<dim3((E + 255) / 256), dim3(256), 0, stream>>>(idn, cnt, E);
    scan_kernel<<<dim3(1), dim3(1024), 0, stream>>>(cnt, row_start, N);
    fill_kernel<<<dim3((E + 255) / 256), dim3(256), 0, stream>>>(idm, idn, row_start, cursor,
                                                                 csr_src, E);

    hipMemcpyAsync(cur, links_state, nd * sizeof(float), hipMemcpyDeviceToDevice, stream);

    int nbTot = (N + NB - 1) / NB;         // 6250
    int gridA = (nbTot + 15) / 16;         // 391
    int gridB = (nbTot + 7) / 8;           // 782
    for (int t = 0; t < T; ++t) {
        yz_kernel<<<dim3(gridA), dim3(1024), 0, stream>>>(cur, Wmsg, y, z, N);
        step_kernel<<<dim3(gridB), dim3(512), 0, stream>>>(y, z, cur, bmsg, row_start,
                                                           csr_src, Wih, Whh, bih, bhh, N);
    }

    hipMemsetAsync(kp, 0, (size_t)K * 64 * sizeof(float), stream);
    pathsum_kernel<<<dim3(256), dim3(256), 0, stream>>>(cur, kp, N, K);
    readout1_kernel<<<dim3(8), dim3(256), 0, stream>>>(kp, Wr1, br1, Wr2, br2, h2);
    readout2_kernel<<<dim3(1), dim3(256), 0, stream>>>(h2, Wr3, br3, (float*)d_out);
}

// Round 9
// 709.260 us; speedup vs baseline: 1.3632x; 1.3622x over previous
//
#include <hip/hip_runtime.h>
#include <hip/hip_bf16.h>

#define D 64
#define NB 8      // nodes per wave-block
#define WPAD 68   // padded weight stride (floats), 16B-aligned, bank-spread

__device__ __forceinline__ float selu_f(float x) {
    const float SC = 1.0507009873554805f;
    const float AL = 1.6732632423543772f;
    return x > 0.f ? SC * x : SC * AL * (expf(x) - 1.f);
}
__device__ __forceinline__ float sigmoid_f(float x) { return 1.f / (1.f + expf(-x)); }
__device__ __forceinline__ float dot4(float4 a, float4 b, float acc) {
    acc = fmaf(a.x, b.x, acc);
    acc = fmaf(a.y, b.y, acc);
    acc = fmaf(a.z, b.z, acc);
    return fmaf(a.w, b.w, acc);
}

// ---- A: y = x@Wy^T, z = x@Wz^T (Wy = Wmsg[:,:64], Wz = Wmsg[:,64:]) ----
__global__ void __launch_bounds__(1024) yz_kernel(const float* __restrict__ x,
                                                  const float* __restrict__ Wmsg,
                                                  float* __restrict__ y,
                                                  float* __restrict__ z, int N) {
    __shared__ __align__(16) float wbuf[2 * 64 * WPAD];  // 34 KB
    __shared__ __align__(16) float xs[16 * NB * 64];     // 32 KB
    for (int idx = threadIdx.x; idx < 2 * 64 * 64; idx += 1024) {
        int g = idx >> 12, rem = idx & 4095;
        int d = rem >> 6, j = rem & 63;
        wbuf[g * 64 * WPAD + d * WPAD + j] = Wmsg[d * 128 + g * 64 + j];
    }
    __syncthreads();
    int lane = threadIdx.x & 63;
    int w = threadIdx.x >> 6;
    float* xw = &xs[w * (NB * 64)];
    const float* wy = wbuf;
    const float* wz = wbuf + 64 * WPAD;
    int nbTot = (N + NB - 1) / NB;
    for (int nb = blockIdx.x * 16 + w; nb < nbTot; nb += gridDim.x * 16) {
        int n0 = nb * NB;
#pragma unroll
        for (int n = 0; n < NB; ++n) {
            int i = n0 + n;
            xw[n * 64 + lane] = (i < N) ? x[(size_t)i * 64 + lane] : 0.f;
        }
        float accy[NB], accz[NB];
#pragma unroll
        for (int n = 0; n < NB; ++n) { accy[n] = 0.f; accz[n] = 0.f; }
#pragma unroll 1
        for (int jg = 0; jg < 16; ++jg) {
            float4 wyv = *(const float4*)&wy[lane * WPAD + jg * 4];
            float4 wzv = *(const float4*)&wz[lane * WPAD + jg * 4];
#pragma unroll
            for (int n = 0; n < NB; ++n) {
                float4 xv = *(const float4*)&xw[n * 64 + jg * 4];  // uniform: broadcast
                accy[n] = dot4(wyv, xv, accy[n]);
                accz[n] = dot4(wzv, xv, accz[n]);
            }
        }
#pragma unroll
        for (int n = 0; n < NB; ++n) {
            int i = n0 + n;
            if (i < N) {
                y[(size_t)i * 64 + lane] = accy[n];
                z[(size_t)i * 64 + lane] = accz[n];
            }
        }
    }
}

// ---- CSR build ----
__global__ void __launch_bounds__(256) count_kernel(const int* __restrict__ idn,
                                                    int* __restrict__ cnt, int E) {
    int i = blockIdx.x * blockDim.x + threadIdx.x;
    if (i < E) atomicAdd(&cnt[idn[i]], 1);
}

__global__ void __launch_bounds__(1024) scan_kernel(const int* __restrict__ cnt,
                                                    int* __restrict__ row_start, int N) {
    __shared__ int part[1024];
    int t = threadIdx.x;
    int chunk = (N + 1023) / 1024;
    int lo = t * chunk;
    int hi = lo + chunk < N ? lo + chunk : N;
    int s = 0;
    for (int i = lo; i < hi; ++i) s += cnt[i];
    part[t] = s;
    __syncthreads();
    for (int off = 1; off < 1024; off <<= 1) {
        int v = part[t];
        int u = (t >= off) ? part[t - off] : 0;
        __syncthreads();
        part[t] = v + u;
        __syncthreads();
    }
    int excl = (t == 0) ? 0 : part[t - 1];
    for (int i = lo; i < hi; ++i) {
        row_start[i] = excl;
        excl += cnt[i];
    }
    if (t == 1023) row_start[N] = part[1023];
}

__global__ void __launch_bounds__(256) fill_kernel(const int* __restrict__ idm,
                                                   const int* __restrict__ idn,
                                                   const int* __restrict__ row_start,
                                                   int* __restrict__ cursor,
                                                   int* __restrict__ csr_src, int E) {
    int i = blockIdx.x * blockDim.x + threadIdx.x;
    if (i < E) {
        int n = idn[i];
        int p = atomicAdd(&cursor[n], 1);
        csr_src[row_start[n] + p] = idm[i];
    }
}

// ---- B1: gather+selu -> M (one wave per node, no LDS, high occupancy) ----
__global__ void __launch_bounds__(256) gather_kernel(
    const float* __restrict__ y, const float* __restrict__ z,
    const float* __restrict__ bmsg, const int* __restrict__ row_start,
    const int* __restrict__ csr_src, float* __restrict__ M, int N) {
    int lane = threadIdx.x & 63;
    int wave = blockIdx.x * (blockDim.x >> 6) + (threadIdx.x >> 6);
    int nwaves = gridDim.x * (blockDim.x >> 6);
    float b = bmsg[lane];
    for (int i = wave; i < N; i += nwaves) {
        float zb = z[(size_t)i * 64 + lane] + b;
        int s0 = row_start[i], s1 = row_start[i + 1];
        float macc = 0.f;
        int s = s0;
        for (; s + 8 <= s1; s += 8) {
            int e0 = csr_src[s],     e1 = csr_src[s + 1];
            int e2 = csr_src[s + 2], e3 = csr_src[s + 3];
            int e4 = csr_src[s + 4], e5 = csr_src[s + 5];
            int e6 = csr_src[s + 6], e7 = csr_src[s + 7];
            float v0 = y[(size_t)e0 * 64 + lane];
            float v1 = y[(size_t)e1 * 64 + lane];
            float v2 = y[(size_t)e2 * 64 + lane];
            float v3 = y[(size_t)e3 * 64 + lane];
            float v4 = y[(size_t)e4 * 64 + lane];
            float v5 = y[(size_t)e5 * 64 + lane];
            float v6 = y[(size_t)e6 * 64 + lane];
            float v7 = y[(size_t)e7 * 64 + lane];
            macc += selu_f(v0 + zb);
            macc += selu_f(v1 + zb);
            macc += selu_f(v2 + zb);
            macc += selu_f(v3 + zb);
            macc += selu_f(v4 + zb);
            macc += selu_f(v5 + zb);
            macc += selu_f(v6 + zb);
            macc += selu_f(v7 + zb);
        }
        for (; s + 2 <= s1; s += 2) {
            int e0 = csr_src[s], e1 = csr_src[s + 1];
            float v0 = y[(size_t)e0 * 64 + lane];
            float v1 = y[(size_t)e1 * 64 + lane];
            macc += selu_f(v0 + zb);
            macc += selu_f(v1 + zb);
        }
        for (; s < s1; ++s) macc += selu_f(y[(size_t)csr_src[s] * 64 + lane] + zb);
        M[(size_t)i * 64 + lane] = macc;
    }
}

// ---- B2: gi = M@Wih^T ; gh = h@Whh^T ; GRU combine (linear reads only) ----
__global__ void __launch_bounds__(512) gru_kernel(
    const float* __restrict__ M, float* __restrict__ cur,
    const float* __restrict__ Wih, const float* __restrict__ Whh,
    const float* __restrict__ bih, const float* __restrict__ bhh, int N) {
    __shared__ __align__(16) float wbuf[6 * 64 * WPAD];  // 104.4 KB
    __shared__ __align__(16) float xsM[8 * NB * 64];     // 16 KB
    __shared__ __align__(16) float xsH[8 * NB * 64];     // 16 KB
    for (int idx = threadIdx.x; idx < 6 * 64 * 64; idx += 512) {
        int g = idx >> 12, rem = idx & 4095;
        int d = rem >> 6, j = rem & 63;
        const float* src = (g < 3) ? Wih : Whh;
        int gg = (g < 3) ? g : g - 3;
        wbuf[g * 64 * WPAD + d * WPAD + j] = src[(gg * 64 + d) * 64 + j];
    }
    __syncthreads();
    int lane = threadIdx.x & 63;
    int w = threadIdx.x >> 6;
    float* xm = &xsM[w * (NB * 64)];
    float* xh = &xsH[w * (NB * 64)];
    const float* wir = wbuf + 0 * 64 * WPAD;
    const float* wiz = wbuf + 1 * 64 * WPAD;
    const float* win = wbuf + 2 * 64 * WPAD;
    const float* whr = wbuf + 3 * 64 * WPAD;
    const float* whz = wbuf + 4 * 64 * WPAD;
    const float* whn = wbuf + 5 * 64 * WPAD;
    float bir = bih[lane], biz = bih[64 + lane], bin_ = bih[128 + lane];
    float bhr = bhh[lane], bhz = bhh[64 + lane], bhn = bhh[128 + lane];
    int nbTot = (N + NB - 1) / NB;
    for (int nb = blockIdx.x * 8 + w; nb < nbTot; nb += gridDim.x * 8) {
        int n0 = nb * NB;
        float hv[NB];
#pragma unroll
        for (int n = 0; n < NB; ++n) {
            int i = n0 + n;
            hv[n] = (i < N) ? cur[(size_t)i * 64 + lane] : 0.f;
            xh[n * 64 + lane] = hv[n];
            xm[n * 64 + lane] = (i < N) ? M[(size_t)i * 64 + lane] : 0.f;
        }
        float air[NB], aiz[NB], ain[NB], ahr[NB], ahz[NB], ahn[NB];
#pragma unroll
        for (int n = 0; n < NB; ++n) {
            air[n] = 0.f; aiz[n] = 0.f; ain[n] = 0.f;
            ahr[n] = 0.f; ahz[n] = 0.f; ahn[n] = 0.f;
        }
#pragma unroll 1
        for (int jg = 0; jg < 16; ++jg) {
            float4 wirv = *(const float4*)&wir[lane * WPAD + jg * 4];
            float4 wizv = *(const float4*)&wiz[lane * WPAD + jg * 4];
            float4 winv = *(const float4*)&win[lane * WPAD + jg * 4];
            float4 whrv = *(const float4*)&whr[lane * WPAD + jg * 4];
            float4 whzv = *(const float4*)&whz[lane * WPAD + jg * 4];
            float4 whnv = *(const float4*)&whn[lane * WPAD + jg * 4];
#pragma unroll
            for (int n = 0; n < NB; ++n) {
                float4 m4 = *(const float4*)&xm[n * 64 + jg * 4];  // uniform broadcast
                float4 h4 = *(const float4*)&xh[n * 64 + jg * 4];
                air[n] = dot4(wirv, m4, air[n]);
                aiz[n] = dot4(wizv, m4, aiz[n]);
                ain[n] = dot4(winv, m4, ain[n]);
                ahr[n] = dot4(whrv, h4, ahr[n]);
                ahz[n] = dot4(whzv, h4, ahz[n]);
                ahn[n] = dot4(whnv, h4, ahn[n]);
            }
        }
#pragma unroll
        for (int n = 0; n < NB; ++n) {
            int i = n0 + n;
            if (i < N) {
                float r = sigmoid_f(air[n] + bir + ahr[n] + bhr);
                float zg = sigmoid_f(aiz[n] + biz + ahz[n] + bhz);
                float nn = tanhf(ain[n] + bin_ + r * (ahn[n] + bhn));
                cur[(size_t)i * 64 + lane] = (1.f - zg) * nn + zg * hv[n];
            }
        }
    }
}

__global__ void __launch_bounds__(256) pathsum_kernel(const float* __restrict__ h,
                                                      float* __restrict__ kp, int N, int K) {
    int per = N / K;
    int blocksPerPath = gridDim.x / K;
    int p = blockIdx.x / blocksPerPath;
    int c = blockIdx.x % blocksPerPath;
    int d = threadIdx.x & 63;
    int row0 = c * (blockDim.x >> 6) + (threadIdx.x >> 6);
    int stride = blocksPerPath * (blockDim.x >> 6);
    float acc = 0.f;
    for (int r = row0; r < per; r += stride) acc += h[((size_t)p * per + r) * 64 + d];
    __shared__ float red[256];
    red[threadIdx.x] = acc;
    __syncthreads();
    if (threadIdx.x < 64) {
        float s = red[threadIdx.x] + red[64 + threadIdx.x] + red[128 + threadIdx.x] +
                  red[192 + threadIdx.x];
        atomicAdd(&kp[p * 64 + threadIdx.x], s);
    }
}

// 8 blocks, one per path: h1 = selu(kp@Wr1^T+br1); h2 = selu(h1@Wr2^T+br2)
__global__ void __launch_bounds__(256) readout1_kernel(const float* __restrict__ kp,
                                                       const float* __restrict__ Wr1,
                                                       const float* __restrict__ br1,
                                                       const float* __restrict__ Wr2,
                                                       const float* __restrict__ br2,
                                                       float* __restrict__ h2) {
    int p = blockIdx.x;
    int t = threadIdx.x;
    __shared__ __align__(16) float kps[64];
    __shared__ __align__(16) float h1[256];
    if (t < 64) kps[t] = kp[p * 64 + t];
    __syncthreads();
    float acc = br1[t];
#pragma unroll
    for (int d4 = 0; d4 < 16; ++d4) {
        float4 wv = *(const float4*)&Wr1[t * 64 + d4 * 4];
        float4 kv = *(const float4*)&kps[d4 * 4];
        acc = dot4(wv, kv, acc);
    }
    h1[t] = selu_f(acc);
    __syncthreads();
    float acc2 = br2[t];
#pragma unroll 8
    for (int j4 = 0; j4 < 64; ++j4) {
        float4 wv = *(const float4*)&Wr2[t * 256 + j4 * 4];
        float4 hv = *(const float4*)&h1[j4 * 4];
        acc2 = dot4(wv, hv, acc2);
    }
    h2[p * 256 + t] = selu_f(acc2);
}

__global__ void __launch_bounds__(256) readout2_kernel(const float* __restrict__ h2,
                                                       const float* __restrict__ Wr3,
                                                       const float* __restrict__ br3,
                                                       float* __restrict__ out) {
    __shared__ float red[256];
    __shared__ float lg[8];
    int t = threadIdx.x;
    float w3 = Wr3[t];
    for (int p = 0; p < 8; ++p) {
        red[t] = w3 * h2[p * 256 + t];
        __syncthreads();
        for (int off = 128; off > 0; off >>= 1) {
            if (t < off) red[t] += red[t + off];
            __syncthreads();
        }
        if (t == 0) lg[p] = red[0] + br3[0];
        __syncthreads();
    }
    if (t == 0) {
        float mx = lg[0];
        for (int p = 1; p < 8; ++p) mx = fmaxf(mx, lg[p]);
        float s = 0.f, e[8];
        for (int p = 0; p < 8; ++p) {
            e[p] = expf(lg[p] - mx);
            s += e[p];
        }
        for (int p = 0; p < 8; ++p) out[p] = e[p] / s;
    }
}

extern "C" void kernel_launch(void* const* d_in, const int* in_sizes, int n_in,
                              void* d_out, int out_size, void* d_ws, size_t ws_size,
                              hipStream_t stream) {
    const float* links_state = (const float*)d_in[0];
    const int* idm = (const int*)d_in[1];
    const int* idn = (const int*)d_in[2];
    const float* Wmsg = (const float*)d_in[3];
    const float* bmsg = (const float*)d_in[4];
    const float* Wih = (const float*)d_in[5];
    const float* Whh = (const float*)d_in[6];
    const float* bih = (const float*)d_in[7];
    const float* bhh = (const float*)d_in[8];
    const float* Wr1 = (const float*)d_in[9];
    const float* br1 = (const float*)d_in[10];
    const float* Wr2 = (const float*)d_in[11];
    const float* br2 = (const float*)d_in[12];
    const float* Wr3 = (const float*)d_in[13];
    const float* br3 = (const float*)d_in[14];

    const int N = in_sizes[0] / D;  // 50000
    const int E = in_sizes[1];      // 800000
    const int K = 8, T = 3;

    float* ws = (float*)d_ws;
    size_t nd = (size_t)N * D;
    float* cur = ws;
    float* y = ws + nd;
    float* z = ws + 2 * nd;
    float* M = ws + 3 * nd;
    float* kp = ws + 4 * nd;       // 512
    float* h2 = kp + 512;          // 2048
    int* ibase = (int*)(h2 + 2048);
    int* cnt = ibase;                  // N
    int* row_start = ibase + N;        // N+1
    int* cursor = ibase + 2 * N + 1;   // N
    int* csr_src = ibase + 3 * N + 1;  // E

    // CSR build (once per launch)
    hipMemsetAsync(cnt, 0, (size_t)N * sizeof(int), stream);
    hipMemsetAsync(cursor, 0, (size_t)N * sizeof(int), stream);
    count_kernel<<<dim3((E + 255) / 256), dim3(256), 0, stream>>>(idn, cnt, E);
    scan_kernel<<<dim3(1), dim3(1024), 0, stream>>>(cnt, row_start, N);
    fill_kernel<<<dim3((E + 255) / 256), dim3(256), 0, stream>>>(idm, idn, row_start, cursor,
                                                                 csr_src, E);

    hipMemcpyAsync(cur, links_state, nd * sizeof(float), hipMemcpyDeviceToDevice, stream);

    int nbTot = (N + NB - 1) / NB;         // 6250
    int gridA = (nbTot + 15) / 16;         // 391
    int gridB = (nbTot + 7) / 8;           // 782
    for (int t = 0; t < T; ++t) {
        yz_kernel<<<dim3(gridA), dim3(1024), 0, stream>>>(cur, Wmsg, y, z, N);
        gather_kernel<<<dim3(2048), dim3(256), 0, stream>>>(y, z, bmsg, row_start, csr_src,
                                                            M, N);
        gru_kernel<<<dim3(gridB), dim3(512), 0, stream>>>(M, cur, Wih, Whh, bih, bhh, N);
    }

    hipMemsetAsync(kp, 0, (size_t)K * 64 * sizeof(float), stream);
    pathsum_kernel<<<dim3(256), dim3(256), 0, stream>>>(cur, kp, N, K);
    readout1_kernel<<<dim3(8), dim3(256), 0, stream>>>(kp, Wr1, br1, Wr2, br2, h2);
    readout2_kernel<<<dim3(1), dim3(256), 0, stream>>>(h2, Wr3, br3, (float*)d_out);
}

// Round 10
// 553.541 us; speedup vs baseline: 1.7467x; 1.2813x over previous
//
#include <hip/hip_runtime.h>
#include <hip/hip_bf16.h>

#define D 64
#define NB 8      // nodes per wave-block
#define WPAD 68   // padded weight stride (floats), 16B-aligned, bank-spread
#define HPAD 72   // padded fp16 weight stride (halves): 144 B rows, 16B-aligned

typedef _Float16 f16;
typedef _Float16 f16x2 __attribute__((ext_vector_type(2)));
typedef _Float16 f16x8 __attribute__((ext_vector_type(8)));

__device__ __forceinline__ float selu_f(float x) {
    const float SC = 1.0507009873554805f;
    const float AL = 1.6732632423543772f;
    return x > 0.f ? SC * x : SC * AL * (expf(x) - 1.f);
}
__device__ __forceinline__ float sigmoid_f(float x) { return 1.f / (1.f + expf(-x)); }
__device__ __forceinline__ float dot4(float4 a, float4 b, float acc) {
    acc = fmaf(a.x, b.x, acc);
    acc = fmaf(a.y, b.y, acc);
    acc = fmaf(a.z, b.z, acc);
    return fmaf(a.w, b.w, acc);
}
__device__ __forceinline__ float dot8h(f16x8 a, f16x8 b, float acc) {
    f16x2 a0 = {a[0], a[1]}, b0 = {b[0], b[1]};
    f16x2 a1 = {a[2], a[3]}, b1 = {b[2], b[3]};
    f16x2 a2 = {a[4], a[5]}, b2 = {b[4], b[5]};
    f16x2 a3 = {a[6], a[7]}, b3 = {b[6], b[7]};
    acc = __builtin_amdgcn_fdot2(a0, b0, acc, false);
    acc = __builtin_amdgcn_fdot2(a1, b1, acc, false);
    acc = __builtin_amdgcn_fdot2(a2, b2, acc, false);
    acc = __builtin_amdgcn_fdot2(a3, b3, acc, false);
    return acc;
}

// ---- A: y = x@Wy^T, z = x@Wz^T (Wy = Wmsg[:,:64], Wz = Wmsg[:,64:]) ----
__global__ void __launch_bounds__(1024) yz_kernel(const float* __restrict__ x,
                                                  const float* __restrict__ Wmsg,
                                                  float* __restrict__ y,
                                                  float* __restrict__ z, int N) {
    __shared__ __align__(16) float wbuf[2 * 64 * WPAD];  // 34 KB
    __shared__ __align__(16) float xs[16 * NB * 64];     // 32 KB
    for (int idx = threadIdx.x; idx < 2 * 64 * 64; idx += 1024) {
        int g = idx >> 12, rem = idx & 4095;
        int d = rem >> 6, j = rem & 63;
        wbuf[g * 64 * WPAD + d * WPAD + j] = Wmsg[d * 128 + g * 64 + j];
    }
    __syncthreads();
    int lane = threadIdx.x & 63;
    int w = threadIdx.x >> 6;
    float* xw = &xs[w * (NB * 64)];
    const float* wy = wbuf;
    const float* wz = wbuf + 64 * WPAD;
    int nbTot = (N + NB - 1) / NB;
    for (int nb = blockIdx.x * 16 + w; nb < nbTot; nb += gridDim.x * 16) {
        int n0 = nb * NB;
#pragma unroll
        for (int n = 0; n < NB; ++n) {
            int i = n0 + n;
            xw[n * 64 + lane] = (i < N) ? x[(size_t)i * 64 + lane] : 0.f;
        }
        float accy[NB], accz[NB];
#pragma unroll
        for (int n = 0; n < NB; ++n) { accy[n] = 0.f; accz[n] = 0.f; }
#pragma unroll 1
        for (int jg = 0; jg < 16; ++jg) {
            float4 wyv = *(const float4*)&wy[lane * WPAD + jg * 4];
            float4 wzv = *(const float4*)&wz[lane * WPAD + jg * 4];
#pragma unroll
            for (int n = 0; n < NB; ++n) {
                float4 xv = *(const float4*)&xw[n * 64 + jg * 4];  // uniform: broadcast
                accy[n] = dot4(wyv, xv, accy[n]);
                accz[n] = dot4(wzv, xv, accz[n]);
            }
        }
#pragma unroll
        for (int n = 0; n < NB; ++n) {
            int i = n0 + n;
            if (i < N) {
                y[(size_t)i * 64 + lane] = accy[n];
                z[(size_t)i * 64 + lane] = accz[n];
            }
        }
    }
}

// ---- CSR build ----
__global__ void __launch_bounds__(256) count_kernel(const int* __restrict__ idn,
                                                    int* __restrict__ cnt, int E) {
    int i = blockIdx.x * blockDim.x + threadIdx.x;
    if (i < E) atomicAdd(&cnt[idn[i]], 1);
}

__global__ void __launch_bounds__(1024) scan_kernel(const int* __restrict__ cnt,
                                                    int* __restrict__ row_start, int N) {
    __shared__ int part[1024];
    int t = threadIdx.x;
    int chunk = (N + 1023) / 1024;
    int lo = t * chunk;
    int hi = lo + chunk < N ? lo + chunk : N;
    int s = 0;
    for (int i = lo; i < hi; ++i) s += cnt[i];
    part[t] = s;
    __syncthreads();
    for (int off = 1; off < 1024; off <<= 1) {
        int v = part[t];
        int u = (t >= off) ? part[t - off] : 0;
        __syncthreads();
        part[t] = v + u;
        __syncthreads();
    }
    int excl = (t == 0) ? 0 : part[t - 1];
    for (int i = lo; i < hi; ++i) {
        row_start[i] = excl;
        excl += cnt[i];
    }
    if (t == 1023) row_start[N] = part[1023];
}

__global__ void __launch_bounds__(256) fill_kernel(const int* __restrict__ idm,
                                                   const int* __restrict__ idn,
                                                   const int* __restrict__ row_start,
                                                   int* __restrict__ cursor,
                                                   int* __restrict__ csr_src, int E) {
    int i = blockIdx.x * blockDim.x + threadIdx.x;
    if (i < E) {
        int n = idn[i];
        int p = atomicAdd(&cursor[n], 1);
        csr_src[row_start[n] + p] = idm[i];
    }
}

// ---- B1: gather+selu -> M (one wave per node, no LDS, high occupancy) ----
__global__ void __launch_bounds__(256) gather_kernel(
    const float* __restrict__ y, const float* __restrict__ z,
    const float* __restrict__ bmsg, const int* __restrict__ row_start,
    const int* __restrict__ csr_src, float* __restrict__ M, int N) {
    int lane = threadIdx.x & 63;
    int wave = blockIdx.x * (blockDim.x >> 6) + (threadIdx.x >> 6);
    int nwaves = gridDim.x * (blockDim.x >> 6);
    float b = bmsg[lane];
    for (int i = wave; i < N; i += nwaves) {
        float zb = z[(size_t)i * 64 + lane] + b;
        int s0 = row_start[i], s1 = row_start[i + 1];
        float macc = 0.f;
        int s = s0;
        for (; s + 8 <= s1; s += 8) {
            int e0 = csr_src[s],     e1 = csr_src[s + 1];
            int e2 = csr_src[s + 2], e3 = csr_src[s + 3];
            int e4 = csr_src[s + 4], e5 = csr_src[s + 5];
            int e6 = csr_src[s + 6], e7 = csr_src[s + 7];
            float v0 = y[(size_t)e0 * 64 + lane];
            float v1 = y[(size_t)e1 * 64 + lane];
            float v2 = y[(size_t)e2 * 64 + lane];
            float v3 = y[(size_t)e3 * 64 + lane];
            float v4 = y[(size_t)e4 * 64 + lane];
            float v5 = y[(size_t)e5 * 64 + lane];
            float v6 = y[(size_t)e6 * 64 + lane];
            float v7 = y[(size_t)e7 * 64 + lane];
            macc += selu_f(v0 + zb);
            macc += selu_f(v1 + zb);
            macc += selu_f(v2 + zb);
            macc += selu_f(v3 + zb);
            macc += selu_f(v4 + zb);
            macc += selu_f(v5 + zb);
            macc += selu_f(v6 + zb);
            macc += selu_f(v7 + zb);
        }
        for (; s + 2 <= s1; s += 2) {
            int e0 = csr_src[s], e1 = csr_src[s + 1];
            float v0 = y[(size_t)e0 * 64 + lane];
            float v1 = y[(size_t)e1 * 64 + lane];
            macc += selu_f(v0 + zb);
            macc += selu_f(v1 + zb);
        }
        for (; s < s1; ++s) macc += selu_f(y[(size_t)csr_src[s] * 64 + lane] + zb);
        M[(size_t)i * 64 + lane] = macc;
    }
}

// ---- B2: gi = M@Wih^T ; gh = h@Whh^T ; GRU combine — fp16 dot2 path ----
__global__ void __launch_bounds__(512) gru_kernel(
    const float* __restrict__ M, float* __restrict__ cur,
    const float* __restrict__ Wih, const float* __restrict__ Whh,
    const float* __restrict__ bih, const float* __restrict__ bhh, int N) {
    __shared__ __align__(16) f16 wbuf[6 * 64 * HPAD];  // 54 KB
    __shared__ __align__(16) f16 xsM[8 * NB * 64];     // 8 KB
    __shared__ __align__(16) f16 xsH[8 * NB * 64];     // 8 KB
    for (int idx = threadIdx.x; idx < 6 * 64 * 64; idx += 512) {
        int g = idx >> 12, rem = idx & 4095;
        int d = rem >> 6, j = rem & 63;
        const float* src = (g < 3) ? Wih : Whh;
        int gg = (g < 3) ? g : g - 3;
        wbuf[(g * 64 + d) * HPAD + j] = (f16)src[(gg * 64 + d) * 64 + j];
    }
    __syncthreads();
    int lane = threadIdx.x & 63;
    int w = threadIdx.x >> 6;
    f16* xm = &xsM[w * (NB * 64)];
    f16* xh = &xsH[w * (NB * 64)];
    const f16* wir = wbuf + 0 * 64 * HPAD;
    const f16* wiz = wbuf + 1 * 64 * HPAD;
    const f16* win = wbuf + 2 * 64 * HPAD;
    const f16* whr = wbuf + 3 * 64 * HPAD;
    const f16* whz = wbuf + 4 * 64 * HPAD;
    const f16* whn = wbuf + 5 * 64 * HPAD;
    float bir = bih[lane], biz = bih[64 + lane], bin_ = bih[128 + lane];
    float bhr = bhh[lane], bhz = bhh[64 + lane], bhn = bhh[128 + lane];
    int nbTot = (N + NB - 1) / NB;
    for (int nb = blockIdx.x * 8 + w; nb < nbTot; nb += gridDim.x * 8) {
        int n0 = nb * NB;
        float hv[NB];
#pragma unroll
        for (int n = 0; n < NB; ++n) {
            int i = n0 + n;
            hv[n] = (i < N) ? cur[(size_t)i * 64 + lane] : 0.f;
            float mv = (i < N) ? M[(size_t)i * 64 + lane] : 0.f;
            xh[n * 64 + lane] = (f16)hv[n];
            xm[n * 64 + lane] = (f16)mv;
        }
        float air[NB], aiz[NB], ain[NB], ahr[NB], ahz[NB], ahn[NB];
#pragma unroll
        for (int n = 0; n < NB; ++n) {
            air[n] = 0.f; aiz[n] = 0.f; ain[n] = 0.f;
            ahr[n] = 0.f; ahz[n] = 0.f; ahn[n] = 0.f;
        }
#pragma unroll 1
        for (int jg = 0; jg < 8; ++jg) {
            f16x8 wirv = *(const f16x8*)&wir[lane * HPAD + jg * 8];
            f16x8 wizv = *(const f16x8*)&wiz[lane * HPAD + jg * 8];
            f16x8 winv = *(const f16x8*)&win[lane * HPAD + jg * 8];
            f16x8 whrv = *(const f16x8*)&whr[lane * HPAD + jg * 8];
            f16x8 whzv = *(const f16x8*)&whz[lane * HPAD + jg * 8];
            f16x8 whnv = *(const f16x8*)&whn[lane * HPAD + jg * 8];
#pragma unroll
            for (int n = 0; n < NB; ++n) {
                f16x8 m8 = *(const f16x8*)&xm[n * 64 + jg * 8];  // uniform broadcast
                f16x8 h8 = *(const f16x8*)&xh[n * 64 + jg * 8];
                air[n] = dot8h(wirv, m8, air[n]);
                aiz[n] = dot8h(wizv, m8, aiz[n]);
                ain[n] = dot8h(winv, m8, ain[n]);
                ahr[n] = dot8h(whrv, h8, ahr[n]);
                ahz[n] = dot8h(whzv, h8, ahz[n]);
                ahn[n] = dot8h(whnv, h8, ahn[n]);
            }
        }
#pragma unroll
        for (int n = 0; n < NB; ++n) {
            int i = n0 + n;
            if (i < N) {
                float r = sigmoid_f(air[n] + bir + ahr[n] + bhr);
                float zg = sigmoid_f(aiz[n] + biz + ahz[n] + bhz);
                float nn = tanhf(ain[n] + bin_ + r * (ahn[n] + bhn));
                cur[(size_t)i * 64 + lane] = (1.f - zg) * nn + zg * hv[n];
            }
        }
    }
}

__global__ void __launch_bounds__(256) pathsum_kernel(const float* __restrict__ h,
                                                      float* __restrict__ kp, int N, int K) {
    int per = N / K;
    int blocksPerPath = gridDim.x / K;
    int p = blockIdx.x / blocksPerPath;
    int c = blockIdx.x % blocksPerPath;
    int d = threadIdx.x & 63;
    int row0 = c * (blockDim.x >> 6) + (threadIdx.x >> 6);
    int stride = blocksPerPath * (blockDim.x >> 6);
    float acc = 0.f;
    for (int r = row0; r < per; r += stride) acc += h[((size_t)p * per + r) * 64 + d];
    __shared__ float red[256];
    red[threadIdx.x] = acc;
    __syncthreads();
    if (threadIdx.x < 64) {
        float s = red[threadIdx.x] + red[64 + threadIdx.x] + red[128 + threadIdx.x] +
                  red[192 + threadIdx.x];
        atomicAdd(&kp[p * 64 + threadIdx.x], s);
    }
}

// 8 blocks, one per path: h1 = selu(kp@Wr1^T+br1); h2 = selu(h1@Wr2^T+br2)
__global__ void __launch_bounds__(256) readout1_kernel(const float* __restrict__ kp,
                                                       const float* __restrict__ Wr1,
                                                       const float* __restrict__ br1,
                                                       const float* __restrict__ Wr2,
                                                       const float* __restrict__ br2,
                                                       float* __restrict__ h2) {
    int p = blockIdx.x;
    int t = threadIdx.x;
    __shared__ __align__(16) float kps[64];
    __shared__ __align__(16) float h1[256];
    if (t < 64) kps[t] = kp[p * 64 + t];
    __syncthreads();
    float acc = br1[t];
#pragma unroll
    for (int d4 = 0; d4 < 16; ++d4) {
        float4 wv = *(const float4*)&Wr1[t * 64 + d4 * 4];
        float4 kv = *(const float4*)&kps[d4 * 4];
        acc = dot4(wv, kv, acc);
    }
    h1[t] = selu_f(acc);
    __syncthreads();
    float acc2 = br2[t];
#pragma unroll 8
    for (int j4 = 0; j4 < 64; ++j4) {
        float4 wv = *(const float4*)&Wr2[t * 256 + j4 * 4];
        float4 hv = *(const float4*)&h1[j4 * 4];
        acc2 = dot4(wv, hv, acc2);
    }
    h2[p * 256 + t] = selu_f(acc2);
}

__global__ void __launch_bounds__(256) readout2_kernel(const float* __restrict__ h2,
                                                       const float* __restrict__ Wr3,
                                                       const float* __restrict__ br3,
                                                       float* __restrict__ out) {
    __shared__ float red[256];
    __shared__ float lg[8];
    int t = threadIdx.x;
    float w3 = Wr3[t];
    for (int p = 0; p < 8; ++p) {
        red[t] = w3 * h2[p * 256 + t];
        __syncthreads();
        for (int off = 128; off > 0; off >>= 1) {
            if (t < off) red[t] += red[t + off];
            __syncthreads();
        }
        if (t == 0) lg[p] = red[0] + br3[0];
        __syncthreads();
    }
    if (t == 0) {
        float mx = lg[0];
        for (int p = 1; p < 8; ++p) mx = fmaxf(mx, lg[p]);
        float s = 0.f, e[8];
        for (int p = 0; p < 8; ++p) {
            e[p] = expf(lg[p] - mx);
            s += e[p];
        }
        for (int p = 0; p < 8; ++p) out[p] = e[p] / s;
    }
}

extern "C" void kernel_launch(void* const* d_in, const int* in_sizes, int n_in,
                              void* d_out, int out_size, void* d_ws, size_t ws_size,
                              hipStream_t stream) {
    const float* links_state = (const float*)d_in[0];
    const int* idm = (const int*)d_in[1];
    const int* idn = (const int*)d_in[2];
    const float* Wmsg = (const float*)d_in[3];
    const float* bmsg = (const float*)d_in[4];
    const float* Wih = (const float*)d_in[5];
    const float* Whh = (const float*)d_in[6];
    const float* bih = (const float*)d_in[7];
    const float* bhh = (const float*)d_in[8];
    const float* Wr1 = (const float*)d_in[9];
    const float* br1 = (const float*)d_in[10];
    const float* Wr2 = (const float*)d_in[11];
    const float* br2 = (const float*)d_in[12];
    const float* Wr3 = (const float*)d_in[13];
    const float* br3 = (const float*)d_in[14];

    const int N = in_sizes[0] / D;  // 50000
    const int E = in_sizes[1];      // 800000
    const int K = 8, T = 3;

    float* ws = (float*)d_ws;
    size_t nd = (size_t)N * D;
    float* cur = ws;
    float* y = ws + nd;
    float* z = ws + 2 * nd;
    float* M = ws + 3 * nd;
    float* kp = ws + 4 * nd;       // 512
    float* h2 = kp + 512;          // 2048
    int* ibase = (int*)(h2 + 2048);
    int* cnt = ibase;                  // N
    int* row_start = ibase + N;        // N+1
    int* cursor = ibase + 2 * N + 1;   // N
    int* csr_src = ibase + 3 * N + 1;  // E

    // CSR build (once per launch)
    hipMemsetAsync(cnt, 0, (size_t)N * sizeof(int), stream);
    hipMemsetAsync(cursor, 0, (size_t)N * sizeof(int), stream);
    count_kernel<<<dim3((E + 255) / 256), dim3(256), 0, stream>>>(idn, cnt, E);
    scan_kernel<<<dim3(1), dim3(1024), 0, stream>>>(cnt, row_start, N);
    fill_kernel<<<dim3((E + 255) / 256), dim3(256), 0, stream>>>(idm, idn, row_start, cursor,
                                                                 csr_src, E);

    hipMemcpyAsync(cur, links_state, nd * sizeof(float), hipMemcpyDeviceToDevice, stream);

    int nbTot = (N + NB - 1) / NB;         // 6250
    int gridA = (nbTot + 15) / 16;         // 391
    int gridB = (nbTot + 7) / 8;           // 782
    for (int t = 0; t < T; ++t) {
        yz_kernel<<<dim3(gridA), dim3(1024), 0, stream>>>(cur, Wmsg, y, z, N);
        gather_kernel<<<dim3(2048), dim3(256), 0, stream>>>(y, z, bmsg, row_start, csr_src,
                                                            M, N);
        gru_kernel<<<dim3(gridB), dim3(512), 0, stream>>>(M, cur, Wih, Whh, bih, bhh, N);
    }

    hipMemsetAsync(kp, 0, (size_t)K * 64 * sizeof(float), stream);
    pathsum_kernel<<<dim3(256), dim3(256), 0, stream>>>(cur, kp, N, K);
    readout1_kernel<<<dim3(8), dim3(256), 0, stream>>>(kp, Wr1, br1, Wr2, br2, h2);
    readout2_kernel<<<dim3(1), dim3(256), 0, stream>>>(h2, Wr3, br3, (float*)d_out);
}

// Round 11
// 469.396 us; speedup vs baseline: 2.0598x; 1.1793x over previous
//
#include <hip/hip_runtime.h>
#include <hip/hip_bf16.h>

#define D 64
#define NB 8      // nodes per wave-block
#define HPAD 72   // padded fp16 weight stride (halves): 144 B rows, 16B-aligned

typedef _Float16 f16;
typedef _Float16 f16x2 __attribute__((ext_vector_type(2)));
typedef _Float16 f16x8 __attribute__((ext_vector_type(8)));

__device__ __forceinline__ float selu_f(float x) {
    const float SC = 1.0507009873554805f;
    const float AL = 1.6732632423543772f;
    return x > 0.f ? SC * x : SC * AL * (expf(x) - 1.f);
}
__device__ __forceinline__ float sigmoid_f(float x) { return 1.f / (1.f + expf(-x)); }
__device__ __forceinline__ float dot4(float4 a, float4 b, float acc) {
    acc = fmaf(a.x, b.x, acc);
    acc = fmaf(a.y, b.y, acc);
    acc = fmaf(a.z, b.z, acc);
    return fmaf(a.w, b.w, acc);
}
__device__ __forceinline__ float dot8h(f16x8 a, f16x8 b, float acc) {
    f16x2 a0 = {a[0], a[1]}, b0 = {b[0], b[1]};
    f16x2 a1 = {a[2], a[3]}, b1 = {b[2], b[3]};
    f16x2 a2 = {a[4], a[5]}, b2 = {b[4], b[5]};
    f16x2 a3 = {a[6], a[7]}, b3 = {b[6], b[7]};
    acc = __builtin_amdgcn_fdot2(a0, b0, acc, false);
    acc = __builtin_amdgcn_fdot2(a1, b1, acc, false);
    acc = __builtin_amdgcn_fdot2(a2, b2, acc, false);
    acc = __builtin_amdgcn_fdot2(a3, b3, acc, false);
    return acc;
}

// ---- A: y = x@Wy^T, z = x@Wz^T (fp16 weights/activations, fp32 accum) ----
__global__ void __launch_bounds__(1024) yz_kernel(const float* __restrict__ x,
                                                  const float* __restrict__ Wmsg,
                                                  f16* __restrict__ y16,
                                                  f16* __restrict__ z16, int N) {
    __shared__ __align__(16) f16 wbuf[2 * 64 * HPAD];  // 18 KB
    __shared__ __align__(16) f16 xs[16 * NB * 64];     // 16 KB
    for (int idx = threadIdx.x; idx < 2 * 64 * 64; idx += 1024) {
        int g = idx >> 12, rem = idx & 4095;
        int d = rem >> 6, j = rem & 63;
        wbuf[(g * 64 + d) * HPAD + j] = (f16)Wmsg[d * 128 + g * 64 + j];
    }
    __syncthreads();
    int lane = threadIdx.x & 63;
    int w = threadIdx.x >> 6;
    f16* xw = &xs[w * (NB * 64)];
    const f16* wy = wbuf;
    const f16* wz = wbuf + 64 * HPAD;
    int nbTot = (N + NB - 1) / NB;
    for (int nb = blockIdx.x * 16 + w; nb < nbTot; nb += gridDim.x * 16) {
        int n0 = nb * NB;
#pragma unroll
        for (int n = 0; n < NB; ++n) {
            int i = n0 + n;
            xw[n * 64 + lane] = (f16)((i < N) ? x[(size_t)i * 64 + lane] : 0.f);
        }
        float accy[NB], accz[NB];
#pragma unroll
        for (int n = 0; n < NB; ++n) { accy[n] = 0.f; accz[n] = 0.f; }
#pragma unroll 1
        for (int jg = 0; jg < 8; ++jg) {
            f16x8 wyv = *(const f16x8*)&wy[lane * HPAD + jg * 8];
            f16x8 wzv = *(const f16x8*)&wz[lane * HPAD + jg * 8];
#pragma unroll
            for (int n = 0; n < NB; ++n) {
                f16x8 xv = *(const f16x8*)&xw[n * 64 + jg * 8];  // uniform broadcast
                accy[n] = dot8h(wyv, xv, accy[n]);
                accz[n] = dot8h(wzv, xv, accz[n]);
            }
        }
#pragma unroll
        for (int n = 0; n < NB; ++n) {
            int i = n0 + n;
            if (i < N) {
                y16[(size_t)i * 64 + lane] = (f16)accy[n];
                z16[(size_t)i * 64 + lane] = (f16)accz[n];
            }
        }
    }
}

// ---- CSR build ----
__global__ void __launch_bounds__(256) count_kernel(const int* __restrict__ idn,
                                                    int* __restrict__ cnt, int E) {
    int i = blockIdx.x * blockDim.x + threadIdx.x;
    if (i < E) atomicAdd(&cnt[idn[i]], 1);
}

// 3-phase parallel exclusive scan over cnt[N] -> row_start[N+1]
__global__ void __launch_bounds__(256) scan1_kernel(const int* __restrict__ cnt,
                                                    int* __restrict__ partial, int N) {
    __shared__ int s[256];
    int t = threadIdx.x;
    int i = blockIdx.x * 256 + t;
    s[t] = (i < N) ? cnt[i] : 0;
    __syncthreads();
    for (int off = 128; off > 0; off >>= 1) {
        if (t < off) s[t] += s[t + off];
        __syncthreads();
    }
    if (t == 0) partial[blockIdx.x] = s[0];
}

__global__ void __launch_bounds__(256) scan2_kernel(const int* __restrict__ partial,
                                                    int* __restrict__ offs,
                                                    int* __restrict__ row_start,
                                                    int G, int N) {
    __shared__ int s[256];
    int t = threadIdx.x;
    int v0 = (t < G) ? partial[t] : 0;
    s[t] = v0;
    __syncthreads();
    for (int off = 1; off < 256; off <<= 1) {
        int v = s[t];
        int u = (t >= off) ? s[t - off] : 0;
        __syncthreads();
        s[t] = v + u;
        __syncthreads();
    }
    if (t < G) offs[t] = s[t] - v0;  // exclusive
    if (t == 255) row_start[N] = s[255];
}

__global__ void __launch_bounds__(256) scan3_kernel(const int* __restrict__ cnt,
                                                    const int* __restrict__ offs,
                                                    int* __restrict__ row_start, int N) {
    __shared__ int s[256];
    int t = threadIdx.x;
    int i = blockIdx.x * 256 + t;
    int v0 = (i < N) ? cnt[i] : 0;
    s[t] = v0;
    __syncthreads();
    for (int off = 1; off < 256; off <<= 1) {
        int v = s[t];
        int u = (t >= off) ? s[t - off] : 0;
        __syncthreads();
        s[t] = v + u;
        __syncthreads();
    }
    if (i < N) row_start[i] = offs[blockIdx.x] + s[t] - v0;
}

__global__ void __launch_bounds__(256) fill_kernel(const int* __restrict__ idm,
                                                   const int* __restrict__ idn,
                                                   const int* __restrict__ row_start,
                                                   int* __restrict__ cursor,
                                                   int* __restrict__ csr_src, int E) {
    int i = blockIdx.x * blockDim.x + threadIdx.x;
    if (i < E) {
        int n = idn[i];
        int p = atomicAdd(&cursor[n], 1);
        csr_src[row_start[n] + p] = idm[i];
    }
}

// ---- B1: gather+selu -> M16 (one wave per node, no LDS, high occupancy) ----
__global__ void __launch_bounds__(256) gather_kernel(
    const f16* __restrict__ y16, const f16* __restrict__ z16,
    const float* __restrict__ bmsg, const int* __restrict__ row_start,
    const int* __restrict__ csr_src, f16* __restrict__ M16, int N) {
    int lane = threadIdx.x & 63;
    int wave = blockIdx.x * (blockDim.x >> 6) + (threadIdx.x >> 6);
    int nwaves = gridDim.x * (blockDim.x >> 6);
    float b = bmsg[lane];
    for (int i = wave; i < N; i += nwaves) {
        float zb = (float)z16[(size_t)i * 64 + lane] + b;
        int s0 = row_start[i], s1 = row_start[i + 1];
        float macc = 0.f;
        int s = s0;
        for (; s + 8 <= s1; s += 8) {
            int e0 = csr_src[s],     e1 = csr_src[s + 1];
            int e2 = csr_src[s + 2], e3 = csr_src[s + 3];
            int e4 = csr_src[s + 4], e5 = csr_src[s + 5];
            int e6 = csr_src[s + 6], e7 = csr_src[s + 7];
            float v0 = (float)y16[(size_t)e0 * 64 + lane];
            float v1 = (float)y16[(size_t)e1 * 64 + lane];
            float v2 = (float)y16[(size_t)e2 * 64 + lane];
            float v3 = (float)y16[(size_t)e3 * 64 + lane];
            float v4 = (float)y16[(size_t)e4 * 64 + lane];
            float v5 = (float)y16[(size_t)e5 * 64 + lane];
            float v6 = (float)y16[(size_t)e6 * 64 + lane];
            float v7 = (float)y16[(size_t)e7 * 64 + lane];
            macc += selu_f(v0 + zb);
            macc += selu_f(v1 + zb);
            macc += selu_f(v2 + zb);
            macc += selu_f(v3 + zb);
            macc += selu_f(v4 + zb);
            macc += selu_f(v5 + zb);
            macc += selu_f(v6 + zb);
            macc += selu_f(v7 + zb);
        }
        for (; s + 2 <= s1; s += 2) {
            int e0 = csr_src[s], e1 = csr_src[s + 1];
            float v0 = (float)y16[(size_t)e0 * 64 + lane];
            float v1 = (float)y16[(size_t)e1 * 64 + lane];
            macc += selu_f(v0 + zb);
            macc += selu_f(v1 + zb);
        }
        for (; s < s1; ++s)
            macc += selu_f((float)y16[(size_t)csr_src[s] * 64 + lane] + zb);
        M16[(size_t)i * 64 + lane] = (f16)macc;
    }
}

// ---- B2: gi = M@Wih^T ; gh = h@Whh^T ; GRU combine — fp16 dot2 path ----
__global__ void __launch_bounds__(512) gru_kernel(
    const f16* __restrict__ M16, float* __restrict__ cur,
    const float* __restrict__ Wih, const float* __restrict__ Whh,
    const float* __restrict__ bih, const float* __restrict__ bhh, int N) {
    __shared__ __align__(16) f16 wbuf[6 * 64 * HPAD];  // 54 KB
    __shared__ __align__(16) f16 xsM[8 * NB * 64];     // 8 KB
    __shared__ __align__(16) f16 xsH[8 * NB * 64];     // 8 KB
    for (int idx = threadIdx.x; idx < 6 * 64 * 64; idx += 512) {
        int g = idx >> 12, rem = idx & 4095;
        int d = rem >> 6, j = rem & 63;
        const float* src = (g < 3) ? Wih : Whh;
        int gg = (g < 3) ? g : g - 3;
        wbuf[(g * 64 + d) * HPAD + j] = (f16)src[(gg * 64 + d) * 64 + j];
    }
    __syncthreads();
    int lane = threadIdx.x & 63;
    int w = threadIdx.x >> 6;
    f16* xm = &xsM[w * (NB * 64)];
    f16* xh = &xsH[w * (NB * 64)];
    const f16* wir = wbuf + 0 * 64 * HPAD;
    const f16* wiz = wbuf + 1 * 64 * HPAD;
    const f16* win = wbuf + 2 * 64 * HPAD;
    const f16* whr = wbuf + 3 * 64 * HPAD;
    const f16* whz = wbuf + 4 * 64 * HPAD;
    const f16* whn = wbuf + 5 * 64 * HPAD;
    float bir = bih[lane], biz = bih[64 + lane], bin_ = bih[128 + lane];
    float bhr = bhh[lane], bhz = bhh[64 + lane], bhn = bhh[128 + lane];
    int nbTot = (N + NB - 1) / NB;
    for (int nb = blockIdx.x * 8 + w; nb < nbTot; nb += gridDim.x * 8) {
        int n0 = nb * NB;
        float hv[NB];
#pragma unroll
        for (int n = 0; n < NB; ++n) {
            int i = n0 + n;
            hv[n] = (i < N) ? cur[(size_t)i * 64 + lane] : 0.f;
            xh[n * 64 + lane] = (f16)hv[n];
            xm[n * 64 + lane] = (i < N) ? M16[(size_t)i * 64 + lane] : (f16)0.f;
        }
        float air[NB], aiz[NB], ain[NB], ahr[NB], ahz[NB], ahn[NB];
#pragma unroll
        for (int n = 0; n < NB; ++n) {
            air[n] = 0.f; aiz[n] = 0.f; ain[n] = 0.f;
            ahr[n] = 0.f; ahz[n] = 0.f; ahn[n] = 0.f;
        }
#pragma unroll 1
        for (int jg = 0; jg < 8; ++jg) {
            f16x8 wirv = *(const f16x8*)&wir[lane * HPAD + jg * 8];
            f16x8 wizv = *(const f16x8*)&wiz[lane * HPAD + jg * 8];
            f16x8 winv = *(const f16x8*)&win[lane * HPAD + jg * 8];
            f16x8 whrv = *(const f16x8*)&whr[lane * HPAD + jg * 8];
            f16x8 whzv = *(const f16x8*)&whz[lane * HPAD + jg * 8];
            f16x8 whnv = *(const f16x8*)&whn[lane * HPAD + jg * 8];
#pragma unroll
            for (int n = 0; n < NB; ++n) {
                f16x8 m8 = *(const f16x8*)&xm[n * 64 + jg * 8];  // uniform broadcast
                f16x8 h8 = *(const f16x8*)&xh[n * 64 + jg * 8];
                air[n] = dot8h(wirv, m8, air[n]);
                aiz[n] = dot8h(wizv, m8, aiz[n]);
                ain[n] = dot8h(winv, m8, ain[n]);
                ahr[n] = dot8h(whrv, h8, ahr[n]);
                ahz[n] = dot8h(whzv, h8, ahz[n]);
                ahn[n] = dot8h(whnv, h8, ahn[n]);
            }
        }
#pragma unroll
        for (int n = 0; n < NB; ++n) {
            int i = n0 + n;
            if (i < N) {
                float r = sigmoid_f(air[n] + bir + ahr[n] + bhr);
                float zg = sigmoid_f(aiz[n] + biz + ahz[n] + bhz);
                float nn = tanhf(ain[n] + bin_ + r * (ahn[n] + bhn));
                cur[(size_t)i * 64 + lane] = (1.f - zg) * nn + zg * hv[n];
            }
        }
    }
}

__global__ void __launch_bounds__(256) pathsum_kernel(const float* __restrict__ h,
                                                      float* __restrict__ kp, int N, int K) {
    int per = N / K;
    int blocksPerPath = gridDim.x / K;
    int p = blockIdx.x / blocksPerPath;
    int c = blockIdx.x % blocksPerPath;
    int d = threadIdx.x & 63;
    int row0 = c * (blockDim.x >> 6) + (threadIdx.x >> 6);
    int stride = blocksPerPath * (blockDim.x >> 6);
    float acc = 0.f;
    for (int r = row0; r < per; r += stride) acc += h[((size_t)p * per + r) * 64 + d];
    __shared__ float red[256];
    red[threadIdx.x] = acc;
    __syncthreads();
    if (threadIdx.x < 64) {
        float s = red[threadIdx.x] + red[64 + threadIdx.x] + red[128 + threadIdx.x] +
                  red[192 + threadIdx.x];
        atomicAdd(&kp[p * 64 + threadIdx.x], s);
    }
}

// 8 blocks, one per path: h1 = selu(kp@Wr1^T+br1); h2 = selu(h1@Wr2^T+br2)
__global__ void __launch_bounds__(256) readout1_kernel(const float* __restrict__ kp,
                                                       const float* __restrict__ Wr1,
                                                       const float* __restrict__ br1,
                                                       const float* __restrict__ Wr2,
                                                       const float* __restrict__ br2,
                                                       float* __restrict__ h2) {
    int p = blockIdx.x;
    int t = threadIdx.x;
    __shared__ __align__(16) float kps[64];
    __shared__ __align__(16) float h1[256];
    if (t < 64) kps[t] = kp[p * 64 + t];
    __syncthreads();
    float acc = br1[t];
#pragma unroll
    for (int d4 = 0; d4 < 16; ++d4) {
        float4 wv = *(const float4*)&Wr1[t * 64 + d4 * 4];
        float4 kv = *(const float4*)&kps[d4 * 4];
        acc = dot4(wv, kv, acc);
    }
    h1[t] = selu_f(acc);
    __syncthreads();
    float acc2 = br2[t];
#pragma unroll 8
    for (int j4 = 0; j4 < 64; ++j4) {
        float4 wv = *(const float4*)&Wr2[t * 256 + j4 * 4];
        float4 hv = *(const float4*)&h1[j4 * 4];
        acc2 = dot4(wv, hv, acc2);
    }
    h2[p * 256 + t] = selu_f(acc2);
}

__global__ void __launch_bounds__(256) readout2_kernel(const float* __restrict__ h2,
                                                       const float* __restrict__ Wr3,
                                                       const float* __restrict__ br3,
                                                       float* __restrict__ out) {
    __shared__ float red[256];
    __shared__ float lg[8];
    int t = threadIdx.x;
    float w3 = Wr3[t];
    for (int p = 0; p < 8; ++p) {
        red[t] = w3 * h2[p * 256 + t];
        __syncthreads();
        for (int off = 128; off > 0; off >>= 1) {
            if (t < off) red[t] += red[t + off];
            __syncthreads();
        }
        if (t == 0) lg[p] = red[0] + br3[0];
        __syncthreads();
    }
    if (t == 0) {
        float mx = lg[0];
        for (int p = 1; p < 8; ++p) mx = fmaxf(mx, lg[p]);
        float s = 0.f, e[8];
        for (int p = 0; p < 8; ++p) {
            e[p] = expf(lg[p] - mx);
            s += e[p];
        }
        for (int p = 0; p < 8; ++p) out[p] = e[p] / s;
    }
}

extern "C" void kernel_launch(void* const* d_in, const int* in_sizes, int n_in,
                              void* d_out, int out_size, void* d_ws, size_t ws_size,
                              hipStream_t stream) {
    const float* links_state = (const float*)d_in[0];
    const int* idm = (const int*)d_in[1];
    const int* idn = (const int*)d_in[2];
    const float* Wmsg = (const float*)d_in[3];
    const float* bmsg = (const float*)d_in[4];
    const float* Wih = (const float*)d_in[5];
    const float* Whh = (const float*)d_in[6];
    const float* bih = (const float*)d_in[7];
    const float* bhh = (const float*)d_in[8];
    const float* Wr1 = (const float*)d_in[9];
    const float* br1 = (const float*)d_in[10];
    const float* Wr2 = (const float*)d_in[11];
    const float* br2 = (const float*)d_in[12];
    const float* Wr3 = (const float*)d_in[13];
    const float* br3 = (const float*)d_in[14];

    const int N = in_sizes[0] / D;  // 50000
    const int E = in_sizes[1];      // 800000
    const int K = 8, T = 3;
    const int G = (N + 255) / 256;  // 196 scan blocks

    float* ws = (float*)d_ws;
    size_t nd = (size_t)N * D;
    float* cur = ws;                    // nd floats
    f16* y16 = (f16*)(ws + nd);         // nd halves
    f16* z16 = y16 + nd;                // nd halves
    f16* M16 = z16 + nd;                // nd halves
    float* kp = (float*)(M16 + nd);     // 512 floats
    float* h2 = kp + 512;               // 2048 floats
    int* ibase = (int*)(h2 + 2048);
    int* cnt = ibase;                   // N
    int* cursor = ibase + N;            // N  (adjacent to cnt: single memset)
    int* row_start = ibase + 2 * N;     // N+1
    int* partial = row_start + N + 1;   // G
    int* offs = partial + G;            // G
    int* csr_src = offs + G;            // E

    // CSR build (once per launch)
    hipMemsetAsync(cnt, 0, (size_t)2 * N * sizeof(int), stream);  // cnt + cursor
    count_kernel<<<dim3((E + 255) / 256), dim3(256), 0, stream>>>(idn, cnt, E);
    scan1_kernel<<<dim3(G), dim3(256), 0, stream>>>(cnt, partial, N);
    scan2_kernel<<<dim3(1), dim3(256), 0, stream>>>(partial, offs, row_start, G, N);
    scan3_kernel<<<dim3(G), dim3(256), 0, stream>>>(cnt, offs, row_start, N);
    fill_kernel<<<dim3((E + 255) / 256), dim3(256), 0, stream>>>(idm, idn, row_start, cursor,
                                                                 csr_src, E);

    hipMemcpyAsync(cur, links_state, nd * sizeof(float), hipMemcpyDeviceToDevice, stream);

    int nbTot = (N + NB - 1) / NB;  // 6250
    int gridA = (nbTot + 15) / 16;  // 391
    int gridB = (nbTot + 7) / 8;    // 782
    for (int t = 0; t < T; ++t) {
        yz_kernel<<<dim3(gridA), dim3(1024), 0, stream>>>(cur, Wmsg, y16, z16, N);
        gather_kernel<<<dim3(2048), dim3(256), 0, stream>>>(y16, z16, bmsg, row_start,
                                                            csr_src, M16, N);
        gru_kernel<<<dim3(gridB), dim3(512), 0, stream>>>(M16, cur, Wih, Whh, bih, bhh, N);
    }

    hipMemsetAsync(kp, 0, (size_t)K * 64 * sizeof(float), stream);
    pathsum_kernel<<<dim3(256), dim3(256), 0, stream>>>(cur, kp, N, K);
    readout1_kernel<<<dim3(8), dim3(256), 0, stream>>>(kp, Wr1, br1, Wr2, br2, h2);
    readout2_kernel<<<dim3(1), dim3(256), 0, stream>>>(h2, Wr3, br3, (float*)d_out);
}

// Round 12
// 376.514 us; speedup vs baseline: 2.5679x; 1.2467x over previous
//
#include <hip/hip_runtime.h>
#include <hip/hip_bf16.h>

#define D 64
#define NB 8      // nodes per wave-block (fdot2 kernels)
#define HPAD 72   // padded fp16 weight stride (halves)

typedef _Float16 f16;
typedef _Float16 f16x2 __attribute__((ext_vector_type(2)));
typedef _Float16 f16x4 __attribute__((ext_vector_type(4)));
typedef _Float16 f16x8 __attribute__((ext_vector_type(8)));
typedef float f32x16 __attribute__((ext_vector_type(16)));

#define MFMA_F16(a, b, c) __builtin_amdgcn_mfma_f32_32x32x16_f16(a, b, c, 0, 0, 0)

__device__ __forceinline__ float selu_f(float x) {
    const float SC = 1.0507009873554805f;
    const float AL = 1.6732632423543772f;
    return x > 0.f ? SC * x : SC * AL * (expf(x) - 1.f);
}
__device__ __forceinline__ float sigmoid_f(float x) { return 1.f / (1.f + __expf(-x)); }
__device__ __forceinline__ float tanh_f(float x) {
    float s = x < 0.f ? -1.f : 1.f;
    float t = __expf(-2.f * fabsf(x));
    return s * (1.f - t) / (1.f + t);
}
__device__ __forceinline__ float dot8h(f16x8 a, f16x8 b, float acc) {
    f16x2 a0 = {a[0], a[1]}, b0 = {b[0], b[1]};
    f16x2 a1 = {a[2], a[3]}, b1 = {b[2], b[3]};
    f16x2 a2 = {a[4], a[5]}, b2 = {b[4], b[5]};
    f16x2 a3 = {a[6], a[7]}, b3 = {b[6], b[7]};
    acc = __builtin_amdgcn_fdot2(a0, b0, acc, false);
    acc = __builtin_amdgcn_fdot2(a1, b1, acc, false);
    acc = __builtin_amdgcn_fdot2(a2, b2, acc, false);
    acc = __builtin_amdgcn_fdot2(a3, b3, acc, false);
    return acc;
}
__device__ __forceinline__ f32x16 zero16() {
    f32x16 v;
#pragma unroll
    for (int i = 0; i < 16; ++i) v[i] = 0.f;
    return v;
}

// ---- A: y = x@Wy^T, z = x@Wz^T (fp16 weights/activations, fp32 accum) ----
__global__ void __launch_bounds__(1024) yz_kernel(const float* __restrict__ x,
                                                  const float* __restrict__ Wmsg,
                                                  f16* __restrict__ y16,
                                                  f16* __restrict__ z16, int N) {
    __shared__ __align__(16) f16 wbuf[2 * 64 * HPAD];  // 18 KB
    __shared__ __align__(16) f16 xs[16 * NB * 64];     // 16 KB
    for (int idx = threadIdx.x; idx < 2 * 64 * 64; idx += 1024) {
        int g = idx >> 12, rem = idx & 4095;
        int d = rem >> 6, j = rem & 63;
        wbuf[(g * 64 + d) * HPAD + j] = (f16)Wmsg[d * 128 + g * 64 + j];
    }
    __syncthreads();
    int lane = threadIdx.x & 63;
    int w = threadIdx.x >> 6;
    f16* xw = &xs[w * (NB * 64)];
    const f16* wy = wbuf;
    const f16* wz = wbuf + 64 * HPAD;
    int nbTot = (N + NB - 1) / NB;
    for (int nb = blockIdx.x * 16 + w; nb < nbTot; nb += gridDim.x * 16) {
        int n0 = nb * NB;
#pragma unroll
        for (int n = 0; n < NB; ++n) {
            int i = n0 + n;
            xw[n * 64 + lane] = (f16)((i < N) ? x[(size_t)i * 64 + lane] : 0.f);
        }
        float accy[NB], accz[NB];
#pragma unroll
        for (int n = 0; n < NB; ++n) { accy[n] = 0.f; accz[n] = 0.f; }
#pragma unroll 1
        for (int jg = 0; jg < 8; ++jg) {
            f16x8 wyv = *(const f16x8*)&wy[lane * HPAD + jg * 8];
            f16x8 wzv = *(const f16x8*)&wz[lane * HPAD + jg * 8];
#pragma unroll
            for (int n = 0; n < NB; ++n) {
                f16x8 xv = *(const f16x8*)&xw[n * 64 + jg * 8];  // uniform broadcast
                accy[n] = dot8h(wyv, xv, accy[n]);
                accz[n] = dot8h(wzv, xv, accz[n]);
            }
        }
#pragma unroll
        for (int n = 0; n < NB; ++n) {
            int i = n0 + n;
            if (i < N) {
                y16[(size_t)i * 64 + lane] = (f16)accy[n];
                z16[(size_t)i * 64 + lane] = (f16)accz[n];
            }
        }
    }
}

// ---- CSR build ----
__global__ void __launch_bounds__(256) count_kernel(const int* __restrict__ idn,
                                                    int* __restrict__ cnt, int E) {
    int i = blockIdx.x * blockDim.x + threadIdx.x;
    if (i < E) atomicAdd(&cnt[idn[i]], 1);
}

__global__ void __launch_bounds__(256) scan1_kernel(const int* __restrict__ cnt,
                                                    int* __restrict__ partial, int N) {
    __shared__ int s[256];
    int t = threadIdx.x;
    int i = blockIdx.x * 256 + t;
    s[t] = (i < N) ? cnt[i] : 0;
    __syncthreads();
    for (int off = 128; off > 0; off >>= 1) {
        if (t < off) s[t] += s[t + off];
        __syncthreads();
    }
    if (t == 0) partial[blockIdx.x] = s[0];
}

__global__ void __launch_bounds__(256) scan2_kernel(const int* __restrict__ partial,
                                                    int* __restrict__ offs,
                                                    int* __restrict__ row_start,
                                                    int G, int N) {
    __shared__ int s[256];
    int t = threadIdx.x;
    int v0 = (t < G) ? partial[t] : 0;
    s[t] = v0;
    __syncthreads();
    for (int off = 1; off < 256; off <<= 1) {
        int v = s[t];
        int u = (t >= off) ? s[t - off] : 0;
        __syncthreads();
        s[t] = v + u;
        __syncthreads();
    }
    if (t < G) offs[t] = s[t] - v0;  // exclusive
    if (t == 255) row_start[N] = s[255];
}

__global__ void __launch_bounds__(256) scan3_kernel(const int* __restrict__ cnt,
                                                    const int* __restrict__ offs,
                                                    int* __restrict__ row_start, int N) {
    __shared__ int s[256];
    int t = threadIdx.x;
    int i = blockIdx.x * 256 + t;
    int v0 = (i < N) ? cnt[i] : 0;
    s[t] = v0;
    __syncthreads();
    for (int off = 1; off < 256; off <<= 1) {
        int v = s[t];
        int u = (t >= off) ? s[t - off] : 0;
        __syncthreads();
        s[t] = v + u;
        __syncthreads();
    }
    if (i < N) row_start[i] = offs[blockIdx.x] + s[t] - v0;
}

__global__ void __launch_bounds__(256) fill_kernel(const int* __restrict__ idm,
                                                   const int* __restrict__ idn,
                                                   const int* __restrict__ row_start,
                                                   int* __restrict__ cursor,
                                                   int* __restrict__ csr_src, int E) {
    int i = blockIdx.x * blockDim.x + threadIdx.x;
    if (i < E) {
        int n = idn[i];
        int p = atomicAdd(&cursor[n], 1);
        csr_src[row_start[n] + p] = idm[i];
    }
}

// ---- B1: gather+selu -> M16 (one wave per node, no LDS, high occupancy) ----
__global__ void __launch_bounds__(256) gather_kernel(
    const f16* __restrict__ y16, const f16* __restrict__ z16,
    const float* __restrict__ bmsg, const int* __restrict__ row_start,
    const int* __restrict__ csr_src, f16* __restrict__ M16, int N) {
    int lane = threadIdx.x & 63;
    int wave = blockIdx.x * (blockDim.x >> 6) + (threadIdx.x >> 6);
    int nwaves = gridDim.x * (blockDim.x >> 6);
    float b = bmsg[lane];
    for (int i = wave; i < N; i += nwaves) {
        float zb = (float)z16[(size_t)i * 64 + lane] + b;
        int s0 = row_start[i], s1 = row_start[i + 1];
        float macc = 0.f;
        int s = s0;
        for (; s + 8 <= s1; s += 8) {
            int e0 = csr_src[s],     e1 = csr_src[s + 1];
            int e2 = csr_src[s + 2], e3 = csr_src[s + 3];
            int e4 = csr_src[s + 4], e5 = csr_src[s + 5];
            int e6 = csr_src[s + 6], e7 = csr_src[s + 7];
            float v0 = (float)y16[(size_t)e0 * 64 + lane];
            float v1 = (float)y16[(size_t)e1 * 64 + lane];
            float v2 = (float)y16[(size_t)e2 * 64 + lane];
            float v3 = (float)y16[(size_t)e3 * 64 + lane];
            float v4 = (float)y16[(size_t)e4 * 64 + lane];
            float v5 = (float)y16[(size_t)e5 * 64 + lane];
            float v6 = (float)y16[(size_t)e6 * 64 + lane];
            float v7 = (float)y16[(size_t)e7 * 64 + lane];
            macc += selu_f(v0 + zb);
            macc += selu_f(v1 + zb);
            macc += selu_f(v2 + zb);
            macc += selu_f(v3 + zb);
            macc += selu_f(v4 + zb);
            macc += selu_f(v5 + zb);
            macc += selu_f(v6 + zb);
            macc += selu_f(v7 + zb);
        }
        for (; s + 2 <= s1; s += 2) {
            int e0 = csr_src[s], e1 = csr_src[s + 1];
            float v0 = (float)y16[(size_t)e0 * 64 + lane];
            float v1 = (float)y16[(size_t)e1 * 64 + lane];
            macc += selu_f(v0 + zb);
            macc += selu_f(v1 + zb);
        }
        for (; s < s1; ++s)
            macc += selu_f((float)y16[(size_t)csr_src[s] * 64 + lane] + zb);
        M16[(size_t)i * 64 + lane] = (f16)macc;
    }
}

// ---- B2: MFMA GRU. One block = 64 nodes. D[node][dim] = x @ W^T per gate. ----
// LDS x/w tiles are [row][k] (128 B rows) with XOR swizzle k ^= (row&7)<<3.
__global__ void __launch_bounds__(256, 2) gru_kernel(
    const f16* __restrict__ M16, float* __restrict__ cur,
    const float* __restrict__ Wih, const float* __restrict__ Whh,
    const float* __restrict__ bih, const float* __restrict__ bhh, int N) {
    __shared__ __align__(16) f16 wlds[6 * 64 * 64];  // 48 KB, [g][d][k] swizzled by d
    __shared__ __align__(16) f16 xm[64 * 64];        // 8 KB, [node][k] swizzled
    __shared__ __align__(16) f16 xh[64 * 64];        // 8 KB
    int t = threadIdx.x;
    int base = blockIdx.x * 64;

    // stage weights: 6*64*64 halves, 8 per thread per iter
#pragma unroll 1
    for (int it = 0; it < 12; ++it) {
        int f = (it * 256 + t) * 8;
        int g = f >> 12;
        int rem = f & 4095;
        int d = rem >> 6, k0 = rem & 63;
        const float* src = ((g < 3) ? Wih : Whh) + (((g < 3 ? g : g - 3) * 64 + d) * 64 + k0);
        f16x8 v;
#pragma unroll
        for (int u = 0; u < 8; ++u) v[u] = (f16)src[u];
        *(f16x8*)&wlds[g * 4096 + d * 64 + (k0 ^ ((d & 7) << 3))] = v;
    }
    // stage M16: 64 nodes x 64 k halves, b128 per thread, 2 iters
#pragma unroll 1
    for (int it = 0; it < 2; ++it) {
        int idx = it * 256 + t;
        int node = idx >> 3, k0 = (idx & 7) * 8;
        int gn = base + node;
        f16x8 v;
        if (gn < N) v = *(const f16x8*)&M16[(size_t)gn * 64 + k0];
        else {
#pragma unroll
            for (int u = 0; u < 8; ++u) v[u] = (f16)0.f;
        }
        *(f16x8*)&xm[node * 64 + (k0 ^ ((node & 7) << 3))] = v;
    }
    // stage h (cur f32 -> f16): float4 per thread, 4 iters
#pragma unroll 1
    for (int it = 0; it < 4; ++it) {
        int idx = it * 256 + t;
        int node = idx >> 4, k0 = (idx & 15) * 4;
        int gn = base + node;
        f16x4 v;
        if (gn < N) {
            float4 f4 = *(const float4*)&cur[(size_t)gn * 64 + k0];
            v[0] = (f16)f4.x; v[1] = (f16)f4.y; v[2] = (f16)f4.z; v[3] = (f16)f4.w;
        } else {
#pragma unroll
            for (int u = 0; u < 4; ++u) v[u] = (f16)0.f;
        }
        *(f16x4*)&xh[node * 64 + (k0 ^ ((node & 7) << 3))] = v;
    }
    __syncthreads();

    int lane = t & 63;
    int w = t >> 6;         // 4 waves: 2 node-groups x 2 dim-halves
    int ng = w >> 1;
    int dh = w & 1;
    int arow = ng * 32 + (lane & 31);
    int arow64 = arow * 64;
    int axor = (arow & 7) << 3;
    int bcol = dh * 32 + (lane & 31);   // output dim
    int bxor = (bcol & 7) << 3;
    int kg = (lane >> 5) * 8;

    float bIR = bih[bcol], bIZ = bih[64 + bcol], bIN = bih[128 + bcol];
    float bHR = bhh[bcol], bHZ = bhh[64 + bcol], bHN = bhh[128 + bcol];

    f32x16 aIR = zero16(), aIZ = zero16(), aIN = zero16();
    f32x16 aHR = zero16(), aHZ = zero16(), aHN = zero16();
#pragma unroll
    for (int ks = 0; ks < 4; ++ks) {
        int kb = ks * 16 + kg;
        f16x8 am = *(const f16x8*)&xm[arow64 + (kb ^ axor)];
        f16x8 ah = *(const f16x8*)&xh[arow64 + (kb ^ axor)];
        int wof = bcol * 64 + (kb ^ bxor);
        aIR = MFMA_F16(am, *(const f16x8*)&wlds[0 * 4096 + wof], aIR);
        aIZ = MFMA_F16(am, *(const f16x8*)&wlds[1 * 4096 + wof], aIZ);
        aIN = MFMA_F16(am, *(const f16x8*)&wlds[2 * 4096 + wof], aIN);
        aHR = MFMA_F16(ah, *(const f16x8*)&wlds[3 * 4096 + wof], aHR);
        aHZ = MFMA_F16(ah, *(const f16x8*)&wlds[4 * 4096 + wof], aHZ);
        aHN = MFMA_F16(ah, *(const f16x8*)&wlds[5 * 4096 + wof], aHN);
    }

#pragma unroll
    for (int r = 0; r < 16; ++r) {
        int rowC = (r & 3) + 8 * (r >> 2) + 4 * (lane >> 5);
        int gn = base + ng * 32 + rowC;
        if (gn < N) {
            size_t o = (size_t)gn * 64 + bcol;
            float hold = cur[o];
            float rr = sigmoid_f(aIR[r] + bIR + aHR[r] + bHR);
            float zz = sigmoid_f(aIZ[r] + bIZ + aHZ[r] + bHZ);
            float nn = tanh_f(aIN[r] + bIN + rr * (aHN[r] + bHN));
            cur[o] = (1.f - zz) * nn + zz * hold;
        }
    }
}

__global__ void __launch_bounds__(256) pathsum_kernel(const float* __restrict__ h,
                                                      float* __restrict__ kp, int N, int K) {
    int per = N / K;
    int blocksPerPath = gridDim.x / K;
    int p = blockIdx.x / blocksPerPath;
    int c = blockIdx.x % blocksPerPath;
    int d = threadIdx.x & 63;
    int row0 = c * (blockDim.x >> 6) + (threadIdx.x >> 6);
    int stride = blocksPerPath * (blockDim.x >> 6);
    float acc = 0.f;
    for (int r = row0; r < per; r += stride) acc += h[((size_t)p * per + r) * 64 + d];
    __shared__ float red[256];
    red[threadIdx.x] = acc;
    __syncthreads();
    if (threadIdx.x < 64) {
        float s = red[threadIdx.x] + red[64 + threadIdx.x] + red[128 + threadIdx.x] +
                  red[192 + threadIdx.x];
        atomicAdd(&kp[p * 64 + threadIdx.x], s);
    }
}

__device__ __forceinline__ float dot4(float4 a, float4 b, float acc) {
    acc = fmaf(a.x, b.x, acc);
    acc = fmaf(a.y, b.y, acc);
    acc = fmaf(a.z, b.z, acc);
    return fmaf(a.w, b.w, acc);
}

__global__ void __launch_bounds__(256) readout1_kernel(const float* __restrict__ kp,
                                                       const float* __restrict__ Wr1,
                                                       const float* __restrict__ br1,
                                                       const float* __restrict__ Wr2,
                                                       const float* __restrict__ br2,
                                                       float* __restrict__ h2) {
    int p = blockIdx.x;
    int t = threadIdx.x;
    __shared__ __align__(16) float kps[64];
    __shared__ __align__(16) float h1[256];
    if (t < 64) kps[t] = kp[p * 64 + t];
    __syncthreads();
    float acc = br1[t];
#pragma unroll
    for (int d4 = 0; d4 < 16; ++d4) {
        float4 wv = *(const float4*)&Wr1[t * 64 + d4 * 4];
        float4 kv = *(const float4*)&kps[d4 * 4];
        acc = dot4(wv, kv, acc);
    }
    h1[t] = selu_f(acc);
    __syncthreads();
    float acc2 = br2[t];
#pragma unroll 8
    for (int j4 = 0; j4 < 64; ++j4) {
        float4 wv = *(const float4*)&Wr2[t * 256 + j4 * 4];
        float4 hv = *(const float4*)&h1[j4 * 4];
        acc2 = dot4(wv, hv, acc2);
    }
    h2[p * 256 + t] = selu_f(acc2);
}

__global__ void __launch_bounds__(256) readout2_kernel(const float* __restrict__ h2,
                                                       const float* __restrict__ Wr3,
                                                       const float* __restrict__ br3,
                                                       float* __restrict__ out) {
    __shared__ float red[256];
    __shared__ float lg[8];
    int t = threadIdx.x;
    float w3 = Wr3[t];
    for (int p = 0; p < 8; ++p) {
        red[t] = w3 * h2[p * 256 + t];
        __syncthreads();
        for (int off = 128; off > 0; off >>= 1) {
            if (t < off) red[t] += red[t + off];
            __syncthreads();
        }
        if (t == 0) lg[p] = red[0] + br3[0];
        __syncthreads();
    }
    if (t == 0) {
        float mx = lg[0];
        for (int p = 1; p < 8; ++p) mx = fmaxf(mx, lg[p]);
        float s = 0.f, e[8];
        for (int p = 0; p < 8; ++p) {
            e[p] = expf(lg[p] - mx);
            s += e[p];
        }
        for (int p = 0; p < 8; ++p) out[p] = e[p] / s;
    }
}

extern "C" void kernel_launch(void* const* d_in, const int* in_sizes, int n_in,
                              void* d_out, int out_size, void* d_ws, size_t ws_size,
                              hipStream_t stream) {
    const float* links_state = (const float*)d_in[0];
    const int* idm = (const int*)d_in[1];
    const int* idn = (const int*)d_in[2];
    const float* Wmsg = (const float*)d_in[3];
    const float* bmsg = (const float*)d_in[4];
    const float* Wih = (const float*)d_in[5];
    const float* Whh = (const float*)d_in[6];
    const float* bih = (const float*)d_in[7];
    const float* bhh = (const float*)d_in[8];
    const float* Wr1 = (const float*)d_in[9];
    const float* br1 = (const float*)d_in[10];
    const float* Wr2 = (const float*)d_in[11];
    const float* br2 = (const float*)d_in[12];
    const float* Wr3 = (const float*)d_in[13];
    const float* br3 = (const float*)d_in[14];

    const int N = in_sizes[0] / D;  // 50000
    const int E = in_sizes[1];      // 800000
    const int K = 8, T = 3;
    const int G = (N + 255) / 256;  // 196 scan blocks

    float* ws = (float*)d_ws;
    size_t nd = (size_t)N * D;
    float* cur = ws;                    // nd floats
    f16* y16 = (f16*)(ws + nd);         // nd halves
    f16* z16 = y16 + nd;                // nd halves
    f16* M16 = z16 + nd;                // nd halves
    float* kp = (float*)(M16 + nd);     // 512 floats
    float* h2 = kp + 512;               // 2048 floats
    int* ibase = (int*)(h2 + 2048);
    int* cnt = ibase;                   // N
    int* cursor = ibase + N;            // N
    int* row_start = ibase + 2 * N;     // N+1
    int* partial = row_start + N + 1;   // G
    int* offs = partial + G;            // G
    int* csr_src = offs + G;            // E

    // CSR build (once per launch)
    hipMemsetAsync(cnt, 0, (size_t)2 * N * sizeof(int), stream);  // cnt + cursor
    count_kernel<<<dim3((E + 255) / 256), dim3(256), 0, stream>>>(idn, cnt, E);
    scan1_kernel<<<dim3(G), dim3(256), 0, stream>>>(cnt, partial, N);
    scan2_kernel<<<dim3(1), dim3(256), 0, stream>>>(partial, offs, row_start, G, N);
    scan3_kernel<<<dim3(G), dim3(256), 0, stream>>>(cnt, offs, row_start, N);
    fill_kernel<<<dim3((E + 255) / 256), dim3(256), 0, stream>>>(idm, idn, row_start, cursor,
                                                                 csr_src, E);

    hipMemcpyAsync(cur, links_state, nd * sizeof(float), hipMemcpyDeviceToDevice, stream);

    int nbTot = (N + NB - 1) / NB;  // 6250
    int gridA = (nbTot + 15) / 16;  // 391
    int gridG = (N + 63) / 64;      // 782 (MFMA gru: 64 nodes/block)
    for (int t = 0; t < T; ++t) {
        yz_kernel<<<dim3(gridA), dim3(1024), 0, stream>>>(cur, Wmsg, y16, z16, N);
        gather_kernel<<<dim3(2048), dim3(256), 0, stream>>>(y16, z16, bmsg, row_start,
                                                            csr_src, M16, N);
        gru_kernel<<<dim3(gridG), dim3(256), 0, stream>>>(M16, cur, Wih, Whh, bih, bhh, N);
    }

    hipMemsetAsync(kp, 0, (size_t)K * 64 * sizeof(float), stream);
    pathsum_kernel<<<dim3(256), dim3(256), 0, stream>>>(cur, kp, N, K);
    readout1_kernel<<<dim3(8), dim3(256), 0, stream>>>(kp, Wr1, br1, Wr2, br2, h2);
    readout2_kernel<<<dim3(1), dim3(256), 0, stream>>>(h2, Wr3, br3, (float*)d_out);
}

// Round 13
// 332.595 us; speedup vs baseline: 2.9070x; 1.1320x over previous
//
#include <hip/hip_runtime.h>
#include <hip/hip_bf16.h>

#define D 64
#define NB 8      // nodes per wave-block (fdot2 yz kernel)
#define HPAD 72   // padded fp16 weight stride (halves)

typedef _Float16 f16;
typedef _Float16 f16x2 __attribute__((ext_vector_type(2)));
typedef _Float16 f16x4 __attribute__((ext_vector_type(4)));
typedef _Float16 f16x8 __attribute__((ext_vector_type(8)));
typedef float f32x16 __attribute__((ext_vector_type(16)));

#define MFMA_F16(a, b, c) __builtin_amdgcn_mfma_f32_32x32x16_f16(a, b, c, 0, 0, 0)

__device__ __forceinline__ float selu_f(float x) {
    const float SC = 1.0507009873554805f;
    const float AL = 1.6732632423543772f;
    return x > 0.f ? SC * x : SC * AL * (__expf(x) - 1.f);
}
__device__ __forceinline__ float sigmoid_f(float x) { return 1.f / (1.f + __expf(-x)); }
__device__ __forceinline__ float tanh_f(float x) {
    float s = x < 0.f ? -1.f : 1.f;
    float t = __expf(-2.f * fabsf(x));
    return s * (1.f - t) / (1.f + t);
}
__device__ __forceinline__ float dot8h(f16x8 a, f16x8 b, float acc) {
    f16x2 a0 = {a[0], a[1]}, b0 = {b[0], b[1]};
    f16x2 a1 = {a[2], a[3]}, b1 = {b[2], b[3]};
    f16x2 a2 = {a[4], a[5]}, b2 = {b[4], b[5]};
    f16x2 a3 = {a[6], a[7]}, b3 = {b[6], b[7]};
    acc = __builtin_amdgcn_fdot2(a0, b0, acc, false);
    acc = __builtin_amdgcn_fdot2(a1, b1, acc, false);
    acc = __builtin_amdgcn_fdot2(a2, b2, acc, false);
    acc = __builtin_amdgcn_fdot2(a3, b3, acc, false);
    return acc;
}
__device__ __forceinline__ float dot4(float4 a, float4 b, float acc) {
    acc = fmaf(a.x, b.x, acc);
    acc = fmaf(a.y, b.y, acc);
    acc = fmaf(a.z, b.z, acc);
    return fmaf(a.w, b.w, acc);
}
__device__ __forceinline__ f32x16 zero16() {
    f32x16 v;
#pragma unroll
    for (int i = 0; i < 16; ++i) v[i] = 0.f;
    return v;
}

// ---- Prologue only: y = x@Wy^T, z = x@Wz^T from f32 links_state ----
__global__ void __launch_bounds__(1024) yz_kernel(const float* __restrict__ x,
                                                  const float* __restrict__ Wmsg,
                                                  f16* __restrict__ y16,
                                                  f16* __restrict__ z16, int N) {
    __shared__ __align__(16) f16 wbuf[2 * 64 * HPAD];  // 18 KB
    __shared__ __align__(16) f16 xs[16 * NB * 64];     // 16 KB
    for (int idx = threadIdx.x; idx < 2 * 64 * 64; idx += 1024) {
        int g = idx >> 12, rem = idx & 4095;
        int d = rem >> 6, j = rem & 63;
        wbuf[(g * 64 + d) * HPAD + j] = (f16)Wmsg[d * 128 + g * 64 + j];
    }
    __syncthreads();
    int lane = threadIdx.x & 63;
    int w = threadIdx.x >> 6;
    f16* xw = &xs[w * (NB * 64)];
    const f16* wy = wbuf;
    const f16* wz = wbuf + 64 * HPAD;
    int nbTot = (N + NB - 1) / NB;
    for (int nb = blockIdx.x * 16 + w; nb < nbTot; nb += gridDim.x * 16) {
        int n0 = nb * NB;
#pragma unroll
        for (int n = 0; n < NB; ++n) {
            int i = n0 + n;
            xw[n * 64 + lane] = (f16)((i < N) ? x[(size_t)i * 64 + lane] : 0.f);
        }
        float accy[NB], accz[NB];
#pragma unroll
        for (int n = 0; n < NB; ++n) { accy[n] = 0.f; accz[n] = 0.f; }
#pragma unroll 1
        for (int jg = 0; jg < 8; ++jg) {
            f16x8 wyv = *(const f16x8*)&wy[lane * HPAD + jg * 8];
            f16x8 wzv = *(const f16x8*)&wz[lane * HPAD + jg * 8];
#pragma unroll
            for (int n = 0; n < NB; ++n) {
                f16x8 xv = *(const f16x8*)&xw[n * 64 + jg * 8];  // uniform broadcast
                accy[n] = dot8h(wyv, xv, accy[n]);
                accz[n] = dot8h(wzv, xv, accz[n]);
            }
        }
#pragma unroll
        for (int n = 0; n < NB; ++n) {
            int i = n0 + n;
            if (i < N) {
                y16[(size_t)i * 64 + lane] = (f16)accy[n];
                z16[(size_t)i * 64 + lane] = (f16)accz[n];
            }
        }
    }
}

// ---- CSR build ----
__global__ void __launch_bounds__(256) count_kernel(const int* __restrict__ idn,
                                                    int* __restrict__ cnt, int E) {
    int i = blockIdx.x * blockDim.x + threadIdx.x;
    if (i < E) atomicAdd(&cnt[idn[i]], 1);
}

__global__ void __launch_bounds__(256) scan1_kernel(const int* __restrict__ cnt,
                                                    int* __restrict__ partial, int N) {
    __shared__ int s[256];
    int t = threadIdx.x;
    int i = blockIdx.x * 256 + t;
    s[t] = (i < N) ? cnt[i] : 0;
    __syncthreads();
    for (int off = 128; off > 0; off >>= 1) {
        if (t < off) s[t] += s[t + off];
        __syncthreads();
    }
    if (t == 0) partial[blockIdx.x] = s[0];
}

__global__ void __launch_bounds__(256) scan2_kernel(const int* __restrict__ partial,
                                                    int* __restrict__ offs,
                                                    int* __restrict__ row_start,
                                                    int G, int N) {
    __shared__ int s[256];
    int t = threadIdx.x;
    int v0 = (t < G) ? partial[t] : 0;
    s[t] = v0;
    __syncthreads();
    for (int off = 1; off < 256; off <<= 1) {
        int v = s[t];
        int u = (t >= off) ? s[t - off] : 0;
        __syncthreads();
        s[t] = v + u;
        __syncthreads();
    }
    if (t < G) offs[t] = s[t] - v0;  // exclusive
    if (t == 255) row_start[N] = s[255];
}

__global__ void __launch_bounds__(256) scan3_kernel(const int* __restrict__ cnt,
                                                    const int* __restrict__ offs,
                                                    int* __restrict__ row_start, int N) {
    __shared__ int s[256];
    int t = threadIdx.x;
    int i = blockIdx.x * 256 + t;
    int v0 = (i < N) ? cnt[i] : 0;
    s[t] = v0;
    __syncthreads();
    for (int off = 1; off < 256; off <<= 1) {
        int v = s[t];
        int u = (t >= off) ? s[t - off] : 0;
        __syncthreads();
        s[t] = v + u;
        __syncthreads();
    }
    if (i < N) row_start[i] = offs[blockIdx.x] + s[t] - v0;
}

__global__ void __launch_bounds__(256) fill_kernel(const int* __restrict__ idm,
                                                   const int* __restrict__ idn,
                                                   const int* __restrict__ row_start,
                                                   int* __restrict__ cursor,
                                                   int* __restrict__ csr_src, int E) {
    int i = blockIdx.x * blockDim.x + threadIdx.x;
    if (i < E) {
        int n = idn[i];
        int p = atomicAdd(&cursor[n], 1);
        csr_src[row_start[n] + p] = idm[i];
    }
}

// ---- B1: gather+selu -> M16 (one wave per node, no LDS, high occupancy) ----
__global__ void __launch_bounds__(256) gather_kernel(
    const f16* __restrict__ y16, const f16* __restrict__ z16,
    const float* __restrict__ bmsg, const int* __restrict__ row_start,
    const int* __restrict__ csr_src, f16* __restrict__ M16, int N) {
    int lane = threadIdx.x & 63;
    int wave = blockIdx.x * (blockDim.x >> 6) + (threadIdx.x >> 6);
    int nwaves = gridDim.x * (blockDim.x >> 6);
    float b = bmsg[lane];
    for (int i = wave; i < N; i += nwaves) {
        float zb = (float)z16[(size_t)i * 64 + lane] + b;
        int s0 = row_start[i], s1 = row_start[i + 1];
        float macc = 0.f;
        int s = s0;
        for (; s + 8 <= s1; s += 8) {
            int e0 = csr_src[s],     e1 = csr_src[s + 1];
            int e2 = csr_src[s + 2], e3 = csr_src[s + 3];
            int e4 = csr_src[s + 4], e5 = csr_src[s + 5];
            int e6 = csr_src[s + 6], e7 = csr_src[s + 7];
            float v0 = (float)y16[(size_t)e0 * 64 + lane];
            float v1 = (float)y16[(size_t)e1 * 64 + lane];
            float v2 = (float)y16[(size_t)e2 * 64 + lane];
            float v3 = (float)y16[(size_t)e3 * 64 + lane];
            float v4 = (float)y16[(size_t)e4 * 64 + lane];
            float v5 = (float)y16[(size_t)e5 * 64 + lane];
            float v6 = (float)y16[(size_t)e6 * 64 + lane];
            float v7 = (float)y16[(size_t)e7 * 64 + lane];
            macc += selu_f(v0 + zb);
            macc += selu_f(v1 + zb);
            macc += selu_f(v2 + zb);
            macc += selu_f(v3 + zb);
            macc += selu_f(v4 + zb);
            macc += selu_f(v5 + zb);
            macc += selu_f(v6 + zb);
            macc += selu_f(v7 + zb);
        }
        for (; s + 2 <= s1; s += 2) {
            int e0 = csr_src[s], e1 = csr_src[s + 1];
            float v0 = (float)y16[(size_t)e0 * 64 + lane];
            float v1 = (float)y16[(size_t)e1 * 64 + lane];
            macc += selu_f(v0 + zb);
            macc += selu_f(v1 + zb);
        }
        for (; s < s1; ++s)
            macc += selu_f((float)y16[(size_t)csr_src[s] * 64 + lane] + zb);
        M16[(size_t)i * 64 + lane] = (f16)macc;
    }
}

// ---- B2: fused MFMA GRU + next-step y/z. One block = 64 nodes. ----
// LDS tiles [row][k] (128 B rows), XOR swizzle k ^= (row&7)<<3.
// wlds gates: 0..2 = Wih{r,z,n}, 3..5 = Whh{r,z,n}, 6 = Wy, 7 = Wz.
__global__ void __launch_bounds__(256, 2) gruyz_kernel(
    const f16* __restrict__ M16, float* __restrict__ cur,
    const float* __restrict__ Wih, const float* __restrict__ Whh,
    const float* __restrict__ bih, const float* __restrict__ bhh,
    const float* __restrict__ Wmsg, f16* __restrict__ y16, f16* __restrict__ z16,
    int N) {
    __shared__ __align__(16) f16 wlds[8 * 64 * 64];  // 64 KB
    __shared__ __align__(16) f16 xm[64 * 64];        // 8 KB (M, later h_new)
    __shared__ __align__(16) f16 xh[64 * 64];        // 8 KB (h_old)
    int t = threadIdx.x;
    int base = blockIdx.x * 64;

    // stage weights: 8 gates * 4096 halves, 8 per thread per iter -> 16 iters
#pragma unroll 1
    for (int it = 0; it < 16; ++it) {
        int f = (it * 256 + t) * 8;
        int g = f >> 12;
        int rem = f & 4095;
        int d = rem >> 6, k0 = rem & 63;
        const float* src;
        if (g < 3)      src = Wih + ((g * 64 + d) * 64 + k0);
        else if (g < 6) src = Whh + (((g - 3) * 64 + d) * 64 + k0);
        else            src = Wmsg + (d * 128 + (g - 6) * 64 + k0);
        f16x8 v;
#pragma unroll
        for (int u = 0; u < 8; ++u) v[u] = (f16)src[u];
        *(f16x8*)&wlds[g * 4096 + d * 64 + (k0 ^ ((d & 7) << 3))] = v;
    }
    // stage M16: b128 per thread, 2 iters
#pragma unroll 1
    for (int it = 0; it < 2; ++it) {
        int idx = it * 256 + t;
        int node = idx >> 3, k0 = (idx & 7) * 8;
        int gn = base + node;
        f16x8 v;
        if (gn < N) v = *(const f16x8*)&M16[(size_t)gn * 64 + k0];
        else {
#pragma unroll
            for (int u = 0; u < 8; ++u) v[u] = (f16)0.f;
        }
        *(f16x8*)&xm[node * 64 + (k0 ^ ((node & 7) << 3))] = v;
    }
    // stage h_old (cur f32 -> f16): float4 per thread, 4 iters
#pragma unroll 1
    for (int it = 0; it < 4; ++it) {
        int idx = it * 256 + t;
        int node = idx >> 4, k0 = (idx & 15) * 4;
        int gn = base + node;
        f16x4 v;
        if (gn < N) {
            float4 f4 = *(const float4*)&cur[(size_t)gn * 64 + k0];
            v[0] = (f16)f4.x; v[1] = (f16)f4.y; v[2] = (f16)f4.z; v[3] = (f16)f4.w;
        } else {
#pragma unroll
            for (int u = 0; u < 4; ++u) v[u] = (f16)0.f;
        }
        *(f16x4*)&xh[node * 64 + (k0 ^ ((node & 7) << 3))] = v;
    }
    __syncthreads();

    int lane = t & 63;
    int w = t >> 6;         // 4 waves: 2 node-groups x 2 dim-halves
    int ng = w >> 1;
    int dh = w & 1;
    int arow = ng * 32 + (lane & 31);
    int arow64 = arow * 64;
    int axor = (arow & 7) << 3;
    int bcol = dh * 32 + (lane & 31);   // output dim
    int bxor = (bcol & 7) << 3;
    int kg = (lane >> 5) * 8;

    float bIR = bih[bcol], bIZ = bih[64 + bcol], bIN = bih[128 + bcol];
    float bHR = bhh[bcol], bHZ = bhh[64 + bcol], bHN = bhh[128 + bcol];

    f32x16 aIR = zero16(), aIZ = zero16(), aIN = zero16();
    f32x16 aHR = zero16(), aHZ = zero16(), aHN = zero16();
#pragma unroll
    for (int ks = 0; ks < 4; ++ks) {
        int kb = ks * 16 + kg;
        f16x8 am = *(const f16x8*)&xm[arow64 + (kb ^ axor)];
        f16x8 ah = *(const f16x8*)&xh[arow64 + (kb ^ axor)];
        int wof = bcol * 64 + (kb ^ bxor);
        aIR = MFMA_F16(am, *(const f16x8*)&wlds[0 * 4096 + wof], aIR);
        aIZ = MFMA_F16(am, *(const f16x8*)&wlds[1 * 4096 + wof], aIZ);
        aIN = MFMA_F16(am, *(const f16x8*)&wlds[2 * 4096 + wof], aIN);
        aHR = MFMA_F16(ah, *(const f16x8*)&wlds[3 * 4096 + wof], aHR);
        aHZ = MFMA_F16(ah, *(const f16x8*)&wlds[4 * 4096 + wof], aHZ);
        aHN = MFMA_F16(ah, *(const f16x8*)&wlds[5 * 4096 + wof], aHN);
    }

    __syncthreads();  // all waves done reading xm/xh; xm will be overwritten

    // epilogue-1: h_new per reg; write cur (f32) + xm (f16, swizzled)
#pragma unroll
    for (int r = 0; r < 16; ++r) {
        int rowC = (r & 3) + 8 * (r >> 2) + 4 * (lane >> 5);
        int nodeLocal = ng * 32 + rowC;
        int gn = base + nodeLocal;
        float hnew = 0.f;
        if (gn < N) {
            size_t o = (size_t)gn * 64 + bcol;
            float hold = cur[o];
            float rr = sigmoid_f(aIR[r] + bIR + aHR[r] + bHR);
            float zz = sigmoid_f(aIZ[r] + bIZ + aHZ[r] + bHZ);
            float nn = tanh_f(aIN[r] + bIN + rr * (aHN[r] + bHN));
            hnew = (1.f - zz) * nn + zz * hold;
            cur[o] = hnew;
        }
        xm[nodeLocal * 64 + (bcol ^ ((rowC & 7) << 3))] = (f16)hnew;
    }
    __syncthreads();

    // y/z for the next step: y = h_new @ Wy^T, z = h_new @ Wz^T
    f32x16 aY = zero16(), aZ = zero16();
#pragma unroll
    for (int ks = 0; ks < 4; ++ks) {
        int kb = ks * 16 + kg;
        f16x8 ahn2 = *(const f16x8*)&xm[arow64 + (kb ^ axor)];
        int wof = bcol * 64 + (kb ^ bxor);
        aY = MFMA_F16(ahn2, *(const f16x8*)&wlds[6 * 4096 + wof], aY);
        aZ = MFMA_F16(ahn2, *(const f16x8*)&wlds[7 * 4096 + wof], aZ);
    }
#pragma unroll
    for (int r = 0; r < 16; ++r) {
        int rowC = (r & 3) + 8 * (r >> 2) + 4 * (lane >> 5);
        int gn = base + ng * 32 + rowC;
        if (gn < N) {
            size_t o = (size_t)gn * 64 + bcol;
            y16[o] = (f16)aY[r];
            z16[o] = (f16)aZ[r];
        }
    }
}

__global__ void __launch_bounds__(256) pathsum_kernel(const float* __restrict__ h,
                                                      float* __restrict__ kp, int N, int K) {
    int per = N / K;
    int blocksPerPath = gridDim.x / K;
    int p = blockIdx.x / blocksPerPath;
    int c = blockIdx.x % blocksPerPath;
    int d = threadIdx.x & 63;
    int row0 = c * (blockDim.x >> 6) + (threadIdx.x >> 6);
    int stride = blocksPerPath * (blockDim.x >> 6);
    float acc = 0.f;
    for (int r = row0; r < per; r += stride) acc += h[((size_t)p * per + r) * 64 + d];
    __shared__ float red[256];
    red[threadIdx.x] = acc;
    __syncthreads();
    if (threadIdx.x < 64) {
        float s = red[threadIdx.x] + red[64 + threadIdx.x] + red[128 + threadIdx.x] +
                  red[192 + threadIdx.x];
        atomicAdd(&kp[p * 64 + threadIdx.x], s);
    }
}

__global__ void __launch_bounds__(256) readout1_kernel(const float* __restrict__ kp,
                                                       const float* __restrict__ Wr1,
                                                       const float* __restrict__ br1,
                                                       const float* __restrict__ Wr2,
                                                       const float* __restrict__ br2,
                                                       float* __restrict__ h2) {
    int p = blockIdx.x;
    int t = threadIdx.x;
    __shared__ __align__(16) float kps[64];
    __shared__ __align__(16) float h1[256];
    if (t < 64) kps[t] = kp[p * 64 + t];
    __syncthreads();
    float acc = br1[t];
#pragma unroll
    for (int d4 = 0; d4 < 16; ++d4) {
        float4 wv = *(const float4*)&Wr1[t * 64 + d4 * 4];
        float4 kv = *(const float4*)&kps[d4 * 4];
        acc = dot4(wv, kv, acc);
    }
    h1[t] = selu_f(acc);
    __syncthreads();
    float acc2 = br2[t];
#pragma unroll 8
    for (int j4 = 0; j4 < 64; ++j4) {
        float4 wv = *(const float4*)&Wr2[t * 256 + j4 * 4];
        float4 hv = *(const float4*)&h1[j4 * 4];
        acc2 = dot4(wv, hv, acc2);
    }
    h2[p * 256 + t] = selu_f(acc2);
}

__global__ void __launch_bounds__(256) readout2_kernel(const float* __restrict__ h2,
                                                       const float* __restrict__ Wr3,
                                                       const float* __restrict__ br3,
                                                       float* __restrict__ out) {
    __shared__ float red[256];
    __shared__ float lg[8];
    int t = threadIdx.x;
    float w3 = Wr3[t];
    for (int p = 0; p < 8; ++p) {
        red[t] = w3 * h2[p * 256 + t];
        __syncthreads();
        for (int off = 128; off > 0; off >>= 1) {
            if (t < off) red[t] += red[t + off];
            __syncthreads();
        }
        if (t == 0) lg[p] = red[0] + br3[0];
        __syncthreads();
    }
    if (t == 0) {
        float mx = lg[0];
        for (int p = 1; p < 8; ++p) mx = fmaxf(mx, lg[p]);
        float s = 0.f, e[8];
        for (int p = 0; p < 8; ++p) {
            e[p] = expf(lg[p] - mx);
            s += e[p];
        }
        for (int p = 0; p < 8; ++p) out[p] = e[p] / s;
    }
}

extern "C" void kernel_launch(void* const* d_in, const int* in_sizes, int n_in,
                              void* d_out, int out_size, void* d_ws, size_t ws_size,
                              hipStream_t stream) {
    const float* links_state = (const float*)d_in[0];
    const int* idm = (const int*)d_in[1];
    const int* idn = (const int*)d_in[2];
    const float* Wmsg = (const float*)d_in[3];
    const float* bmsg = (const float*)d_in[4];
    const float* Wih = (const float*)d_in[5];
    const float* Whh = (const float*)d_in[6];
    const float* bih = (const float*)d_in[7];
    const float* bhh = (const float*)d_in[8];
    const float* Wr1 = (const float*)d_in[9];
    const float* br1 = (const float*)d_in[10];
    const float* Wr2 = (const float*)d_in[11];
    const float* br2 = (const float*)d_in[12];
    const float* Wr3 = (const float*)d_in[13];
    const float* br3 = (const float*)d_in[14];

    const int N = in_sizes[0] / D;  // 50000
    const int E = in_sizes[1];      // 800000
    const int K = 8, T = 3;
    const int G = (N + 255) / 256;  // 196 scan blocks

    float* ws = (float*)d_ws;
    size_t nd = (size_t)N * D;
    float* cur = ws;                    // nd floats
    f16* y16 = (f16*)(ws + nd);         // nd halves
    f16* z16 = y16 + nd;                // nd halves
    f16* M16 = z16 + nd;                // nd halves
    float* kp = (float*)(M16 + nd);     // 512 floats
    float* h2 = kp + 512;               // 2048 floats
    int* ibase = (int*)(h2 + 2048);
    int* cnt = ibase;                   // N
    int* cursor = ibase + N;            // N
    int* row_start = ibase + 2 * N;     // N+1
    int* partial = row_start + N + 1;   // G
    int* offs = partial + G;            // G
    int* csr_src = offs + G;            // E

    // CSR build (once per launch)
    hipMemsetAsync(cnt, 0, (size_t)2 * N * sizeof(int), stream);  // cnt + cursor
    count_kernel<<<dim3((E + 255) / 256), dim3(256), 0, stream>>>(idn, cnt, E);
    scan1_kernel<<<dim3(G), dim3(256), 0, stream>>>(cnt, partial, N);
    scan2_kernel<<<dim3(1), dim3(256), 0, stream>>>(partial, offs, row_start, G, N);
    scan3_kernel<<<dim3(G), dim3(256), 0, stream>>>(cnt, offs, row_start, N);
    fill_kernel<<<dim3((E + 255) / 256), dim3(256), 0, stream>>>(idm, idn, row_start, cursor,
                                                                 csr_src, E);

    hipMemcpyAsync(cur, links_state, nd * sizeof(float), hipMemcpyDeviceToDevice, stream);

    int nbTot = (N + NB - 1) / NB;  // 6250
    int gridA = (nbTot + 15) / 16;  // 391
    int gridG = (N + 63) / 64;      // 782 (MFMA: 64 nodes/block)
    yz_kernel<<<dim3(gridA), dim3(1024), 0, stream>>>(cur, Wmsg, y16, z16, N);
    for (int t = 0; t < T; ++t) {
        gather_kernel<<<dim3(2048), dim3(256), 0, stream>>>(y16, z16, bmsg, row_start,
                                                            csr_src, M16, N);
        gruyz_kernel<<<dim3(gridG), dim3(256), 0, stream>>>(M16, cur, Wih, Whh, bih, bhh,
                                                            Wmsg, y16, z16, N);
    }

    hipMemsetAsync(kp, 0, (size_t)K * 64 * sizeof(float), stream);
    pathsum_kernel<<<dim3(256), dim3(256), 0, stream>>>(cur, kp, N, K);
    readout1_kernel<<<dim3(8), dim3(256), 0, stream>>>(kp, Wr1, br1, Wr2, br2, h2);
    readout2_kernel<<<dim3(1), dim3(256), 0, stream>>>(h2, Wr3, br3, (float*)d_out);
}

// Round 14
// 294.330 us; speedup vs baseline: 3.2850x; 1.1300x over previous
//
#include <hip/hip_runtime.h>
#include <hip/hip_bf16.h>

#define D 64

typedef _Float16 f16;
typedef _Float16 f16x2 __attribute__((ext_vector_type(2)));
typedef _Float16 f16x4 __attribute__((ext_vector_type(4)));
typedef _Float16 f16x8 __attribute__((ext_vector_type(8)));
typedef float f32x16 __attribute__((ext_vector_type(16)));

#define MFMA_F16(a, b, c) __builtin_amdgcn_mfma_f32_32x32x16_f16(a, b, c, 0, 0, 0)

__device__ __forceinline__ float selu_f(float x) {
    const float SC = 1.0507009873554805f;
    const float AL = 1.6732632423543772f;
    return x > 0.f ? SC * x : SC * AL * (__expf(x) - 1.f);
}
__device__ __forceinline__ float sigmoid_f(float x) { return 1.f / (1.f + __expf(-x)); }
__device__ __forceinline__ float tanh_f(float x) {
    float s = x < 0.f ? -1.f : 1.f;
    float t = __expf(-2.f * fabsf(x));
    return s * (1.f - t) / (1.f + t);
}
__device__ __forceinline__ float dot4(float4 a, float4 b, float acc) {
    acc = fmaf(a.x, b.x, acc);
    acc = fmaf(a.y, b.y, acc);
    acc = fmaf(a.z, b.z, acc);
    return fmaf(a.w, b.w, acc);
}
__device__ __forceinline__ f32x16 zero16() {
    f32x16 v;
#pragma unroll
    for (int i = 0; i < 16; ++i) v[i] = 0.f;
    return v;
}

// ---- once: pack 8 gate matrices to f16 with LDS swizzle pre-baked ----
// gates 0..2 = Wih{r,z,n}, 3..5 = Whh{r,z,n}, 6 = Wy, 7 = Wz
__global__ void __launch_bounds__(256) pack_kernel(const float* __restrict__ Wih,
                                                   const float* __restrict__ Whh,
                                                   const float* __restrict__ Wmsg,
                                                   f16* __restrict__ w16) {
    int idx = blockIdx.x * 256 + threadIdx.x;  // [0, 32768)
    int g = idx >> 12;
    int rem = idx & 4095;
    int d = rem >> 6, k0 = rem & 63;
    float v;
    if (g < 3)      v = Wih[(g * 64 + d) * 64 + k0];
    else if (g < 6) v = Whh[((g - 3) * 64 + d) * 64 + k0];
    else            v = Wmsg[d * 128 + (g - 6) * 64 + k0];
    w16[g * 4096 + d * 64 + (k0 ^ ((d & 7) << 3))] = (f16)v;
}

// ---- CSR build ----
__global__ void __launch_bounds__(256) count_kernel(const int* __restrict__ idn,
                                                    int* __restrict__ cnt, int E) {
    int i = blockIdx.x * blockDim.x + threadIdx.x;
    if (i < E) atomicAdd(&cnt[idn[i]], 1);
}

__global__ void __launch_bounds__(256) scan1_kernel(const int* __restrict__ cnt,
                                                    int* __restrict__ partial, int N) {
    __shared__ int s[256];
    int t = threadIdx.x;
    int i = blockIdx.x * 256 + t;
    s[t] = (i < N) ? cnt[i] : 0;
    __syncthreads();
    for (int off = 128; off > 0; off >>= 1) {
        if (t < off) s[t] += s[t + off];
        __syncthreads();
    }
    if (t == 0) partial[blockIdx.x] = s[0];
}

__global__ void __launch_bounds__(256) scan2_kernel(const int* __restrict__ partial,
                                                    int* __restrict__ offs,
                                                    int* __restrict__ row_start,
                                                    int G, int N) {
    __shared__ int s[256];
    int t = threadIdx.x;
    int v0 = (t < G) ? partial[t] : 0;
    s[t] = v0;
    __syncthreads();
    for (int off = 1; off < 256; off <<= 1) {
        int v = s[t];
        int u = (t >= off) ? s[t - off] : 0;
        __syncthreads();
        s[t] = v + u;
        __syncthreads();
    }
    if (t < G) offs[t] = s[t] - v0;  // exclusive
    if (t == 255) row_start[N] = s[255];
}

__global__ void __launch_bounds__(256) scan3_kernel(const int* __restrict__ cnt,
                                                    const int* __restrict__ offs,
                                                    int* __restrict__ row_start, int N) {
    __shared__ int s[256];
    int t = threadIdx.x;
    int i = blockIdx.x * 256 + t;
    int v0 = (i < N) ? cnt[i] : 0;
    s[t] = v0;
    __syncthreads();
    for (int off = 1; off < 256; off <<= 1) {
        int v = s[t];
        int u = (t >= off) ? s[t - off] : 0;
        __syncthreads();
        s[t] = v + u;
        __syncthreads();
    }
    if (i < N) row_start[i] = offs[blockIdx.x] + s[t] - v0;
}

__global__ void __launch_bounds__(256) fill_kernel(const int* __restrict__ idm,
                                                   const int* __restrict__ idn,
                                                   const int* __restrict__ row_start,
                                                   int* __restrict__ cursor,
                                                   int* __restrict__ csr_src, int E) {
    int i = blockIdx.x * blockDim.x + threadIdx.x;
    if (i < E) {
        int n = idn[i];
        int p = atomicAdd(&cursor[n], 1);
        csr_src[row_start[n] + p] = idm[i];
    }
}

// ---- B1: pair-gather. 2 edges per wave step; lane = (edge-half, dim-pair). ----
__global__ void __launch_bounds__(256) gather_kernel(
    const f16* __restrict__ y16, const f16* __restrict__ z16,
    const float* __restrict__ bmsg, const int* __restrict__ row_start,
    const int* __restrict__ csr_src, f16* __restrict__ M16, int N) {
    int lane = threadIdx.x & 63;
    int sub = lane >> 5;            // which edge of the pair
    int d0 = (lane & 31) * 2;       // dim pair
    int wave = blockIdx.x * (blockDim.x >> 6) + (threadIdx.x >> 6);
    int nwaves = gridDim.x * (blockDim.x >> 6);
    float b0 = bmsg[d0], b1 = bmsg[d0 + 1];
    for (int i = wave; i < N; i += nwaves) {
        f16x2 zv = *(const f16x2*)&z16[(size_t)i * 64 + d0];
        float zb0 = (float)zv[0] + b0;
        float zb1 = (float)zv[1] + b1;
        int s1 = row_start[i + 1];
        float m0 = 0.f, m1 = 0.f;
        int s = row_start[i] + sub;
        for (; s + 6 < s1; s += 8) {
            int e0 = csr_src[s],     e1 = csr_src[s + 2];
            int e2 = csr_src[s + 4], e3 = csr_src[s + 6];
            f16x2 v0 = *(const f16x2*)&y16[(size_t)e0 * 64 + d0];
            f16x2 v1 = *(const f16x2*)&y16[(size_t)e1 * 64 + d0];
            f16x2 v2 = *(const f16x2*)&y16[(size_t)e2 * 64 + d0];
            f16x2 v3 = *(const f16x2*)&y16[(size_t)e3 * 64 + d0];
            m0 += selu_f((float)v0[0] + zb0);
            m1 += selu_f((float)v0[1] + zb1);
            m0 += selu_f((float)v1[0] + zb0);
            m1 += selu_f((float)v1[1] + zb1);
            m0 += selu_f((float)v2[0] + zb0);
            m1 += selu_f((float)v2[1] + zb1);
            m0 += selu_f((float)v3[0] + zb0);
            m1 += selu_f((float)v3[1] + zb1);
        }
        for (; s < s1; s += 2) {
            int e0 = csr_src[s];
            f16x2 v0 = *(const f16x2*)&y16[(size_t)e0 * 64 + d0];
            m0 += selu_f((float)v0[0] + zb0);
            m1 += selu_f((float)v0[1] + zb1);
        }
        m0 += __shfl_xor(m0, 32, 64);
        m1 += __shfl_xor(m1, 32, 64);
        if (sub == 0) {
            f16x2 mv; mv[0] = (f16)m0; mv[1] = (f16)m1;
            *(f16x2*)&M16[(size_t)i * 64 + d0] = mv;
        }
    }
}

// ---- step 0 prologue: y,z = x@W via MFMA (gates 6,7 of w16) ----
__global__ void __launch_bounds__(256, 2) yz0_kernel(
    const float* __restrict__ cur, const f16* __restrict__ w16,
    f16* __restrict__ y16, f16* __restrict__ z16, int N, int NT) {
    __shared__ __align__(16) f16 wlds[2 * 4096];  // 16 KB
    __shared__ __align__(16) f16 xh[64 * 64];     // 8 KB
    int t = threadIdx.x;
#pragma unroll
    for (int it = 0; it < 4; ++it) {
        int idx = (it * 256 + t) * 8;
        *(f16x8*)&wlds[idx] = *(const f16x8*)&w16[6 * 4096 + idx];
    }
    int lane = t & 63;
    int w = t >> 6;
    int ng = w >> 1;
    int dh = w & 1;
    int arow = ng * 32 + (lane & 31);
    int arow64 = arow * 64;
    int axor = (arow & 7) << 3;
    int bcol = dh * 32 + (lane & 31);
    int bxor = (bcol & 7) << 3;
    int kg = (lane >> 5) * 8;
    __syncthreads();
    for (int tile = blockIdx.x; tile < NT; tile += gridDim.x) {
        int base = tile * 64;
#pragma unroll
        for (int it = 0; it < 4; ++it) {
            int idx = it * 256 + t;
            int node = idx >> 4, k0 = (idx & 15) * 4;
            int gn = base + node;
            f16x4 v;
            if (gn < N) {
                float4 f4 = *(const float4*)&cur[(size_t)gn * 64 + k0];
                v[0] = (f16)f4.x; v[1] = (f16)f4.y; v[2] = (f16)f4.z; v[3] = (f16)f4.w;
            } else {
#pragma unroll
                for (int u = 0; u < 4; ++u) v[u] = (f16)0.f;
            }
            *(f16x4*)&xh[node * 64 + (k0 ^ ((node & 7) << 3))] = v;
        }
        __syncthreads();
        f32x16 aY = zero16(), aZ = zero16();
#pragma unroll
        for (int ks = 0; ks < 4; ++ks) {
            int kb = ks * 16 + kg;
            f16x8 ah = *(const f16x8*)&xh[arow64 + (kb ^ axor)];
            int wof = bcol * 64 + (kb ^ bxor);
            aY = MFMA_F16(ah, *(const f16x8*)&wlds[0 * 4096 + wof], aY);
            aZ = MFMA_F16(ah, *(const f16x8*)&wlds[1 * 4096 + wof], aZ);
        }
#pragma unroll
        for (int r = 0; r < 16; ++r) {
            int rowC = (r & 3) + 8 * (r >> 2) + 4 * (lane >> 5);
            int gn = base + ng * 32 + rowC;
            if (gn < N) {
                size_t o = (size_t)gn * 64 + bcol;
                y16[o] = (f16)aY[r];
                z16[o] = (f16)aZ[r];
            }
        }
        __syncthreads();
    }
}

// ---- B2: fused MFMA GRU (+ next-step y/z when doYZ). Grid-stride tiles. ----
__global__ void __launch_bounds__(256, 2) gruyz_kernel(
    const f16* __restrict__ M16, float* __restrict__ cur,
    const float* __restrict__ bih, const float* __restrict__ bhh,
    const f16* __restrict__ w16, f16* __restrict__ y16, f16* __restrict__ z16,
    int N, int NT, int doYZ) {
    __shared__ __align__(16) f16 wlds[8 * 4096];  // 64 KB
    __shared__ __align__(16) f16 xm[64 * 64];     // 8 KB (M, then h_new)
    __shared__ __align__(16) f16 xh[64 * 64];     // 8 KB (h_old)
    int t = threadIdx.x;
#pragma unroll 4
    for (int it = 0; it < 16; ++it) {
        int idx = (it * 256 + t) * 8;
        *(f16x8*)&wlds[idx] = *(const f16x8*)&w16[idx];
    }
    int lane = t & 63;
    int w = t >> 6;
    int ng = w >> 1;
    int dh = w & 1;
    int arow = ng * 32 + (lane & 31);
    int arow64 = arow * 64;
    int axor = (arow & 7) << 3;
    int bcol = dh * 32 + (lane & 31);
    int bxor = (bcol & 7) << 3;
    int kg = (lane >> 5) * 8;
    float bIR = bih[bcol], bIZ = bih[64 + bcol], bIN = bih[128 + bcol];
    float bHR = bhh[bcol], bHZ = bhh[64 + bcol], bHN = bhh[128 + bcol];
    __syncthreads();
    for (int tile = blockIdx.x; tile < NT; tile += gridDim.x) {
        int base = tile * 64;
#pragma unroll
        for (int it = 0; it < 2; ++it) {
            int idx = it * 256 + t;
            int node = idx >> 3, k0 = (idx & 7) * 8;
            int gn = base + node;
            f16x8 v;
            if (gn < N) v = *(const f16x8*)&M16[(size_t)gn * 64 + k0];
            else {
#pragma unroll
                for (int u = 0; u < 8; ++u) v[u] = (f16)0.f;
            }
            *(f16x8*)&xm[node * 64 + (k0 ^ ((node & 7) << 3))] = v;
        }
#pragma unroll
        for (int it = 0; it < 4; ++it) {
            int idx = it * 256 + t;
            int node = idx >> 4, k0 = (idx & 15) * 4;
            int gn = base + node;
            f16x4 v;
            if (gn < N) {
                float4 f4 = *(const float4*)&cur[(size_t)gn * 64 + k0];
                v[0] = (f16)f4.x; v[1] = (f16)f4.y; v[2] = (f16)f4.z; v[3] = (f16)f4.w;
            } else {
#pragma unroll
                for (int u = 0; u < 4; ++u) v[u] = (f16)0.f;
            }
            *(f16x4*)&xh[node * 64 + (k0 ^ ((node & 7) << 3))] = v;
        }
        __syncthreads();

        f32x16 aIR = zero16(), aIZ = zero16(), aIN = zero16();
        f32x16 aHR = zero16(), aHZ = zero16(), aHN = zero16();
#pragma unroll
        for (int ks = 0; ks < 4; ++ks) {
            int kb = ks * 16 + kg;
            f16x8 am = *(const f16x8*)&xm[arow64 + (kb ^ axor)];
            f16x8 ah = *(const f16x8*)&xh[arow64 + (kb ^ axor)];
            int wof = bcol * 64 + (kb ^ bxor);
            aIR = MFMA_F16(am, *(const f16x8*)&wlds[0 * 4096 + wof], aIR);
            aIZ = MFMA_F16(am, *(const f16x8*)&wlds[1 * 4096 + wof], aIZ);
            aIN = MFMA_F16(am, *(const f16x8*)&wlds[2 * 4096 + wof], aIN);
            aHR = MFMA_F16(ah, *(const f16x8*)&wlds[3 * 4096 + wof], aHR);
            aHZ = MFMA_F16(ah, *(const f16x8*)&wlds[4 * 4096 + wof], aHZ);
            aHN = MFMA_F16(ah, *(const f16x8*)&wlds[5 * 4096 + wof], aHN);
        }
        __syncthreads();  // all waves done reading xm/xh

        // epilogue: h_new per reg; write cur (f32) (+ xm f16 if doYZ)
#pragma unroll
        for (int r = 0; r < 16; ++r) {
            int rowC = (r & 3) + 8 * (r >> 2) + 4 * (lane >> 5);
            int nodeLocal = ng * 32 + rowC;
            int gn = base + nodeLocal;
            float hnew = 0.f;
            if (gn < N) {
                size_t o = (size_t)gn * 64 + bcol;
                float hold = cur[o];
                float rr = sigmoid_f(aIR[r] + bIR + aHR[r] + bHR);
                float zz = sigmoid_f(aIZ[r] + bIZ + aHZ[r] + bHZ);
                float nn = tanh_f(aIN[r] + bIN + rr * (aHN[r] + bHN));
                hnew = (1.f - zz) * nn + zz * hold;
                cur[o] = hnew;
            }
            if (doYZ) xm[nodeLocal * 64 + (bcol ^ ((rowC & 7) << 3))] = (f16)hnew;
        }
        if (doYZ) {
            __syncthreads();
            f32x16 aY = zero16(), aZ = zero16();
#pragma unroll
            for (int ks = 0; ks < 4; ++ks) {
                int kb = ks * 16 + kg;
                f16x8 ahn2 = *(const f16x8*)&xm[arow64 + (kb ^ axor)];
                int wof = bcol * 64 + (kb ^ bxor);
                aY = MFMA_F16(ahn2, *(const f16x8*)&wlds[6 * 4096 + wof], aY);
                aZ = MFMA_F16(ahn2, *(const f16x8*)&wlds[7 * 4096 + wof], aZ);
            }
#pragma unroll
            for (int r = 0; r < 16; ++r) {
                int rowC = (r & 3) + 8 * (r >> 2) + 4 * (lane >> 5);
                int gn = base + ng * 32 + rowC;
                if (gn < N) {
                    size_t o = (size_t)gn * 64 + bcol;
                    y16[o] = (f16)aY[r];
                    z16[o] = (f16)aZ[r];
                }
            }
        }
        __syncthreads();  // before next tile overwrites xm/xh
    }
}

__global__ void __launch_bounds__(256) pathsum_kernel(const float* __restrict__ h,
                                                      float* __restrict__ kp, int N, int K) {
    int per = N / K;
    int blocksPerPath = gridDim.x / K;
    int p = blockIdx.x / blocksPerPath;
    int c = blockIdx.x % blocksPerPath;
    int d = threadIdx.x & 63;
    int row0 = c * (blockDim.x >> 6) + (threadIdx.x >> 6);
    int stride = blocksPerPath * (blockDim.x >> 6);
    float acc = 0.f;
    for (int r = row0; r < per; r += stride) acc += h[((size_t)p * per + r) * 64 + d];
    __shared__ float red[256];
    red[threadIdx.x] = acc;
    __syncthreads();
    if (threadIdx.x < 64) {
        float s = red[threadIdx.x] + red[64 + threadIdx.x] + red[128 + threadIdx.x] +
                  red[192 + threadIdx.x];
        atomicAdd(&kp[p * 64 + threadIdx.x], s);
    }
}

__global__ void __launch_bounds__(256) readout1_kernel(const float* __restrict__ kp,
                                                       const float* __restrict__ Wr1,
                                                       const float* __restrict__ br1,
                                                       const float* __restrict__ Wr2,
                                                       const float* __restrict__ br2,
                                                       float* __restrict__ h2) {
    int p = blockIdx.x;
    int t = threadIdx.x;
    __shared__ __align__(16) float kps[64];
    __shared__ __align__(16) float h1[256];
    if (t < 64) kps[t] = kp[p * 64 + t];
    __syncthreads();
    float acc = br1[t];
#pragma unroll
    for (int d4 = 0; d4 < 16; ++d4) {
        float4 wv = *(const float4*)&Wr1[t * 64 + d4 * 4];
        float4 kv = *(const float4*)&kps[d4 * 4];
        acc = dot4(wv, kv, acc);
    }
    h1[t] = selu_f(acc);
    __syncthreads();
    float acc2 = br2[t];
#pragma unroll 8
    for (int j4 = 0; j4 < 64; ++j4) {
        float4 wv = *(const float4*)&Wr2[t * 256 + j4 * 4];
        float4 hv = *(const float4*)&h1[j4 * 4];
        acc2 = dot4(wv, hv, acc2);
    }
    h2[p * 256 + t] = selu_f(acc2);
}

__global__ void __launch_bounds__(256) readout2_kernel(const float* __restrict__ h2,
                                                       const float* __restrict__ Wr3,
                                                       const float* __restrict__ br3,
                                                       float* __restrict__ out) {
    __shared__ float red[256];
    __shared__ float lg[8];
    int t = threadIdx.x;
    float w3 = Wr3[t];
    for (int p = 0; p < 8; ++p) {
        red[t] = w3 * h2[p * 256 + t];
        __syncthreads();
        for (int off = 128; off > 0; off >>= 1) {
            if (t < off) red[t] += red[t + off];
            __syncthreads();
        }
        if (t == 0) lg[p] = red[0] + br3[0];
        __syncthreads();
    }
    if (t == 0) {
        float mx = lg[0];
        for (int p = 1; p < 8; ++p) mx = fmaxf(mx, lg[p]);
        float s = 0.f, e[8];
        for (int p = 0; p < 8; ++p) {
            e[p] = expf(lg[p] - mx);
            s += e[p];
        }
        for (int p = 0; p < 8; ++p) out[p] = e[p] / s;
    }
}

extern "C" void kernel_launch(void* const* d_in, const int* in_sizes, int n_in,
                              void* d_out, int out_size, void* d_ws, size_t ws_size,
                              hipStream_t stream) {
    const float* links_state = (const float*)d_in[0];
    const int* idm = (const int*)d_in[1];
    const int* idn = (const int*)d_in[2];
    const float* Wmsg = (const float*)d_in[3];
    const float* bmsg = (const float*)d_in[4];
    const float* Wih = (const float*)d_in[5];
    const float* Whh = (const float*)d_in[6];
    const float* bih = (const float*)d_in[7];
    const float* bhh = (const float*)d_in[8];
    const float* Wr1 = (const float*)d_in[9];
    const float* br1 = (const float*)d_in[10];
    const float* Wr2 = (const float*)d_in[11];
    const float* br2 = (const float*)d_in[12];
    const float* Wr3 = (const float*)d_in[13];
    const float* br3 = (const float*)d_in[14];

    const int N = in_sizes[0] / D;  // 50000
    const int E = in_sizes[1];      // 800000
    const int K = 8, T = 3;
    const int G = (N + 255) / 256;  // 196 scan blocks
    const int NT = (N + 63) / 64;   // 782 node tiles

    float* ws = (float*)d_ws;
    size_t nd = (size_t)N * D;
    float* cur = ws;                    // nd floats
    f16* y16 = (f16*)(ws + nd);         // nd halves
    f16* z16 = y16 + nd;                // nd halves
    f16* M16 = z16 + nd;                // nd halves
    float* kp = (float*)(M16 + nd);     // 512 floats
    float* h2 = kp + 512;               // 2048 floats
    f16* w16 = (f16*)(h2 + 2048);       // 32768 halves (64 KB)
    int* ibase = (int*)(w16 + 32768);
    int* cnt = ibase;                   // N
    int* cursor = ibase + N;            // N
    int* row_start = ibase + 2 * N;     // N+1
    int* partial = row_start + N + 1;   // G
    int* offs = partial + G;            // G
    int* csr_src = offs + G;            // E

    // CSR build + weight pack (once per launch)
    hipMemsetAsync(cnt, 0, (size_t)2 * N * sizeof(int), stream);  // cnt + cursor
    count_kernel<<<dim3((E + 255) / 256), dim3(256), 0, stream>>>(idn, cnt, E);
    scan1_kernel<<<dim3(G), dim3(256), 0, stream>>>(cnt, partial, N);
    scan2_kernel<<<dim3(1), dim3(256), 0, stream>>>(partial, offs, row_start, G, N);
    scan3_kernel<<<dim3(G), dim3(256), 0, stream>>>(cnt, offs, row_start, N);
    fill_kernel<<<dim3((E + 255) / 256), dim3(256), 0, stream>>>(idm, idn, row_start, cursor,
                                                                 csr_src, E);
    pack_kernel<<<dim3(128), dim3(256), 0, stream>>>(Wih, Whh, Wmsg, w16);

    hipMemcpyAsync(cur, links_state, nd * sizeof(float), hipMemcpyDeviceToDevice, stream);

    yz0_kernel<<<dim3(512), dim3(256), 0, stream>>>(cur, w16, y16, z16, N, NT);
    for (int t = 0; t < T; ++t) {
        gather_kernel<<<dim3(2048), dim3(256), 0, stream>>>(y16, z16, bmsg, row_start,
                                                            csr_src, M16, N);
        gruyz_kernel<<<dim3(512), dim3(256), 0, stream>>>(M16, cur, bih, bhh, w16, y16, z16,
                                                          N, NT, t < T - 1 ? 1 : 0);
    }

    hipMemsetAsync(kp, 0, (size_t)K * 64 * sizeof(float), stream);
    pathsum_kernel<<<dim3(256), dim3(256), 0, stream>>>(cur, kp, N, K);
    readout1_kernel<<<dim3(8), dim3(256), 0, stream>>>(kp, Wr1, br1, Wr2, br2, h2);
    readout2_kernel<<<dim3(1), dim3(256), 0, stream>>>(h2, Wr3, br3, (float*)d_out);
}

// Round 15
// 228.171 us; speedup vs baseline: 4.2374x; 1.2900x over previous
//
#include <hip/hip_runtime.h>
#include <hip/hip_bf16.h>

#define D 64
#define CAP 5120   // bucket capacity: mean 4096, sigma 64 -> +16 sigma

typedef _Float16 f16;
typedef _Float16 f16x2 __attribute__((ext_vector_type(2)));
typedef _Float16 f16x4 __attribute__((ext_vector_type(4)));
typedef _Float16 f16x8 __attribute__((ext_vector_type(8)));
typedef float f32x16 __attribute__((ext_vector_type(16)));

#define MFMA_F16(a, b, c) __builtin_amdgcn_mfma_f32_32x32x16_f16(a, b, c, 0, 0, 0)

__device__ __forceinline__ float selu_f(float x) {
    const float SC = 1.0507009873554805f;
    const float AL = 1.6732632423543772f;
    return x > 0.f ? SC * x : SC * AL * (__expf(x) - 1.f);
}
__device__ __forceinline__ float sigmoid_f(float x) { return 1.f / (1.f + __expf(-x)); }
__device__ __forceinline__ float tanh_f(float x) {
    float s = x < 0.f ? -1.f : 1.f;
    float t = __expf(-2.f * fabsf(x));
    return s * (1.f - t) / (1.f + t);
}
__device__ __forceinline__ float dot4(float4 a, float4 b, float acc) {
    acc = fmaf(a.x, b.x, acc);
    acc = fmaf(a.y, b.y, acc);
    acc = fmaf(a.z, b.z, acc);
    return fmaf(a.w, b.w, acc);
}
__device__ __forceinline__ f32x16 zero16() {
    f32x16 v;
#pragma unroll
    for (int i = 0; i < 16; ++i) v[i] = 0.f;
    return v;
}

// ---- once: pack 8 gate matrices to f16 with LDS swizzle pre-baked; zero kp ----
// gates 0..2 = Wih{r,z,n}, 3..5 = Whh{r,z,n}, 6 = Wy, 7 = Wz
__global__ void __launch_bounds__(256) pack_kernel(const float* __restrict__ Wih,
                                                   const float* __restrict__ Whh,
                                                   const float* __restrict__ Wmsg,
                                                   f16* __restrict__ w16,
                                                   float* __restrict__ kp) {
    int idx = blockIdx.x * 256 + threadIdx.x;  // [0, 32768)
    if (idx < 512) kp[idx] = 0.f;
    int g = idx >> 12;
    int rem = idx & 4095;
    int d = rem >> 6, k0 = rem & 63;
    float v;
    if (g < 3)      v = Wih[(g * 64 + d) * 64 + k0];
    else if (g < 6) v = Whh[((g - 3) * 64 + d) * 64 + k0];
    else            v = Wmsg[d * 128 + (g - 6) * 64 + k0];
    w16[g * 4096 + d * 64 + (k0 ^ ((d & 7) << 3))] = (f16)v;
}

// ---- CSR pass 1: bucket edges by idn>>8 with per-block run reservation ----
__global__ void __launch_bounds__(256) bucket_kernel(const int* __restrict__ idm,
                                                     const int* __restrict__ idn,
                                                     int* __restrict__ cursor,
                                                     uint2* __restrict__ barr,
                                                     int E, int NBK) {
    __shared__ int hist[256];
    __shared__ int gbase[256];
    __shared__ int loff[256];
    int t = threadIdx.x;
    if (t < NBK) hist[t] = 0;
    __syncthreads();
    int tile = blockIdx.x * 2048;
    int n_[8], m_[8], b_[8];
#pragma unroll
    for (int j = 0; j < 8; ++j) {
        int e = tile + j * 256 + t;
        if (e < E) {
            n_[j] = idn[e];
            m_[j] = idm[e];
            b_[j] = n_[j] >> 8;
            atomicAdd(&hist[b_[j]], 1);
        } else {
            b_[j] = -1;
        }
    }
    __syncthreads();
    if (t < NBK) {
        gbase[t] = hist[t] ? atomicAdd(&cursor[t], hist[t]) : 0;
        loff[t] = 0;
    }
    __syncthreads();
#pragma unroll
    for (int j = 0; j < 8; ++j) {
        if (b_[j] >= 0) {
            int r = atomicAdd(&loff[b_[j]], 1);
            uint2 e;
            e.x = (unsigned)n_[j];
            e.y = (unsigned)m_[j];
            barr[(size_t)b_[j] * CAP + gbase[b_[j]] + r] = e;
        }
    }
}

// ---- CSR pass 2: per-bucket counting sort -> row_start + coalesced csr_src ----
__global__ void __launch_bounds__(256) csr_kernel(const uint2* __restrict__ barr,
                                                  const int* __restrict__ cursor,
                                                  int* __restrict__ row_start,
                                                  int* __restrict__ csr_src,
                                                  int N, int E) {
    __shared__ int hist[256];
    __shared__ int offs[256];
    __shared__ int curc[256];
    __shared__ int red[256];
    __shared__ int ldsIdm[CAP];
    __shared__ int baseSh;
    int b = blockIdx.x, t = threadIdx.x;
    int cntb = cursor[b];
    // bucketEdgeBase = sum of cursor[0..b-1]
    red[t] = (t < b) ? cursor[t] : 0;
    __syncthreads();
    for (int off = 128; off > 0; off >>= 1) {
        if (t < off) red[t] += red[t + off];
        __syncthreads();
    }
    if (t == 0) baseSh = red[0];
    hist[t] = 0;
    __syncthreads();
    int base = baseSh;
    for (int i = t; i < cntb; i += 256) {
        int n = (int)(barr[(size_t)b * CAP + i].x) & 255;
        atomicAdd(&hist[n], 1);
    }
    __syncthreads();
    // exclusive scan hist -> offs
    int v0 = hist[t];
    offs[t] = v0;
    __syncthreads();
    for (int off = 1; off < 256; off <<= 1) {
        int v = offs[t];
        int u = (t >= off) ? offs[t - off] : 0;
        __syncthreads();
        offs[t] = v + u;
        __syncthreads();
    }
    int excl = offs[t] - v0;
    curc[t] = excl;
    int node = (b << 8) + t;
    if (node < N) row_start[node] = base + excl;
    if (b == gridDim.x - 1 && t == 0) row_start[N] = E;
    __syncthreads();
    // scatter into LDS in node order
    for (int i = t; i < cntb; i += 256) {
        uint2 e = barr[(size_t)b * CAP + i];
        int r = atomicAdd(&curc[e.x & 255], 1);
        ldsIdm[r] = (int)e.y;
    }
    __syncthreads();
    // coalesced write out
    for (int i = t; i < cntb; i += 256) csr_src[base + i] = ldsIdm[i];
}

// ---- B1: pair-gather. 2 edges per wave step; lane = (edge-half, dim-pair). ----
__global__ void __launch_bounds__(256) gather_kernel(
    const f16* __restrict__ y16, const f16* __restrict__ z16,
    const float* __restrict__ bmsg, const int* __restrict__ row_start,
    const int* __restrict__ csr_src, f16* __restrict__ M16, int N) {
    int lane = threadIdx.x & 63;
    int sub = lane >> 5;            // which edge of the pair
    int d0 = (lane & 31) * 2;       // dim pair
    int wave = blockIdx.x * (blockDim.x >> 6) + (threadIdx.x >> 6);
    int nwaves = gridDim.x * (blockDim.x >> 6);
    float b0 = bmsg[d0], b1 = bmsg[d0 + 1];
    for (int i = wave; i < N; i += nwaves) {
        f16x2 zv = *(const f16x2*)&z16[(size_t)i * 64 + d0];
        float zb0 = (float)zv[0] + b0;
        float zb1 = (float)zv[1] + b1;
        int s1 = row_start[i + 1];
        float m0 = 0.f, m1 = 0.f;
        int s = row_start[i] + sub;
        for (; s + 6 < s1; s += 8) {
            int e0 = csr_src[s],     e1 = csr_src[s + 2];
            int e2 = csr_src[s + 4], e3 = csr_src[s + 6];
            f16x2 v0 = *(const f16x2*)&y16[(size_t)e0 * 64 + d0];
            f16x2 v1 = *(const f16x2*)&y16[(size_t)e1 * 64 + d0];
            f16x2 v2 = *(const f16x2*)&y16[(size_t)e2 * 64 + d0];
            f16x2 v3 = *(const f16x2*)&y16[(size_t)e3 * 64 + d0];
            m0 += selu_f((float)v0[0] + zb0);
            m1 += selu_f((float)v0[1] + zb1);
            m0 += selu_f((float)v1[0] + zb0);
            m1 += selu_f((float)v1[1] + zb1);
            m0 += selu_f((float)v2[0] + zb0);
            m1 += selu_f((float)v2[1] + zb1);
            m0 += selu_f((float)v3[0] + zb0);
            m1 += selu_f((float)v3[1] + zb1);
        }
        for (; s < s1; s += 2) {
            int e0 = csr_src[s];
            f16x2 v0 = *(const f16x2*)&y16[(size_t)e0 * 64 + d0];
            m0 += selu_f((float)v0[0] + zb0);
            m1 += selu_f((float)v0[1] + zb1);
        }
        m0 += __shfl_xor(m0, 32, 64);
        m1 += __shfl_xor(m1, 32, 64);
        if (sub == 0) {
            f16x2 mv; mv[0] = (f16)m0; mv[1] = (f16)m1;
            *(f16x2*)&M16[(size_t)i * 64 + d0] = mv;
        }
    }
}

// ---- step 0 prologue: y,z = x@W via MFMA (gates 6,7 of w16) ----
__global__ void __launch_bounds__(256, 2) yz0_kernel(
    const float* __restrict__ x, const f16* __restrict__ w16,
    f16* __restrict__ y16, f16* __restrict__ z16, int N, int NT) {
    __shared__ __align__(16) f16 wlds[2 * 4096];  // 16 KB
    __shared__ __align__(16) f16 xh[64 * 64];     // 8 KB
    int t = threadIdx.x;
#pragma unroll
    for (int it = 0; it < 4; ++it) {
        int idx = (it * 256 + t) * 8;
        *(f16x8*)&wlds[idx] = *(const f16x8*)&w16[6 * 4096 + idx];
    }
    int lane = t & 63;
    int w = t >> 6;
    int ng = w >> 1;
    int dh = w & 1;
    int arow = ng * 32 + (lane & 31);
    int arow64 = arow * 64;
    int axor = (arow & 7) << 3;
    int bcol = dh * 32 + (lane & 31);
    int bxor = (bcol & 7) << 3;
    int kg = (lane >> 5) * 8;
    __syncthreads();
    for (int tile = blockIdx.x; tile < NT; tile += gridDim.x) {
        int base = tile * 64;
#pragma unroll
        for (int it = 0; it < 4; ++it) {
            int idx = it * 256 + t;
            int node = idx >> 4, k0 = (idx & 15) * 4;
            int gn = base + node;
            f16x4 v;
            if (gn < N) {
                float4 f4 = *(const float4*)&x[(size_t)gn * 64 + k0];
                v[0] = (f16)f4.x; v[1] = (f16)f4.y; v[2] = (f16)f4.z; v[3] = (f16)f4.w;
            } else {
#pragma unroll
                for (int u = 0; u < 4; ++u) v[u] = (f16)0.f;
            }
            *(f16x4*)&xh[node * 64 + (k0 ^ ((node & 7) << 3))] = v;
        }
        __syncthreads();
        f32x16 aY = zero16(), aZ = zero16();
#pragma unroll
        for (int ks = 0; ks < 4; ++ks) {
            int kb = ks * 16 + kg;
            f16x8 ah = *(const f16x8*)&xh[arow64 + (kb ^ axor)];
            int wof = bcol * 64 + (kb ^ bxor);
            aY = MFMA_F16(ah, *(const f16x8*)&wlds[0 * 4096 + wof], aY);
            aZ = MFMA_F16(ah, *(const f16x8*)&wlds[1 * 4096 + wof], aZ);
        }
#pragma unroll
        for (int r = 0; r < 16; ++r) {
            int rowC = (r & 3) + 8 * (r >> 2) + 4 * (lane >> 5);
            int gn = base + ng * 32 + rowC;
            if (gn < N) {
                size_t o = (size_t)gn * 64 + bcol;
                y16[o] = (f16)aY[r];
                z16[o] = (f16)aZ[r];
            }
        }
        __syncthreads();
    }
}

// ---- B2: fused MFMA GRU (+ next-step y/z when doYZ). Grid-stride tiles. ----
__global__ void __launch_bounds__(256, 2) gruyz_kernel(
    const f16* __restrict__ M16, const float* __restrict__ hin,
    float* __restrict__ hout,
    const float* __restrict__ bih, const float* __restrict__ bhh,
    const f16* __restrict__ w16, f16* __restrict__ y16, f16* __restrict__ z16,
    int N, int NT, int doYZ) {
    __shared__ __align__(16) f16 wlds[8 * 4096];  // 64 KB
    __shared__ __align__(16) f16 xm[64 * 64];     // 8 KB (M, then h_new)
    __shared__ __align__(16) f16 xh[64 * 64];     // 8 KB (h_old)
    int t = threadIdx.x;
#pragma unroll 4
    for (int it = 0; it < 16; ++it) {
        int idx = (it * 256 + t) * 8;
        *(f16x8*)&wlds[idx] = *(const f16x8*)&w16[idx];
    }
    int lane = t & 63;
    int w = t >> 6;
    int ng = w >> 1;
    int dh = w & 1;
    int arow = ng * 32 + (lane & 31);
    int arow64 = arow * 64;
    int axor = (arow & 7) << 3;
    int bcol = dh * 32 + (lane & 31);
    int bxor = (bcol & 7) << 3;
    int kg = (lane >> 5) * 8;
    float bIR = bih[bcol], bIZ = bih[64 + bcol], bIN = bih[128 + bcol];
    float bHR = bhh[bcol], bHZ = bhh[64 + bcol], bHN = bhh[128 + bcol];
    __syncthreads();
    for (int tile = blockIdx.x; tile < NT; tile += gridDim.x) {
        int base = tile * 64;
#pragma unroll
        for (int it = 0; it < 2; ++it) {
            int idx = it * 256 + t;
            int node = idx >> 3, k0 = (idx & 7) * 8;
            int gn = base + node;
            f16x8 v;
            if (gn < N) v = *(const f16x8*)&M16[(size_t)gn * 64 + k0];
            else {
#pragma unroll
            for (int u = 0; u < 8; ++u) v[u] = (f16)0.f;
            }
            *(f16x8*)&xm[node * 64 + (k0 ^ ((node & 7) << 3))] = v;
        }
#pragma unroll
        for (int it = 0; it < 4; ++it) {
            int idx = it * 256 + t;
            int node = idx >> 4, k0 = (idx & 15) * 4;
            int gn = base + node;
            f16x4 v;
            if (gn < N) {
                float4 f4 = *(const float4*)&hin[(size_t)gn * 64 + k0];
                v[0] = (f16)f4.x; v[1] = (f16)f4.y; v[2] = (f16)f4.z; v[3] = (f16)f4.w;
            } else {
#pragma unroll
                for (int u = 0; u < 4; ++u) v[u] = (f16)0.f;
            }
            *(f16x4*)&xh[node * 64 + (k0 ^ ((node & 7) << 3))] = v;
        }
        __syncthreads();

        f32x16 aIR = zero16(), aIZ = zero16(), aIN = zero16();
        f32x16 aHR = zero16(), aHZ = zero16(), aHN = zero16();
#pragma unroll
        for (int ks = 0; ks < 4; ++ks) {
            int kb = ks * 16 + kg;
            f16x8 am = *(const f16x8*)&xm[arow64 + (kb ^ axor)];
            f16x8 ah = *(const f16x8*)&xh[arow64 + (kb ^ axor)];
            int wof = bcol * 64 + (kb ^ bxor);
            aIR = MFMA_F16(am, *(const f16x8*)&wlds[0 * 4096 + wof], aIR);
            aIZ = MFMA_F16(am, *(const f16x8*)&wlds[1 * 4096 + wof], aIZ);
            aIN = MFMA_F16(am, *(const f16x8*)&wlds[2 * 4096 + wof], aIN);
            aHR = MFMA_F16(ah, *(const f16x8*)&wlds[3 * 4096 + wof], aHR);
            aHZ = MFMA_F16(ah, *(const f16x8*)&wlds[4 * 4096 + wof], aHZ);
            aHN = MFMA_F16(ah, *(const f16x8*)&wlds[5 * 4096 + wof], aHN);
        }
        __syncthreads();  // all waves done reading xm/xh

        // epilogue: h_new per reg; write hout (f32) (+ xm f16 if doYZ)
#pragma unroll
        for (int r = 0; r < 16; ++r) {
            int rowC = (r & 3) + 8 * (r >> 2) + 4 * (lane >> 5);
            int nodeLocal = ng * 32 + rowC;
            int gn = base + nodeLocal;
            float hnew = 0.f;
            if (gn < N) {
                size_t o = (size_t)gn * 64 + bcol;
                float hold = hin[o];
                float rr = sigmoid_f(aIR[r] + bIR + aHR[r] + bHR);
                float zz = sigmoid_f(aIZ[r] + bIZ + aHZ[r] + bHZ);
                float nn = tanh_f(aIN[r] + bIN + rr * (aHN[r] + bHN));
                hnew = (1.f - zz) * nn + zz * hold;
                hout[o] = hnew;
            }
            if (doYZ) xm[nodeLocal * 64 + (bcol ^ ((rowC & 7) << 3))] = (f16)hnew;
        }
        if (doYZ) {
            __syncthreads();
            f32x16 aY = zero16(), aZ = zero16();
#pragma unroll
            for (int ks = 0; ks < 4; ++ks) {
                int kb = ks * 16 + kg;
                f16x8 ahn2 = *(const f16x8*)&xm[arow64 + (kb ^ axor)];
                int wof = bcol * 64 + (kb ^ bxor);
                aY = MFMA_F16(ahn2, *(const f16x8*)&wlds[6 * 4096 + wof], aY);
                aZ = MFMA_F16(ahn2, *(const f16x8*)&wlds[7 * 4096 + wof], aZ);
            }
#pragma unroll
            for (int r = 0; r < 16; ++r) {
                int rowC = (r & 3) + 8 * (r >> 2) + 4 * (lane >> 5);
                int gn = base + ng * 32 + rowC;
                if (gn < N) {
                    size_t o = (size_t)gn * 64 + bcol;
                    y16[o] = (f16)aY[r];
                    z16[o] = (f16)aZ[r];
                }
            }
        }
        __syncthreads();  // before next tile overwrites xm/xh
    }
}

__global__ void __launch_bounds__(256) pathsum_kernel(const float* __restrict__ h,
                                                      float* __restrict__ kp, int N, int K) {
    int per = N / K;
    int blocksPerPath = gridDim.x / K;
    int p = blockIdx.x / blocksPerPath;
    int c = blockIdx.x % blocksPerPath;
    int d = threadIdx.x & 63;
    int row0 = c * (blockDim.x >> 6) + (threadIdx.x >> 6);
    int stride = blocksPerPath * (blockDim.x >> 6);
    float acc = 0.f;
    for (int r = row0; r < per; r += stride) acc += h[((size_t)p * per + r) * 64 + d];
    __shared__ float red[256];
    red[threadIdx.x] = acc;
    __syncthreads();
    if (threadIdx.x < 64) {
        float s = red[threadIdx.x] + red[64 + threadIdx.x] + red[128 + threadIdx.x] +
                  red[192 + threadIdx.x];
        atomicAdd(&kp[p * 64 + threadIdx.x], s);
    }
}

__global__ void __launch_bounds__(256) readout1_kernel(const float* __restrict__ kp,
                                                       const float* __restrict__ Wr1,
                                                       const float* __restrict__ br1,
                                                       const float* __restrict__ Wr2,
                                                       const float* __restrict__ br2,
                                                       float* __restrict__ h2) {
    int p = blockIdx.x;
    int t = threadIdx.x;
    __shared__ __align__(16) float kps[64];
    __shared__ __align__(16) float h1[256];
    if (t < 64) kps[t] = kp[p * 64 + t];
    __syncthreads();
    float acc = br1[t];
#pragma unroll
    for (int d4 = 0; d4 < 16; ++d4) {
        float4 wv = *(const float4*)&Wr1[t * 64 + d4 * 4];
        float4 kv = *(const float4*)&kps[d4 * 4];
        acc = dot4(wv, kv, acc);
    }
    h1[t] = selu_f(acc);
    __syncthreads();
    float acc2 = br2[t];
#pragma unroll 8
    for (int j4 = 0; j4 < 64; ++j4) {
        float4 wv = *(const float4*)&Wr2[t * 256 + j4 * 4];
        float4 hv = *(const float4*)&h1[j4 * 4];
        acc2 = dot4(wv, hv, acc2);
    }
    h2[p * 256 + t] = selu_f(acc2);
}

__global__ void __launch_bounds__(256) readout2_kernel(const float* __restrict__ h2,
                                                       const float* __restrict__ Wr3,
                                                       const float* __restrict__ br3,
                                                       float* __restrict__ out) {
    __shared__ float red[256];
    __shared__ float lg[8];
    int t = threadIdx.x;
    float w3 = Wr3[t];
    for (int p = 0; p < 8; ++p) {
        red[t] = w3 * h2[p * 256 + t];
        __syncthreads();
        for (int off = 128; off > 0; off >>= 1) {
            if (t < off) red[t] += red[t + off];
            __syncthreads();
        }
        if (t == 0) lg[p] = red[0] + br3[0];
        __syncthreads();
    }
    if (t == 0) {
        float mx = lg[0];
        for (int p = 1; p < 8; ++p) mx = fmaxf(mx, lg[p]);
        float s = 0.f, e[8];
        for (int p = 0; p < 8; ++p) {
            e[p] = expf(lg[p] - mx);
            s += e[p];
        }
        for (int p = 0; p < 8; ++p) out[p] = e[p] / s;
    }
}

extern "C" void kernel_launch(void* const* d_in, const int* in_sizes, int n_in,
                              void* d_out, int out_size, void* d_ws, size_t ws_size,
                              hipStream_t stream) {
    const float* links_state = (const float*)d_in[0];
    const int* idm = (const int*)d_in[1];
    const int* idn = (const int*)d_in[2];
    const float* Wmsg = (const float*)d_in[3];
    const float* bmsg = (const float*)d_in[4];
    const float* Wih = (const float*)d_in[5];
    const float* Whh = (const float*)d_in[6];
    const float* bih = (const float*)d_in[7];
    const float* bhh = (const float*)d_in[8];
    const float* Wr1 = (const float*)d_in[9];
    const float* br1 = (const float*)d_in[10];
    const float* Wr2 = (const float*)d_in[11];
    const float* br2 = (const float*)d_in[12];
    const float* Wr3 = (const float*)d_in[13];
    const float* br3 = (const float*)d_in[14];

    const int N = in_sizes[0] / D;  // 50000
    const int E = in_sizes[1];      // 800000
    const int K = 8, T = 3;
    const int NBK = (N + 255) >> 8;  // 196 buckets
    const int NT = (N + 63) / 64;    // 782 node tiles

    float* ws = (float*)d_ws;
    size_t nd = (size_t)N * D;
    float* cur = ws;                    // nd floats
    f16* y16 = (f16*)(ws + nd);         // nd halves
    f16* z16 = y16 + nd;                // nd halves
    f16* M16 = z16 + nd;                // nd halves
    float* kp = (float*)(M16 + nd);     // 512 floats
    float* h2 = kp + 512;               // 2048 floats
    f16* w16 = (f16*)(h2 + 2048);       // 32768 halves (64 KB)
    uint2* barr = (uint2*)(w16 + 32768);  // NBK*CAP uint2 (~8 MB)
    int* ibase = (int*)(barr + (size_t)NBK * CAP);
    int* cursor = ibase;                // 256
    int* row_start = ibase + 256;       // N+1
    int* csr_src = row_start + N + 1;   // E

    // CSR build (bucket sort) + weight pack + kp zero (once per launch)
    hipMemsetAsync(cursor, 0, 256 * sizeof(int), stream);
    bucket_kernel<<<dim3((E + 2047) / 2048), dim3(256), 0, stream>>>(idm, idn, cursor, barr,
                                                                     E, NBK);
    csr_kernel<<<dim3(NBK), dim3(256), 0, stream>>>(barr, cursor, row_start, csr_src, N, E);
    pack_kernel<<<dim3(128), dim3(256), 0, stream>>>(Wih, Whh, Wmsg, w16, kp);

    yz0_kernel<<<dim3(512), dim3(256), 0, stream>>>(links_state, w16, y16, z16, N, NT);
    for (int t = 0; t < T; ++t) {
        gather_kernel<<<dim3(2048), dim3(256), 0, stream>>>(y16, z16, bmsg, row_start,
                                                            csr_src, M16, N);
        gruyz_kernel<<<dim3(512), dim3(256), 0, stream>>>(
            M16, (t == 0) ? links_state : cur, cur, bih, bhh, w16, y16, z16, N, NT,
            t < T - 1 ? 1 : 0);
    }

    pathsum_kernel<<<dim3(256), dim3(256), 0, stream>>>(cur, kp, N, K);
    readout1_kernel<<<dim3(8), dim3(256), 0, stream>>>(kp, Wr1, br1, Wr2, br2, h2);
    readout2_kernel<<<dim3(1), dim3(256), 0, stream>>>(h2, Wr3, br3, (float*)d_out);
}

// Round 16
// 215.531 us; speedup vs baseline: 4.4859x; 1.0586x over previous
//
#include <hip/hip_runtime.h>
#include <hip/hip_bf16.h>

#define D 64
#define CAP 5120   // bucket capacity: mean 4096, sigma 64 -> +16 sigma

typedef _Float16 f16;
typedef _Float16 f16x2 __attribute__((ext_vector_type(2)));
typedef _Float16 f16x4 __attribute__((ext_vector_type(4)));
typedef _Float16 f16x8 __attribute__((ext_vector_type(8)));
typedef float f32x16 __attribute__((ext_vector_type(16)));

#define MFMA_F16(a, b, c) __builtin_amdgcn_mfma_f32_32x32x16_f16(a, b, c, 0, 0, 0)

__device__ __forceinline__ float selu_f(float x) {
    const float SC = 1.0507009873554805f;
    const float AL = 1.6732632423543772f;
    return x > 0.f ? SC * x : SC * AL * (__expf(x) - 1.f);
}
__device__ __forceinline__ float sigmoid_f(float x) { return 1.f / (1.f + __expf(-x)); }
__device__ __forceinline__ float tanh_f(float x) {
    float s = x < 0.f ? -1.f : 1.f;
    float t = __expf(-2.f * fabsf(x));
    return s * (1.f - t) / (1.f + t);
}
__device__ __forceinline__ float dot4(float4 a, float4 b, float acc) {
    acc = fmaf(a.x, b.x, acc);
    acc = fmaf(a.y, b.y, acc);
    acc = fmaf(a.z, b.z, acc);
    return fmaf(a.w, b.w, acc);
}
__device__ __forceinline__ f32x16 zero16() {
    f32x16 v;
#pragma unroll
    for (int i = 0; i < 16; ++i) v[i] = 0.f;
    return v;
}

// ---- dispatch 1: bucket pass (blocks < NBB) + weight pack / zero (blocks >= NBB) ----
// gates 0..2 = Wih{r,z,n}, 3..5 = Whh{r,z,n}, 6 = Wy, 7 = Wz
__global__ void __launch_bounds__(256) bucketpack_kernel(
    const int* __restrict__ idm, const int* __restrict__ idn,
    int* __restrict__ cursor, uint2* __restrict__ barr,
    const float* __restrict__ Wih, const float* __restrict__ Whh,
    const float* __restrict__ Wmsg, f16* __restrict__ w16,
    float* __restrict__ kp, int* __restrict__ rdcnt,
    int E, int NBK, int NBB) {
    __shared__ int hist[256];
    __shared__ int gbase[256];
    __shared__ int loff[256];
    int t = threadIdx.x;
    if ((int)blockIdx.x >= NBB) {
        // pack part
        int idx = ((int)blockIdx.x - NBB) * 256 + t;  // [0, 32768)
        if (idx < 512) kp[idx] = 0.f;
        if (idx == 0) *rdcnt = 0;
        int g = idx >> 12;
        int rem = idx & 4095;
        int d = rem >> 6, k0 = rem & 63;
        float v;
        if (g < 3)      v = Wih[(g * 64 + d) * 64 + k0];
        else if (g < 6) v = Whh[((g - 3) * 64 + d) * 64 + k0];
        else            v = Wmsg[d * 128 + (g - 6) * 64 + k0];
        w16[g * 4096 + d * 64 + (k0 ^ ((d & 7) << 3))] = (f16)v;
        return;
    }
    if (t < NBK) hist[t] = 0;
    __syncthreads();
    int tile = blockIdx.x * 2048;
    int n_[8], m_[8], b_[8];
#pragma unroll
    for (int j = 0; j < 8; ++j) {
        int e = tile + j * 256 + t;
        if (e < E) {
            n_[j] = idn[e];
            m_[j] = idm[e];
            b_[j] = n_[j] >> 8;
            atomicAdd(&hist[b_[j]], 1);
        } else {
            b_[j] = -1;
        }
    }
    __syncthreads();
    if (t < NBK) {
        gbase[t] = hist[t] ? atomicAdd(&cursor[t], hist[t]) : 0;
        loff[t] = 0;
    }
    __syncthreads();
#pragma unroll
    for (int j = 0; j < 8; ++j) {
        if (b_[j] >= 0) {
            int r = atomicAdd(&loff[b_[j]], 1);
            uint2 e;
            e.x = (unsigned)n_[j];
            e.y = (unsigned)m_[j];
            barr[(size_t)b_[j] * CAP + gbase[b_[j]] + r] = e;
        }
    }
}

// ---- dispatch 2: csr build (blocks < NBK) + step-0 y/z MFMA (blocks >= NBK) ----
__global__ void __launch_bounds__(256) csryz0_kernel(
    const uint2* __restrict__ barr, const int* __restrict__ cursor,
    int* __restrict__ row_start, int* __restrict__ csr_src,
    const float* __restrict__ x, const f16* __restrict__ w16,
    f16* __restrict__ y16, f16* __restrict__ z16,
    int N, int E, int NT, int NBK, int YZGRID) {
    __shared__ int hist[256];
    __shared__ int offs[256];
    __shared__ int curc[256];
    __shared__ int red[256];
    __shared__ int ldsIdm[CAP];
    __shared__ int baseSh;
    __shared__ __align__(16) f16 wlds[2 * 4096];  // 16 KB (yz0)
    __shared__ __align__(16) f16 xh[64 * 64];     // 8 KB  (yz0)
    int t = threadIdx.x;
    if ((int)blockIdx.x < NBK) {
        int b = blockIdx.x;
        int cntb = cursor[b];
        red[t] = (t < b) ? cursor[t] : 0;
        __syncthreads();
        for (int off = 128; off > 0; off >>= 1) {
            if (t < off) red[t] += red[t + off];
            __syncthreads();
        }
        if (t == 0) baseSh = red[0];
        hist[t] = 0;
        __syncthreads();
        int base = baseSh;
        for (int i = t; i < cntb; i += 256) {
            int n = (int)(barr[(size_t)b * CAP + i].x) & 255;
            atomicAdd(&hist[n], 1);
        }
        __syncthreads();
        int v0 = hist[t];
        offs[t] = v0;
        __syncthreads();
        for (int off = 1; off < 256; off <<= 1) {
            int v = offs[t];
            int u = (t >= off) ? offs[t - off] : 0;
            __syncthreads();
            offs[t] = v + u;
            __syncthreads();
        }
        int excl = offs[t] - v0;
        curc[t] = excl;
        int node = (b << 8) + t;
        if (node < N) row_start[node] = base + excl;
        if (b == NBK - 1 && t == 0) row_start[N] = E;
        __syncthreads();
        for (int i = t; i < cntb; i += 256) {
            uint2 e = barr[(size_t)b * CAP + i];
            int r = atomicAdd(&curc[e.x & 255], 1);
            ldsIdm[r] = (int)e.y;
        }
        __syncthreads();
        for (int i = t; i < cntb; i += 256) csr_src[base + i] = ldsIdm[i];
        return;
    }
    // yz0 part
    int yb = (int)blockIdx.x - NBK;
#pragma unroll
    for (int it = 0; it < 4; ++it) {
        int idx = (it * 256 + t) * 8;
        *(f16x8*)&wlds[idx] = *(const f16x8*)&w16[6 * 4096 + idx];
    }
    int lane = t & 63;
    int w = t >> 6;
    int ng = w >> 1;
    int dh = w & 1;
    int arow = ng * 32 + (lane & 31);
    int arow64 = arow * 64;
    int axor = (arow & 7) << 3;
    int bcol = dh * 32 + (lane & 31);
    int bxor = (bcol & 7) << 3;
    int kg = (lane >> 5) * 8;
    __syncthreads();
    for (int tile = yb; tile < NT; tile += YZGRID) {
        int base = tile * 64;
#pragma unroll
        for (int it = 0; it < 4; ++it) {
            int idx = it * 256 + t;
            int node = idx >> 4, k0 = (idx & 15) * 4;
            int gn = base + node;
            f16x4 v;
            if (gn < N) {
                float4 f4 = *(const float4*)&x[(size_t)gn * 64 + k0];
                v[0] = (f16)f4.x; v[1] = (f16)f4.y; v[2] = (f16)f4.z; v[3] = (f16)f4.w;
            } else {
#pragma unroll
                for (int u = 0; u < 4; ++u) v[u] = (f16)0.f;
            }
            *(f16x4*)&xh[node * 64 + (k0 ^ ((node & 7) << 3))] = v;
        }
        __syncthreads();
        f32x16 aY = zero16(), aZ = zero16();
#pragma unroll
        for (int ks = 0; ks < 4; ++ks) {
            int kb = ks * 16 + kg;
            f16x8 ah = *(const f16x8*)&xh[arow64 + (kb ^ axor)];
            int wof = bcol * 64 + (kb ^ bxor);
            aY = MFMA_F16(ah, *(const f16x8*)&wlds[0 * 4096 + wof], aY);
            aZ = MFMA_F16(ah, *(const f16x8*)&wlds[1 * 4096 + wof], aZ);
        }
#pragma unroll
        for (int r = 0; r < 16; ++r) {
            int rowC = (r & 3) + 8 * (r >> 2) + 4 * (lane >> 5);
            int gn = base + ng * 32 + rowC;
            if (gn < N) {
                size_t o = (size_t)gn * 64 + bcol;
                y16[o] = (f16)aY[r];
                z16[o] = (f16)aZ[r];
            }
        }
        __syncthreads();
    }
}

// ---- B1: pair-gather. 2 edges per wave step; lane = (edge-half, dim-pair). ----
__global__ void __launch_bounds__(256) gather_kernel(
    const f16* __restrict__ y16, const f16* __restrict__ z16,
    const float* __restrict__ bmsg, const int* __restrict__ row_start,
    const int* __restrict__ csr_src, f16* __restrict__ M16, int N) {
    int lane = threadIdx.x & 63;
    int sub = lane >> 5;            // which edge of the pair
    int d0 = (lane & 31) * 2;       // dim pair
    int wave = blockIdx.x * (blockDim.x >> 6) + (threadIdx.x >> 6);
    int nwaves = gridDim.x * (blockDim.x >> 6);
    float b0 = bmsg[d0], b1 = bmsg[d0 + 1];
    for (int i = wave; i < N; i += nwaves) {
        f16x2 zv = *(const f16x2*)&z16[(size_t)i * 64 + d0];
        float zb0 = (float)zv[0] + b0;
        float zb1 = (float)zv[1] + b1;
        int s1 = row_start[i + 1];
        float m0 = 0.f, m1 = 0.f;
        int s = row_start[i] + sub;
        for (; s + 6 < s1; s += 8) {
            int e0 = csr_src[s],     e1 = csr_src[s + 2];
            int e2 = csr_src[s + 4], e3 = csr_src[s + 6];
            f16x2 v0 = *(const f16x2*)&y16[(size_t)e0 * 64 + d0];
            f16x2 v1 = *(const f16x2*)&y16[(size_t)e1 * 64 + d0];
            f16x2 v2 = *(const f16x2*)&y16[(size_t)e2 * 64 + d0];
            f16x2 v3 = *(const f16x2*)&y16[(size_t)e3 * 64 + d0];
            m0 += selu_f((float)v0[0] + zb0);
            m1 += selu_f((float)v0[1] + zb1);
            m0 += selu_f((float)v1[0] + zb0);
            m1 += selu_f((float)v1[1] + zb1);
            m0 += selu_f((float)v2[0] + zb0);
            m1 += selu_f((float)v2[1] + zb1);
            m0 += selu_f((float)v3[0] + zb0);
            m1 += selu_f((float)v3[1] + zb1);
        }
        for (; s < s1; s += 2) {
            int e0 = csr_src[s];
            f16x2 v0 = *(const f16x2*)&y16[(size_t)e0 * 64 + d0];
            m0 += selu_f((float)v0[0] + zb0);
            m1 += selu_f((float)v0[1] + zb1);
        }
        m0 += __shfl_xor(m0, 32, 64);
        m1 += __shfl_xor(m1, 32, 64);
        if (sub == 0) {
            f16x2 mv; mv[0] = (f16)m0; mv[1] = (f16)m1;
            *(f16x2*)&M16[(size_t)i * 64 + d0] = mv;
        }
    }
}

// ---- B2: fused MFMA GRU (+ next y/z when doYZ; + path partial sums when !doYZ) ----
__global__ void __launch_bounds__(256, 2) gruyz_kernel(
    const f16* __restrict__ M16, const float* __restrict__ hin,
    float* __restrict__ hout,
    const float* __restrict__ bih, const float* __restrict__ bhh,
    const f16* __restrict__ w16, f16* __restrict__ y16, f16* __restrict__ z16,
    float* __restrict__ kp, int N, int NT, int PER, int doYZ) {
    __shared__ __align__(16) f16 wlds[8 * 4096];  // 64 KB
    __shared__ __align__(16) f16 xm[64 * 64];     // 8 KB (M, then h_new / pathbuf)
    __shared__ __align__(16) f16 xh[64 * 64];     // 8 KB (h_old)
    int t = threadIdx.x;
#pragma unroll 4
    for (int it = 0; it < 16; ++it) {
        int idx = (it * 256 + t) * 8;
        *(f16x8*)&wlds[idx] = *(const f16x8*)&w16[idx];
    }
    int lane = t & 63;
    int w = t >> 6;
    int ng = w >> 1;
    int dh = w & 1;
    int arow = ng * 32 + (lane & 31);
    int arow64 = arow * 64;
    int axor = (arow & 7) << 3;
    int bcol = dh * 32 + (lane & 31);
    int bxor = (bcol & 7) << 3;
    int kg = (lane >> 5) * 8;
    float bIR = bih[bcol], bIZ = bih[64 + bcol], bIN = bih[128 + bcol];
    float bHR = bhh[bcol], bHZ = bhh[64 + bcol], bHN = bhh[128 + bcol];
    float* pathbuf = (float*)xm;
    __syncthreads();
    for (int tile = blockIdx.x; tile < NT; tile += gridDim.x) {
        int base = tile * 64;
#pragma unroll
        for (int it = 0; it < 2; ++it) {
            int idx = it * 256 + t;
            int node = idx >> 3, k0 = (idx & 7) * 8;
            int gn = base + node;
            f16x8 v;
            if (gn < N) v = *(const f16x8*)&M16[(size_t)gn * 64 + k0];
            else {
#pragma unroll
                for (int u = 0; u < 8; ++u) v[u] = (f16)0.f;
            }
            *(f16x8*)&xm[node * 64 + (k0 ^ ((node & 7) << 3))] = v;
        }
#pragma unroll
        for (int it = 0; it < 4; ++it) {
            int idx = it * 256 + t;
            int node = idx >> 4, k0 = (idx & 15) * 4;
            int gn = base + node;
            f16x4 v;
            if (gn < N) {
                float4 f4 = *(const float4*)&hin[(size_t)gn * 64 + k0];
                v[0] = (f16)f4.x; v[1] = (f16)f4.y; v[2] = (f16)f4.z; v[3] = (f16)f4.w;
            } else {
#pragma unroll
                for (int u = 0; u < 4; ++u) v[u] = (f16)0.f;
            }
            *(f16x4*)&xh[node * 64 + (k0 ^ ((node & 7) << 3))] = v;
        }
        __syncthreads();

        f32x16 aIR = zero16(), aIZ = zero16(), aIN = zero16();
        f32x16 aHR = zero16(), aHZ = zero16(), aHN = zero16();
#pragma unroll
        for (int ks = 0; ks < 4; ++ks) {
            int kb = ks * 16 + kg;
            f16x8 am = *(const f16x8*)&xm[arow64 + (kb ^ axor)];
            f16x8 ah = *(const f16x8*)&xh[arow64 + (kb ^ axor)];
            int wof = bcol * 64 + (kb ^ bxor);
            aIR = MFMA_F16(am, *(const f16x8*)&wlds[0 * 4096 + wof], aIR);
            aIZ = MFMA_F16(am, *(const f16x8*)&wlds[1 * 4096 + wof], aIZ);
            aIN = MFMA_F16(am, *(const f16x8*)&wlds[2 * 4096 + wof], aIN);
            aHR = MFMA_F16(ah, *(const f16x8*)&wlds[3 * 4096 + wof], aHR);
            aHZ = MFMA_F16(ah, *(const f16x8*)&wlds[4 * 4096 + wof], aHZ);
            aHN = MFMA_F16(ah, *(const f16x8*)&wlds[5 * 4096 + wof], aHN);
        }
        __syncthreads();  // all waves done reading xm/xh

        int pbase = base / PER;
        int boundary = (pbase + 1) * PER;
        if (!doYZ) {
            if (t < 128) pathbuf[t] = 0.f;
            __syncthreads();
        }
        // epilogue: h_new per reg; write hout (f32) (+ xm f16 if doYZ, else path sums)
#pragma unroll
        for (int r = 0; r < 16; ++r) {
            int rowC = (r & 3) + 8 * (r >> 2) + 4 * (lane >> 5);
            int nodeLocal = ng * 32 + rowC;
            int gn = base + nodeLocal;
            float hnew = 0.f;
            bool valid = gn < N;
            if (valid) {
                size_t o = (size_t)gn * 64 + bcol;
                float hold = hin[o];
                float rr = sigmoid_f(aIR[r] + bIR + aHR[r] + bHR);
                float zz = sigmoid_f(aIZ[r] + bIZ + aHZ[r] + bHZ);
                float nn = tanh_f(aIN[r] + bIN + rr * (aHN[r] + bHN));
                hnew = (1.f - zz) * nn + zz * hold;
                hout[o] = hnew;
            }
            if (doYZ) {
                xm[nodeLocal * 64 + (bcol ^ ((rowC & 7) << 3))] = (f16)hnew;
            } else if (valid) {
                int pidx = (gn >= boundary) ? 1 : 0;
                atomicAdd(&pathbuf[pidx * 64 + bcol], hnew);
            }
        }
        if (doYZ) {
            __syncthreads();
            f32x16 aY = zero16(), aZ = zero16();
#pragma unroll
            for (int ks = 0; ks < 4; ++ks) {
                int kb = ks * 16 + kg;
                f16x8 ahn2 = *(const f16x8*)&xm[arow64 + (kb ^ axor)];
                int wof = bcol * 64 + (kb ^ bxor);
                aY = MFMA_F16(ahn2, *(const f16x8*)&wlds[6 * 4096 + wof], aY);
                aZ = MFMA_F16(ahn2, *(const f16x8*)&wlds[7 * 4096 + wof], aZ);
            }
#pragma unroll
            for (int r = 0; r < 16; ++r) {
                int rowC = (r & 3) + 8 * (r >> 2) + 4 * (lane >> 5);
                int gn = base + ng * 32 + rowC;
                if (gn < N) {
                    size_t o = (size_t)gn * 64 + bcol;
                    y16[o] = (f16)aY[r];
                    z16[o] = (f16)aZ[r];
                }
            }
        } else {
            __syncthreads();
            if (t < 128) {
                int p = pbase + (t >> 6);
                float v = pathbuf[t];
                if (p < 8 && v != 0.f) atomicAdd(&kp[p * 64 + (t & 63)], v);
            }
        }
        __syncthreads();  // before next tile overwrites xm/xh
    }
}

// ---- readout: 8 blocks (one per path); last-arriving block does the softmax ----
__global__ void __launch_bounds__(256) readout_kernel(
    const float* __restrict__ kp, const float* __restrict__ Wr1,
    const float* __restrict__ br1, const float* __restrict__ Wr2,
    const float* __restrict__ br2, const float* __restrict__ Wr3,
    const float* __restrict__ br3, float* __restrict__ lgbuf,
    int* __restrict__ rdcnt, float* __restrict__ out) {
    int p = blockIdx.x;
    int t = threadIdx.x;
    __shared__ __align__(16) float kps[64];
    __shared__ __align__(16) float h1[256];
    __shared__ float red[256];
    if (t < 64) kps[t] = kp[p * 64 + t];
    __syncthreads();
    float acc = br1[t];
#pragma unroll
    for (int d4 = 0; d4 < 16; ++d4) {
        float4 wv = *(const float4*)&Wr1[t * 64 + d4 * 4];
        float4 kv = *(const float4*)&kps[d4 * 4];
        acc = dot4(wv, kv, acc);
    }
    h1[t] = selu_f(acc);
    __syncthreads();
    float acc2 = br2[t];
#pragma unroll 8
    for (int j4 = 0; j4 < 64; ++j4) {
        float4 wv = *(const float4*)&Wr2[t * 256 + j4 * 4];
        float4 hv = *(const float4*)&h1[j4 * 4];
        acc2 = dot4(wv, hv, acc2);
    }
    float h2v = selu_f(acc2);
    red[t] = Wr3[t] * h2v;
    __syncthreads();
    for (int off = 128; off > 0; off >>= 1) {
        if (t < off) red[t] += red[t + off];
        __syncthreads();
    }
    if (t == 0) {
        float logit = red[0] + br3[0];
        atomicExch(&lgbuf[p], logit);
        __threadfence();
        int old = atomicAdd(rdcnt, 1);
        if (old == 7) {
            float lg[8];
#pragma unroll
            for (int j = 0; j < 8; ++j) lg[j] = atomicAdd(&lgbuf[j], 0.f);
            float mx = lg[0];
            for (int j = 1; j < 8; ++j) mx = fmaxf(mx, lg[j]);
            float s = 0.f, e[8];
            for (int j = 0; j < 8; ++j) {
                e[j] = __expf(lg[j] - mx);
                s += e[j];
            }
            for (int j = 0; j < 8; ++j) out[j] = e[j] / s;
        }
    }
}

extern "C" void kernel_launch(void* const* d_in, const int* in_sizes, int n_in,
                              void* d_out, int out_size, void* d_ws, size_t ws_size,
                              hipStream_t stream) {
    const float* links_state = (const float*)d_in[0];
    const int* idm = (const int*)d_in[1];
    const int* idn = (const int*)d_in[2];
    const float* Wmsg = (const float*)d_in[3];
    const float* bmsg = (const float*)d_in[4];
    const float* Wih = (const float*)d_in[5];
    const float* Whh = (const float*)d_in[6];
    const float* bih = (const float*)d_in[7];
    const float* bhh = (const float*)d_in[8];
    const float* Wr1 = (const float*)d_in[9];
    const float* br1 = (const float*)d_in[10];
    const float* Wr2 = (const float*)d_in[11];
    const float* br2 = (const float*)d_in[12];
    const float* Wr3 = (const float*)d_in[13];
    const float* br3 = (const float*)d_in[14];

    const int N = in_sizes[0] / D;  // 50000
    const int E = in_sizes[1];      // 800000
    const int K = 8, T = 3;
    const int NBK = (N + 255) >> 8;       // 196 buckets
    const int NBB = (E + 2047) / 2048;    // 391 bucket blocks
    const int NT = (N + 63) / 64;         // 782 node tiles
    const int PER = N / K;                // 6250

    float* ws = (float*)d_ws;
    size_t nd = (size_t)N * D;
    float* cur = ws;                    // nd floats
    f16* y16 = (f16*)(ws + nd);         // nd halves
    f16* z16 = y16 + nd;                // nd halves
    f16* M16 = z16 + nd;                // nd halves
    float* kp = (float*)(M16 + nd);     // 512 floats
    float* lgbuf = kp + 512;            // 8 floats
    int* rdcnt = (int*)(lgbuf + 8);     // 8 ints (1 used, alignment pad)
    f16* w16 = (f16*)(rdcnt + 8);       // 32768 halves (64 KB)
    uint2* barr = (uint2*)(w16 + 32768);  // NBK*CAP uint2 (~8 MB)
    int* ibase = (int*)(barr + (size_t)NBK * CAP);
    int* cursor = ibase;                // 256
    int* row_start = ibase + 256;       // N+1
    int* csr_src = row_start + N + 1;   // E

    // dispatch 1: bucket + pack (+ zero kp/rdcnt)
    hipMemsetAsync(cursor, 0, 256 * sizeof(int), stream);
    bucketpack_kernel<<<dim3(NBB + 128), dim3(256), 0, stream>>>(
        idm, idn, cursor, barr, Wih, Whh, Wmsg, w16, kp, rdcnt, E, NBK, NBB);
    // dispatch 2: csr + step-0 y/z
    csryz0_kernel<<<dim3(NBK + 512), dim3(256), 0, stream>>>(
        barr, cursor, row_start, csr_src, links_state, w16, y16, z16, N, E, NT, NBK, 512);

    for (int t = 0; t < T; ++t) {
        gather_kernel<<<dim3(2048), dim3(256), 0, stream>>>(y16, z16, bmsg, row_start,
                                                            csr_src, M16, N);
        gruyz_kernel<<<dim3(512), dim3(256), 0, stream>>>(
            M16, (t == 0) ? links_state : cur, cur, bih, bhh, w16, y16, z16, kp, N, NT, PER,
            t < T - 1 ? 1 : 0);
    }

    readout_kernel<<<dim3(8), dim3(256), 0, stream>>>(kp, Wr1, br1, Wr2, br2, Wr3, br3,
                                                      lgbuf, rdcnt, (float*)d_out);
}

// Round 17
// 211.824 us; speedup vs baseline: 4.5645x; 1.0175x over previous
//
#include <hip/hip_runtime.h>
#include <hip/hip_bf16.h>

#define D 64
#define CAP 5120   // bucket capacity: mean 4096, sigma 64 -> +16 sigma

typedef _Float16 f16;
typedef _Float16 f16x2 __attribute__((ext_vector_type(2)));
typedef _Float16 f16x4 __attribute__((ext_vector_type(4)));
typedef _Float16 f16x8 __attribute__((ext_vector_type(8)));
typedef float f32x16 __attribute__((ext_vector_type(16)));

#define MFMA_F16(a, b, c) __builtin_amdgcn_mfma_f32_32x32x16_f16(a, b, c, 0, 0, 0)

__device__ __forceinline__ float selu_f(float x) {
    const float SC = 1.0507009873554805f;
    const float AL = 1.6732632423543772f;
    return x > 0.f ? SC * x : SC * AL * (__expf(x) - 1.f);
}
__device__ __forceinline__ float sigmoid_f(float x) { return 1.f / (1.f + __expf(-x)); }
__device__ __forceinline__ float tanh_f(float x) {
    float s = x < 0.f ? -1.f : 1.f;
    float t = __expf(-2.f * fabsf(x));
    return s * (1.f - t) / (1.f + t);
}
__device__ __forceinline__ float dot4(float4 a, float4 b, float acc) {
    acc = fmaf(a.x, b.x, acc);
    acc = fmaf(a.y, b.y, acc);
    acc = fmaf(a.z, b.z, acc);
    return fmaf(a.w, b.w, acc);
}
__device__ __forceinline__ f32x16 zero16() {
    f32x16 v;
#pragma unroll
    for (int i = 0; i < 16; ++i) v[i] = 0.f;
    return v;
}
__device__ __forceinline__ unsigned char to_fp8(float v) {
    return (unsigned char)(__builtin_amdgcn_cvt_pk_fp8_f32(v, v, 0, false) & 0xff);
}

// ---- dispatch 1: bucket pass (blocks < NBB) + weight pack / zero (blocks >= NBB) ----
// gates 0..2 = Wih{r,z,n}, 3..5 = Whh{r,z,n}, 6 = Wy, 7 = Wz
__global__ void __launch_bounds__(256) bucketpack_kernel(
    const int* __restrict__ idm, const int* __restrict__ idn,
    int* __restrict__ cursor, unsigned* __restrict__ barr,
    const float* __restrict__ Wih, const float* __restrict__ Whh,
    const float* __restrict__ Wmsg, f16* __restrict__ w16,
    float* __restrict__ kp, int* __restrict__ rdcnt,
    int E, int NBK, int NBB) {
    __shared__ int hist[256];
    __shared__ int gbase[256];
    __shared__ int loff[256];
    int t = threadIdx.x;
    if ((int)blockIdx.x >= NBB) {
        int idx = ((int)blockIdx.x - NBB) * 256 + t;  // [0, 32768)
        if (idx < 512) kp[idx] = 0.f;
        if (idx == 0) *rdcnt = 0;
        int g = idx >> 12;
        int rem = idx & 4095;
        int d = rem >> 6, k0 = rem & 63;
        float v;
        if (g < 3)      v = Wih[(g * 64 + d) * 64 + k0];
        else if (g < 6) v = Whh[((g - 3) * 64 + d) * 64 + k0];
        else            v = Wmsg[d * 128 + (g - 6) * 64 + k0];
        w16[g * 4096 + d * 64 + (k0 ^ ((d & 7) << 3))] = (f16)v;
        return;
    }
    if (t < NBK) hist[t] = 0;
    __syncthreads();
    int tile = blockIdx.x * 2048;
    int n_[8], m_[8], b_[8];
#pragma unroll
    for (int j = 0; j < 8; ++j) {
        int e = tile + j * 256 + t;
        if (e < E) {
            n_[j] = idn[e];
            m_[j] = idm[e];
            b_[j] = n_[j] >> 8;
            atomicAdd(&hist[b_[j]], 1);
        } else {
            b_[j] = -1;
        }
    }
    __syncthreads();
    if (t < NBK) {
        gbase[t] = hist[t] ? atomicAdd(&cursor[t], hist[t]) : 0;
        loff[t] = 0;
    }
    __syncthreads();
#pragma unroll
    for (int j = 0; j < 8; ++j) {
        if (b_[j] >= 0) {
            int r = atomicAdd(&loff[b_[j]], 1);
            barr[(size_t)b_[j] * CAP + gbase[b_[j]] + r] =
                ((unsigned)m_[j] << 8) | ((unsigned)n_[j] & 255u);
        }
    }
}

// ---- dispatch 2: csr build (blocks < NBK) + step-0 y/z MFMA (blocks >= NBK) ----
__global__ void __launch_bounds__(256) csryz0_kernel(
    const unsigned* __restrict__ barr, const int* __restrict__ cursor,
    int* __restrict__ row_start, int* __restrict__ csr_src,
    const float* __restrict__ x, const f16* __restrict__ w16,
    unsigned char* __restrict__ y8, f16* __restrict__ z16,
    int N, int E, int NT, int NBK, int YZGRID) {
    __shared__ int hist[256];
    __shared__ int offs[256];
    __shared__ int curc[256];
    __shared__ int red[256];
    __shared__ int ldsIdm[CAP];
    __shared__ int baseSh;
    __shared__ __align__(16) f16 wlds[2 * 4096];  // 16 KB (yz0)
    __shared__ __align__(16) f16 xh[64 * 64];     // 8 KB  (yz0)
    int t = threadIdx.x;
    if ((int)blockIdx.x < NBK) {
        int b = blockIdx.x;
        int cntb = cursor[b];
        red[t] = (t < b) ? cursor[t] : 0;
        __syncthreads();
        for (int off = 128; off > 0; off >>= 1) {
            if (t < off) red[t] += red[t + off];
            __syncthreads();
        }
        if (t == 0) baseSh = red[0];
        hist[t] = 0;
        __syncthreads();
        int base = baseSh;
        for (int i = t; i < cntb; i += 256) {
            int n = (int)(barr[(size_t)b * CAP + i] & 255u);
            atomicAdd(&hist[n], 1);
        }
        __syncthreads();
        int v0 = hist[t];
        offs[t] = v0;
        __syncthreads();
        for (int off = 1; off < 256; off <<= 1) {
            int v = offs[t];
            int u = (t >= off) ? offs[t - off] : 0;
            __syncthreads();
            offs[t] = v + u;
            __syncthreads();
        }
        int excl = offs[t] - v0;
        curc[t] = excl;
        int node = (b << 8) + t;
        if (node < N) row_start[node] = base + excl;
        if (b == NBK - 1 && t == 0) row_start[N] = E;
        __syncthreads();
        for (int i = t; i < cntb; i += 256) {
            unsigned e = barr[(size_t)b * CAP + i];
            int r = atomicAdd(&curc[e & 255u], 1);
            ldsIdm[r] = (int)(e >> 8);
        }
        __syncthreads();
        for (int i = t; i < cntb; i += 256) csr_src[base + i] = ldsIdm[i];
        return;
    }
    // yz0 part
    int yb = (int)blockIdx.x - NBK;
#pragma unroll
    for (int it = 0; it < 4; ++it) {
        int idx = (it * 256 + t) * 8;
        *(f16x8*)&wlds[idx] = *(const f16x8*)&w16[6 * 4096 + idx];
    }
    int lane = t & 63;
    int w = t >> 6;
    int ng = w >> 1;
    int dh = w & 1;
    int arow = ng * 32 + (lane & 31);
    int arow64 = arow * 64;
    int axor = (arow & 7) << 3;
    int bcol = dh * 32 + (lane & 31);
    int bxor = (bcol & 7) << 3;
    int kg = (lane >> 5) * 8;
    __syncthreads();
    for (int tile = yb; tile < NT; tile += YZGRID) {
        int base = tile * 64;
#pragma unroll
        for (int it = 0; it < 4; ++it) {
            int idx = it * 256 + t;
            int node = idx >> 4, k0 = (idx & 15) * 4;
            int gn = base + node;
            f16x4 v;
            if (gn < N) {
                float4 f4 = *(const float4*)&x[(size_t)gn * 64 + k0];
                v[0] = (f16)f4.x; v[1] = (f16)f4.y; v[2] = (f16)f4.z; v[3] = (f16)f4.w;
            } else {
#pragma unroll
                for (int u = 0; u < 4; ++u) v[u] = (f16)0.f;
            }
            *(f16x4*)&xh[node * 64 + (k0 ^ ((node & 7) << 3))] = v;
        }
        __syncthreads();
        f32x16 aY = zero16(), aZ = zero16();
#pragma unroll
        for (int ks = 0; ks < 4; ++ks) {
            int kb = ks * 16 + kg;
            f16x8 ah = *(const f16x8*)&xh[arow64 + (kb ^ axor)];
            int wof = bcol * 64 + (kb ^ bxor);
            aY = MFMA_F16(ah, *(const f16x8*)&wlds[0 * 4096 + wof], aY);
            aZ = MFMA_F16(ah, *(const f16x8*)&wlds[1 * 4096 + wof], aZ);
        }
#pragma unroll
        for (int r = 0; r < 16; ++r) {
            int rowC = (r & 3) + 8 * (r >> 2) + 4 * (lane >> 5);
            int gn = base + ng * 32 + rowC;
            if (gn < N) {
                size_t o = (size_t)gn * 64 + bcol;
                y8[o] = to_fp8(aY[r]);
                z16[o] = (f16)aZ[r];
            }
        }
        __syncthreads();
    }
}

// ---- B1: pair-gather on fp8 y. 2 edges per wave step; lane = (edge-half, dim-pair). ----
__global__ void __launch_bounds__(256) gather_kernel(
    const unsigned char* __restrict__ y8, const f16* __restrict__ z16,
    const float* __restrict__ bmsg, const int* __restrict__ row_start,
    const int* __restrict__ csr_src, f16* __restrict__ M16, int N) {
    int lane = threadIdx.x & 63;
    int sub = lane >> 5;            // which edge of the pair
    int d0 = (lane & 31) * 2;       // dim pair
    int wave = blockIdx.x * (blockDim.x >> 6) + (threadIdx.x >> 6);
    int nwaves = gridDim.x * (blockDim.x >> 6);
    float b0 = bmsg[d0], b1 = bmsg[d0 + 1];
    for (int i = wave; i < N; i += nwaves) {
        f16x2 zv = *(const f16x2*)&z16[(size_t)i * 64 + d0];
        float zb0 = (float)zv[0] + b0;
        float zb1 = (float)zv[1] + b1;
        int s1 = row_start[i + 1];
        float m0 = 0.f, m1 = 0.f;
        int s = row_start[i] + sub;
        for (; s + 6 < s1; s += 8) {
            int e0 = csr_src[s],     e1 = csr_src[s + 2];
            int e2 = csr_src[s + 4], e3 = csr_src[s + 6];
            int v0 = *(const unsigned short*)&y8[(size_t)e0 * 64 + d0];
            int v1 = *(const unsigned short*)&y8[(size_t)e1 * 64 + d0];
            int v2 = *(const unsigned short*)&y8[(size_t)e2 * 64 + d0];
            int v3 = *(const unsigned short*)&y8[(size_t)e3 * 64 + d0];
            m0 += selu_f(__builtin_amdgcn_cvt_f32_fp8(v0, 0) + zb0);
            m1 += selu_f(__builtin_amdgcn_cvt_f32_fp8(v0, 1) + zb1);
            m0 += selu_f(__builtin_amdgcn_cvt_f32_fp8(v1, 0) + zb0);
            m1 += selu_f(__builtin_amdgcn_cvt_f32_fp8(v1, 1) + zb1);
            m0 += selu_f(__builtin_amdgcn_cvt_f32_fp8(v2, 0) + zb0);
            m1 += selu_f(__builtin_amdgcn_cvt_f32_fp8(v2, 1) + zb1);
            m0 += selu_f(__builtin_amdgcn_cvt_f32_fp8(v3, 0) + zb0);
            m1 += selu_f(__builtin_amdgcn_cvt_f32_fp8(v3, 1) + zb1);
        }
        for (; s < s1; s += 2) {
            int e0 = csr_src[s];
            int v0 = *(const unsigned short*)&y8[(size_t)e0 * 64 + d0];
            m0 += selu_f(__builtin_amdgcn_cvt_f32_fp8(v0, 0) + zb0);
            m1 += selu_f(__builtin_amdgcn_cvt_f32_fp8(v0, 1) + zb1);
        }
        m0 += __shfl_xor(m0, 32, 64);
        m1 += __shfl_xor(m1, 32, 64);
        if (sub == 0) {
            f16x2 mv; mv[0] = (f16)m0; mv[1] = (f16)m1;
            *(f16x2*)&M16[(size_t)i * 64 + d0] = mv;
        }
    }
}

// ---- B2: fused MFMA GRU (+ next y/z when doYZ; + path partial sums when !doYZ) ----
__global__ void __launch_bounds__(256, 2) gruyz_kernel(
    const f16* __restrict__ M16, const float* __restrict__ hin,
    float* __restrict__ hout,
    const float* __restrict__ bih, const float* __restrict__ bhh,
    const f16* __restrict__ w16, unsigned char* __restrict__ y8,
    f16* __restrict__ z16,
    float* __restrict__ kp, int N, int NT, int PER, int doYZ) {
    __shared__ __align__(16) f16 wlds[8 * 4096];  // 64 KB
    __shared__ __align__(16) f16 xm[64 * 64];     // 8 KB (M, then h_new / pathbuf)
    __shared__ __align__(16) f16 xh[64 * 64];     // 8 KB (h_old)
    int t = threadIdx.x;
#pragma unroll 4
    for (int it = 0; it < 16; ++it) {
        int idx = (it * 256 + t) * 8;
        *(f16x8*)&wlds[idx] = *(const f16x8*)&w16[idx];
    }
    int lane = t & 63;
    int w = t >> 6;
    int ng = w >> 1;
    int dh = w & 1;
    int arow = ng * 32 + (lane & 31);
    int arow64 = arow * 64;
    int axor = (arow & 7) << 3;
    int bcol = dh * 32 + (lane & 31);
    int bxor = (bcol & 7) << 3;
    int kg = (lane >> 5) * 8;
    float bIR = bih[bcol], bIZ = bih[64 + bcol], bIN = bih[128 + bcol];
    float bHR = bhh[bcol], bHZ = bhh[64 + bcol], bHN = bhh[128 + bcol];
    float* pathbuf = (float*)xm;
    __syncthreads();
    for (int tile = blockIdx.x; tile < NT; tile += gridDim.x) {
        int base = tile * 64;
#pragma unroll
        for (int it = 0; it < 2; ++it) {
            int idx = it * 256 + t;
            int node = idx >> 3, k0 = (idx & 7) * 8;
            int gn = base + node;
            f16x8 v;
            if (gn < N) v = *(const f16x8*)&M16[(size_t)gn * 64 + k0];
            else {
#pragma unroll
                for (int u = 0; u < 8; ++u) v[u] = (f16)0.f;
            }
            *(f16x8*)&xm[node * 64 + (k0 ^ ((node & 7) << 3))] = v;
        }
#pragma unroll
        for (int it = 0; it < 4; ++it) {
            int idx = it * 256 + t;
            int node = idx >> 4, k0 = (idx & 15) * 4;
            int gn = base + node;
            f16x4 v;
            if (gn < N) {
                float4 f4 = *(const float4*)&hin[(size_t)gn * 64 + k0];
                v[0] = (f16)f4.x; v[1] = (f16)f4.y; v[2] = (f16)f4.z; v[3] = (f16)f4.w;
            } else {
#pragma unroll
                for (int u = 0; u < 4; ++u) v[u] = (f16)0.f;
            }
            *(f16x4*)&xh[node * 64 + (k0 ^ ((node & 7) << 3))] = v;
        }
        __syncthreads();

        f32x16 aIR = zero16(), aIZ = zero16(), aIN = zero16();
        f32x16 aHR = zero16(), aHZ = zero16(), aHN = zero16();
#pragma unroll
        for (int ks = 0; ks < 4; ++ks) {
            int kb = ks * 16 + kg;
            f16x8 am = *(const f16x8*)&xm[arow64 + (kb ^ axor)];
            f16x8 ah = *(const f16x8*)&xh[arow64 + (kb ^ axor)];
            int wof = bcol * 64 + (kb ^ bxor);
            aIR = MFMA_F16(am, *(const f16x8*)&wlds[0 * 4096 + wof], aIR);
            aIZ = MFMA_F16(am, *(const f16x8*)&wlds[1 * 4096 + wof], aIZ);
            aIN = MFMA_F16(am, *(const f16x8*)&wlds[2 * 4096 + wof], aIN);
            aHR = MFMA_F16(ah, *(const f16x8*)&wlds[3 * 4096 + wof], aHR);
            aHZ = MFMA_F16(ah, *(const f16x8*)&wlds[4 * 4096 + wof], aHZ);
            aHN = MFMA_F16(ah, *(const f16x8*)&wlds[5 * 4096 + wof], aHN);
        }
        __syncthreads();  // all waves done reading xm/xh

        int pbase = base / PER;
        int boundary = (pbase + 1) * PER;
        if (!doYZ) {
            if (t < 128) pathbuf[t] = 0.f;
            __syncthreads();
        }
#pragma unroll
        for (int r = 0; r < 16; ++r) {
            int rowC = (r & 3) + 8 * (r >> 2) + 4 * (lane >> 5);
            int nodeLocal = ng * 32 + rowC;
            int gn = base + nodeLocal;
            float hnew = 0.f;
            bool valid = gn < N;
            if (valid) {
                size_t o = (size_t)gn * 64 + bcol;
                float hold = hin[o];
                float rr = sigmoid_f(aIR[r] + bIR + aHR[r] + bHR);
                float zz = sigmoid_f(aIZ[r] + bIZ + aHZ[r] + bHZ);
                float nn = tanh_f(aIN[r] + bIN + rr * (aHN[r] + bHN));
                hnew = (1.f - zz) * nn + zz * hold;
                hout[o] = hnew;
            }
            if (doYZ) {
                xm[nodeLocal * 64 + (bcol ^ ((rowC & 7) << 3))] = (f16)hnew;
            } else if (valid) {
                int pidx = (gn >= boundary) ? 1 : 0;
                atomicAdd(&pathbuf[pidx * 64 + bcol], hnew);
            }
        }
        if (doYZ) {
            __syncthreads();
            f32x16 aY = zero16(), aZ = zero16();
#pragma unroll
            for (int ks = 0; ks < 4; ++ks) {
                int kb = ks * 16 + kg;
                f16x8 ahn2 = *(const f16x8*)&xm[arow64 + (kb ^ axor)];
                int wof = bcol * 64 + (kb ^ bxor);
                aY = MFMA_F16(ahn2, *(const f16x8*)&wlds[6 * 4096 + wof], aY);
                aZ = MFMA_F16(ahn2, *(const f16x8*)&wlds[7 * 4096 + wof], aZ);
            }
#pragma unroll
            for (int r = 0; r < 16; ++r) {
                int rowC = (r & 3) + 8 * (r >> 2) + 4 * (lane >> 5);
                int gn = base + ng * 32 + rowC;
                if (gn < N) {
                    size_t o = (size_t)gn * 64 + bcol;
                    y8[o] = to_fp8(aY[r]);
                    z16[o] = (f16)aZ[r];
                }
            }
        } else {
            __syncthreads();
            if (t < 128) {
                int p = pbase + (t >> 6);
                float v = pathbuf[t];
                if (p < 8 && v != 0.f) atomicAdd(&kp[p * 64 + (t & 63)], v);
            }
        }
        __syncthreads();  // before next tile overwrites xm/xh
    }
}

// ---- readout: 8 blocks (one per path); last-arriving block does the softmax ----
__global__ void __launch_bounds__(256) readout_kernel(
    const float* __restrict__ kp, const float* __restrict__ Wr1,
    const float* __restrict__ br1, const float* __restrict__ Wr2,
    const float* __restrict__ br2, const float* __restrict__ Wr3,
    const float* __restrict__ br3, float* __restrict__ lgbuf,
    int* __restrict__ rdcnt, float* __restrict__ out) {
    int p = blockIdx.x;
    int t = threadIdx.x;
    __shared__ __align__(16) float kps[64];
    __shared__ __align__(16) float h1[256];
    __shared__ float red[256];
    if (t < 64) kps[t] = kp[p * 64 + t];
    __syncthreads();
    float acc = br1[t];
#pragma unroll
    for (int d4 = 0; d4 < 16; ++d4) {
        float4 wv = *(const float4*)&Wr1[t * 64 + d4 * 4];
        float4 kv = *(const float4*)&kps[d4 * 4];
        acc = dot4(wv, kv, acc);
    }
    h1[t] = selu_f(acc);
    __syncthreads();
    float acc2 = br2[t];
#pragma unroll 8
    for (int j4 = 0; j4 < 64; ++j4) {
        float4 wv = *(const float4*)&Wr2[t * 256 + j4 * 4];
        float4 hv = *(const float4*)&h1[j4 * 4];
        acc2 = dot4(wv, hv, acc2);
    }
    float h2v = selu_f(acc2);
    red[t] = Wr3[t] * h2v;
    __syncthreads();
    for (int off = 128; off > 0; off >>= 1) {
        if (t < off) red[t] += red[t + off];
        __syncthreads();
    }
    if (t == 0) {
        float logit = red[0] + br3[0];
        atomicExch(&lgbuf[p], logit);
        __threadfence();
        int old = atomicAdd(rdcnt, 1);
        if (old == 7) {
            float lg[8];
#pragma unroll
            for (int j = 0; j < 8; ++j) lg[j] = atomicAdd(&lgbuf[j], 0.f);
            float mx = lg[0];
            for (int j = 1; j < 8; ++j) mx = fmaxf(mx, lg[j]);
            float s = 0.f, e[8];
            for (int j = 0; j < 8; ++j) {
                e[j] = __expf(lg[j] - mx);
                s += e[j];
            }
            for (int j = 0; j < 8; ++j) out[j] = e[j] / s;
        }
    }
}

extern "C" void kernel_launch(void* const* d_in, const int* in_sizes, int n_in,
                              void* d_out, int out_size, void* d_ws, size_t ws_size,
                              hipStream_t stream) {
    const float* links_state = (const float*)d_in[0];
    const int* idm = (const int*)d_in[1];
    const int* idn = (const int*)d_in[2];
    const float* Wmsg = (const float*)d_in[3];
    const float* bmsg = (const float*)d_in[4];
    const float* Wih = (const float*)d_in[5];
    const float* Whh = (const float*)d_in[6];
    const float* bih = (const float*)d_in[7];
    const float* bhh = (const float*)d_in[8];
    const float* Wr1 = (const float*)d_in[9];
    const float* br1 = (const float*)d_in[10];
    const float* Wr2 = (const float*)d_in[11];
    const float* br2 = (const float*)d_in[12];
    const float* Wr3 = (const float*)d_in[13];
    const float* br3 = (const float*)d_in[14];

    const int N = in_sizes[0] / D;  // 50000
    const int E = in_sizes[1];      // 800000
    const int K = 8, T = 3;
    const int NBK = (N + 255) >> 8;       // 196 buckets
    const int NBB = (E + 2047) / 2048;    // 391 bucket blocks
    const int NT = (N + 63) / 64;         // 782 node tiles
    const int PER = N / K;                // 6250

    float* ws = (float*)d_ws;
    size_t nd = (size_t)N * D;
    float* cur = ws;                        // nd floats
    f16* z16 = (f16*)(ws + nd);             // nd halves
    f16* M16 = z16 + nd;                    // nd halves
    unsigned char* y8 = (unsigned char*)(M16 + nd);  // nd bytes
    float* kp = (float*)(y8 + nd);          // 512 floats (nd % 4 == 0)
    float* lgbuf = kp + 512;                // 8 floats
    int* rdcnt = (int*)(lgbuf + 8);         // 8 ints (1 used)
    f16* w16 = (f16*)(rdcnt + 8);           // 32768 halves (64 KB)
    unsigned* barr = (unsigned*)(w16 + 32768);  // NBK*CAP u32 (~4 MB)
    int* ibase = (int*)(barr + (size_t)NBK * CAP);
    int* cursor = ibase;                    // 256
    int* row_start = ibase + 256;           // N+1
    int* csr_src = row_start + N + 1;       // E

    // dispatch 1: bucket + pack (+ zero kp/rdcnt)
    hipMemsetAsync(cursor, 0, 256 * sizeof(int), stream);
    bucketpack_kernel<<<dim3(NBB + 128), dim3(256), 0, stream>>>(
        idm, idn, cursor, barr, Wih, Whh, Wmsg, w16, kp, rdcnt, E, NBK, NBB);
    // dispatch 2: csr + step-0 y/z
    csryz0_kernel<<<dim3(NBK + 512), dim3(256), 0, stream>>>(
        barr, cursor, row_start, csr_src, links_state, w16, y8, z16, N, E, NT, NBK, 512);

    for (int t = 0; t < T; ++t) {
        gather_kernel<<<dim3(2048), dim3(256), 0, stream>>>(y8, z16, bmsg, row_start,
                                                            csr_src, M16, N);
        gruyz_kernel<<<dim3(512), dim3(256), 0, stream>>>(
            M16, (t == 0) ? links_state : cur, cur, bih, bhh, w16, y8, z16, kp, N, NT, PER,
            t < T - 1 ? 1 : 0);
    }

    readout_kernel<<<dim3(8), dim3(256), 0, stream>>>(kp, Wr1, br1, Wr2, br2, Wr3, br3,
                                                      lgbuf, rdcnt, (float*)d_out);
}